// Round 1
// baseline (4771.524 us; speedup 1.0000x reference)
//
#include <hip/hip_runtime.h>
#include <hip/hip_bf16.h>

#define NN 1000000
#define EE 4000000
#define BB 1024
#define DIM 32
#define FXDIM 55
#define EMBD 128
#define VOCAB 26
#define LL 1000
#define NF 32
#define KK 8
#define CF 3872   // 32*121

// ---------------- CSR build ----------------
__global__ void k_count(const int* __restrict__ dst, int* __restrict__ deg) {
    int e = blockIdx.x * blockDim.x + threadIdx.x;
    if (e < EE) atomicAdd(&deg[dst[e]], 1);
}

__global__ void k_scan1(const int* __restrict__ deg, int* __restrict__ rowptr, int* __restrict__ bsum) {
    __shared__ int sh[256];
    int t = threadIdx.x;
    size_t base = (size_t)blockIdx.x * 1024 + (size_t)t * 4;
    int v[4];
#pragma unroll
    for (int j = 0; j < 4; ++j) v[j] = (base + j < NN) ? deg[base + j] : 0;
    int tsum = v[0] + v[1] + v[2] + v[3];
    sh[t] = tsum;
    __syncthreads();
    for (int off = 1; off < 256; off <<= 1) {
        int add = (t >= off) ? sh[t - off] : 0;
        __syncthreads();
        sh[t] += add;
        __syncthreads();
    }
    int run = sh[t] - tsum;  // exclusive prefix
#pragma unroll
    for (int j = 0; j < 4; ++j) {
        if (base + j < NN) rowptr[base + j] = run;
        run += v[j];
    }
    if (t == 255) bsum[blockIdx.x] = sh[255];
}

__global__ void k_scan2(int* __restrict__ bs, int nb) {
    __shared__ int sh[1024];
    int t = threadIdx.x;
    int v = (t < nb) ? bs[t] : 0;
    sh[t] = v;
    __syncthreads();
    for (int off = 1; off < 1024; off <<= 1) {
        int add = (t >= off) ? sh[t - off] : 0;
        __syncthreads();
        sh[t] += add;
        __syncthreads();
    }
    if (t < nb) bs[t] = sh[t] - v;  // exclusive
}

__global__ void k_scan3(int* __restrict__ rowptr, const int* __restrict__ bs) {
    size_t base = (size_t)blockIdx.x * 1024 + (size_t)threadIdx.x * 4;
    int off = bs[blockIdx.x];
#pragma unroll
    for (int j = 0; j < 4; ++j)
        if (base + j < NN) rowptr[base + j] += off;
    if (blockIdx.x == 0 && threadIdx.x == 0) rowptr[NN] = EE;
}

__global__ void k_copy(int* __restrict__ f, const int* __restrict__ r) {
    int i = blockIdx.x * blockDim.x + threadIdx.x;
    if (i < NN) f[i] = r[i];
}

__global__ void k_fill(const int* __restrict__ src, const int* __restrict__ dst,
                       int* __restrict__ fill, int* __restrict__ col) {
    int e = blockIdx.x * blockDim.x + threadIdx.x;
    if (e < EE) {
        int d = dst[e];
        int pos = atomicAdd(&fill[d], 1);
        col[pos] = src[e];
    }
}

// ---------------- layer-1 projection p = xd @ w1 ----------------
__global__ __launch_bounds__(256) void k_p1(const float* __restrict__ xd,
                                            const float* __restrict__ w1,
                                            float* __restrict__ out) {
    int lane = threadIdx.x & 31;
    float wc[FXDIM];
#pragma unroll
    for (int k = 0; k < FXDIM; ++k) wc[k] = w1[k * 32 + lane];
    int gid = (blockIdx.x * blockDim.x + threadIdx.x) >> 5;
    int ng = (gridDim.x * blockDim.x) >> 5;
    for (int i = gid; i < NN; i += ng) {
        const float* row = xd + (size_t)i * FXDIM;
        float x0 = row[lane];
        float x1 = (lane < FXDIM - 32) ? row[32 + lane] : 0.f;
        float acc = 0.f;
#pragma unroll
        for (int k = 0; k < 32; ++k) acc += __shfl(x0, k, 32) * wc[k];
#pragma unroll
        for (int k = 0; k < FXDIM - 32; ++k) acc += __shfl(x1, k, 32) * wc[32 + k];
        out[(size_t)i * 32 + lane] = acc;
    }
}

// ---------------- fused GIN layer: gather-agg + MLP + BN stats ----------------
template <int FIRST>
__global__ __launch_bounds__(256) void k_gin(const float* __restrict__ hsrc,
                                             const int* __restrict__ rowptr,
                                             const int* __restrict__ colidx,
                                             const float* __restrict__ aff,
                                             const float* __restrict__ w1,
                                             const float* __restrict__ b1,
                                             const float* __restrict__ w2,
                                             const float* __restrict__ b2,
                                             float* __restrict__ hdst,
                                             float* __restrict__ partial) {
    const int lane = threadIdx.x & 31;
    float w1c[32], w2c[32];
    if (!FIRST) {
#pragma unroll
        for (int k = 0; k < 32; ++k) w1c[k] = w1[k * 32 + lane];
    }
#pragma unroll
    for (int k = 0; k < 32; ++k) w2c[k] = w2[k * 32 + lane];
    float b1v = b1[lane], b2v = b2[lane];
    float sA = 1.f, tA = 0.f;
    if (!FIRST) { sA = aff[lane]; tA = aff[32 + lane]; }

    float psum = 0.f, psq = 0.f;
    int gid = (blockIdx.x * blockDim.x + threadIdx.x) >> 5;
    int ng = (gridDim.x * blockDim.x) >> 5;
    for (int i = gid; i < NN; i += ng) {
        int r0 = rowptr[i], r1 = rowptr[i + 1];
        float acc = hsrc[(size_t)i * 32 + lane];
        for (int e = r0; e < r1; ++e) {
            int s = colidx[e];
            acc += hsrc[(size_t)s * 32 + lane];
        }
        float z;
        if (FIRST) {
            z = fmaxf(acc + b1v, 0.f);
        } else {
            float u = sA * acc + (float)(r1 - r0 + 1) * tA;
            float a1 = b1v;
#pragma unroll
            for (int k = 0; k < 32; ++k) a1 += __shfl(u, k, 32) * w1c[k];
            z = fmaxf(a1, 0.f);
        }
        float a2 = b2v;
#pragma unroll
        for (int k = 0; k < 32; ++k) a2 += __shfl(z, k, 32) * w2c[k];
        float h = fmaxf(a2, 0.f);
        hdst[(size_t)i * 32 + lane] = h;
        psum += h;
        psq += h * h;
    }
    __shared__ float red[8][64];
    int wid = threadIdx.x >> 5;
    red[wid][lane] = psum;
    red[wid][32 + lane] = psq;
    __syncthreads();
    if (threadIdx.x < 64) {
        float s = 0.f;
#pragma unroll
        for (int w = 0; w < 8; ++w) s += red[w][threadIdx.x];
        partial[(size_t)blockIdx.x * 64 + threadIdx.x] = s;
    }
}

// ---------------- finalize BN stats -> affine s,t ----------------
__global__ void k_reduce(const float* __restrict__ partial, int nblocks,
                         const float* __restrict__ g, const float* __restrict__ bt,
                         float* __restrict__ aff) {
    int t = threadIdx.x;
    int c = t & 63, q = t >> 6;
    double s = 0.0;
    for (int b = q; b < nblocks; b += 4) s += (double)partial[(size_t)b * 64 + c];
    __shared__ double red[4][64];
    red[q][c] = s;
    __syncthreads();
    __shared__ double st[64];
    if (t < 64) st[c] = red[0][c] + red[1][c] + red[2][c] + red[3][c];
    __syncthreads();
    if (t < 32) {
        double mean = st[t] / (double)NN;
        double var = st[32 + t] / (double)NN - mean * mean;
        float r = (float)rsqrt(var + 1e-5);
        float sv = g[t] * r;
        aff[t] = sv;
        aff[32 + t] = bt[t] - (float)mean * sv;
    }
}

// ---------------- pooling (xd_batch sorted -> run-length + atomics) ----------------
__global__ __launch_bounds__(256) void k_pool(const float* __restrict__ h,
                                              const int* __restrict__ batch,
                                              float* __restrict__ ps) {
    int lane = threadIdx.x & 31;
    int g = threadIdx.x >> 5;
    const int chunk = (NN + gridDim.x - 1) / gridDim.x;
    int s0 = blockIdx.x * chunk;
    int s1 = min(NN, s0 + chunk);
    int curb = -1;
    float acc = 0.f;
    for (int i = s0 + g; i < s1; i += 8) {
        int b = batch[i];
        if (b != curb) {
            if (curb >= 0) atomicAdd(&ps[curb * 32 + lane], acc);
            acc = 0.f;
            curb = b;
        }
        acc += h[(size_t)i * 32 + lane];
    }
    if (curb >= 0) atomicAdd(&ps[curb * 32 + lane], acc);
}

__device__ int lowerb(const int* a, int n, int key) {
    int lo = 0, hi = n;
    while (lo < hi) {
        int m = (lo + hi) >> 1;
        if (a[m] < key) lo = m + 1;
        else hi = m;
    }
    return lo;
}

__global__ void k_counts(const int* __restrict__ batch, int* __restrict__ cnt) {
    int b = blockIdx.x * blockDim.x + threadIdx.x;
    if (b < BB) cnt[b] = lowerb(batch, NN, b + 1) - lowerb(batch, NN, b);
}

// ---------------- xdv = ReLU(pooled' @ fcd_w + fcd_b) ----------------
__global__ __launch_bounds__(128) void k_xdv(const float* __restrict__ ps,
                                             const int* __restrict__ cnt,
                                             const float* __restrict__ aff,
                                             const float* __restrict__ w,
                                             const float* __restrict__ bb,
                                             float* __restrict__ xdv) {
    int b = blockIdx.x;
    int j = threadIdx.x;
    __shared__ float p[32];
    if (j < 32) p[j] = aff[j] * ps[b * 32 + j] + (float)cnt[b] * aff[32 + j];
    __syncthreads();
    float acc = bb[j];
#pragma unroll
    for (int c = 0; c < 32; ++c) acc += p[c] * w[c * 128 + j];
    xdv[b * 128 + j] = fmaxf(acc, 0.f);
}

// ---------------- conv branch ----------------
__global__ void k_kT(const float* __restrict__ ck, float* __restrict__ kT) {
    int i = blockIdx.x;
    int t = threadIdx.x;
    int o = t >> 3, k = t & 7;
    kT[(size_t)i * 256 + t] = ck[(size_t)o * (LL * KK) + (size_t)i * KK + k];
}

__global__ __launch_bounds__(256) void k_conv(const int* __restrict__ xt,
                                              const float* __restrict__ kT,
                                              const float* __restrict__ emb,
                                              const float* __restrict__ cb,
                                              float* __restrict__ cbuf) {
    __shared__ float S[VOCAB * 256];
    __shared__ float Em[VOCAB * EMBD];
    int t = threadIdx.x;
    int b = blockIdx.x;
    for (int v = t; v < VOCAB * 256; v += 256) S[v] = 0.f;
    for (int v = t; v < VOCAB * EMBD; v += 256) Em[v] = emb[v];
    __syncthreads();
    const int* row = xt + (size_t)b * LL;
#pragma unroll 4
    for (int i = 0; i < LL; ++i) {
        int v = row[i];
        S[v * 256 + t] += kT[(size_t)i * 256 + t];
    }
    __syncthreads();
    int h = t & 127, half = t >> 7;
    if (h < 121) {
        float acc[16];
        int o0 = half * 16;
#pragma unroll
        for (int o = 0; o < 16; ++o) acc[o] = cb[o0 + o];
        for (int v = 0; v < VOCAB; ++v) {
            float e[8];
#pragma unroll
            for (int k = 0; k < 8; ++k) e[k] = Em[v * EMBD + h + k];
#pragma unroll
            for (int o = 0; o < 16; ++o) {
                float a = acc[o];
#pragma unroll
                for (int k = 0; k < 8; ++k) a += S[v * 256 + (o0 + o) * 8 + k] * e[k];
                acc[o] = a;
            }
        }
#pragma unroll
        for (int o = 0; o < 16; ++o)
            cbuf[(size_t)b * CF + (size_t)(o0 + o) * 121 + h] = acc[o];
    }
}

// ---------------- xtv = c_flat @ fct_w + fct_b ----------------
__global__ __launch_bounds__(128) void k_xtv(const float* __restrict__ c,
                                             const float* __restrict__ w,
                                             const float* __restrict__ bb,
                                             float* __restrict__ xtv) {
    int j = threadIdx.x;
    int b0 = blockIdx.x * 8;
    float acc[8];
#pragma unroll
    for (int r = 0; r < 8; ++r) acc[r] = bb[j];
    for (int f = 0; f < CF; ++f) {
        float wv = w[(size_t)f * 128 + j];
#pragma unroll
        for (int r = 0; r < 8; ++r) acc[r] += c[(size_t)(b0 + r) * CF + f] * wv;
    }
#pragma unroll
    for (int r = 0; r < 8; ++r) xtv[(b0 + r) * 128 + j] = acc[r];
}

// ---------------- classifier ----------------
__global__ __launch_bounds__(1024) void k_cls1(const float* __restrict__ xdv,
                                               const float* __restrict__ xtv,
                                               const float* __restrict__ w,
                                               const float* __restrict__ bb,
                                               float* __restrict__ h1) {
    __shared__ float X[8][256];
    int j = threadIdx.x;
    int b0 = blockIdx.x * 8;
    for (int idx = j; idx < 8 * 256; idx += 1024) {
        int r = idx >> 8, k = idx & 255;
        X[r][k] = (k < 128) ? xdv[(b0 + r) * 128 + k] : xtv[(b0 + r) * 128 + (k - 128)];
    }
    __syncthreads();
    float acc[8];
#pragma unroll
    for (int r = 0; r < 8; ++r) acc[r] = bb[j];
    for (int k = 0; k < 256; ++k) {
        float wv = w[(size_t)k * 1024 + j];
#pragma unroll
        for (int r = 0; r < 8; ++r) acc[r] += X[r][k] * wv;
    }
#pragma unroll
    for (int r = 0; r < 8; ++r) h1[(size_t)(b0 + r) * 1024 + j] = fmaxf(acc[r], 0.f);
}

__global__ __launch_bounds__(256) void k_cls2(const float* __restrict__ h1,
                                              const float* __restrict__ w,
                                              const float* __restrict__ bb,
                                              float* __restrict__ h2) {
    __shared__ float X[8][1024];
    int j = threadIdx.x;
    int b0 = blockIdx.x * 8;
    for (int idx = j; idx < 8 * 1024; idx += 256) {
        int r = idx >> 10, k = idx & 1023;
        X[r][k] = h1[(size_t)(b0 + r) * 1024 + k];
    }
    __syncthreads();
    float acc[8];
#pragma unroll
    for (int r = 0; r < 8; ++r) acc[r] = bb[j];
    for (int k = 0; k < 1024; ++k) {
        float wv = w[(size_t)k * 256 + j];
#pragma unroll
        for (int r = 0; r < 8; ++r) acc[r] += X[r][k] * wv;
    }
#pragma unroll
    for (int r = 0; r < 8; ++r) h2[(size_t)(b0 + r) * 256 + j] = fmaxf(acc[r], 0.f);
}

__global__ __launch_bounds__(256) void k_cls3(const float* __restrict__ h2,
                                              const float* __restrict__ w,
                                              const float* __restrict__ bb,
                                              const float* __restrict__ y,
                                              float* __restrict__ dout) {
    int lane = threadIdx.x & 63;
    int b = (blockIdx.x * blockDim.x + threadIdx.x) >> 6;
    if (b >= BB) return;
    float acc = 0.f;
    for (int k = lane; k < 256; k += 64) acc += h2[(size_t)b * 256 + k] * w[k];
#pragma unroll
    for (int off = 32; off; off >>= 1) acc += __shfl_xor(acc, off, 64);
    if (lane == 0) dout[b] = acc + bb[0];
    if (lane == 1) dout[BB + b] = y[b];
}

// ---------------- launch ----------------
extern "C" void kernel_launch(void* const* d_in, const int* in_sizes, int n_in,
                              void* d_out, int out_size, void* d_ws, size_t ws_size,
                              hipStream_t stream) {
    const float* xd = (const float*)d_in[0];
    const int* ei = (const int*)d_in[1];
    const int* batch = (const int*)d_in[2];
    const int* xt = (const int*)d_in[3];
    const float* y = (const float*)d_in[4];
    const float* g1w1 = (const float*)d_in[5];
    const float* g1b1 = (const float*)d_in[6];
    const float* g1w2 = (const float*)d_in[7];
    const float* g1b2 = (const float*)d_in[8];
    const float* grw1 = (const float*)d_in[9];
    const float* grb1 = (const float*)d_in[10];
    const float* grw2 = (const float*)d_in[11];
    const float* grb2 = (const float*)d_in[12];
    const float* bng = (const float*)d_in[13];
    const float* bnb = (const float*)d_in[14];
    const float* fcdw = (const float*)d_in[15];
    const float* fcdb = (const float*)d_in[16];
    const float* emb = (const float*)d_in[17];
    const float* convk = (const float*)d_in[18];
    const float* convb = (const float*)d_in[19];
    const float* fctw = (const float*)d_in[20];
    const float* fctb = (const float*)d_in[21];
    const float* cw1 = (const float*)d_in[22];
    const float* cb1 = (const float*)d_in[23];
    const float* cw2 = (const float*)d_in[24];
    const float* cb2 = (const float*)d_in[25];
    const float* cw3 = (const float*)d_in[26];
    const float* cb3 = (const float*)d_in[27];

    const int* src = ei;
    const int* dst = ei + EE;

    size_t off = 0;
    auto alloc = [&](size_t bytes) {
        size_t o = off;
        off = (off + bytes + 255) & ~(size_t)255;
        return o;
    };
    char* ws = (char*)d_ws;
    size_t o_deg = alloc(4ull * NN);
    size_t o_rp = alloc(4ull * (NN + 1));
    size_t o_fill = alloc(4ull * NN);
    size_t o_col = alloc(4ull * EE);
    size_t o_bsum = alloc(4ull * 1024);
    size_t o_ha = alloc(4ull * NN * 32);
    size_t o_hb = alloc(4ull * NN * 32);
    size_t o_part = alloc(4ull * 2048 * 64);
    size_t o_aff = alloc(4ull * 64);
    size_t o_ps = alloc(4ull * BB * 32);
    size_t o_cnt = alloc(4ull * BB);
    size_t o_xdv = alloc(4ull * BB * 128);
    size_t o_kT = alloc(4ull * LL * 256);
    size_t o_c = alloc(4ull * BB * CF);
    size_t o_xtv = alloc(4ull * BB * 128);
    size_t o_h1 = alloc(4ull * BB * 1024);
    size_t o_h2 = alloc(4ull * BB * 256);

    int* deg = (int*)(ws + o_deg);
    int* rp = (int*)(ws + o_rp);
    int* fill = (int*)(ws + o_fill);
    int* col = (int*)(ws + o_col);
    int* bsum = (int*)(ws + o_bsum);
    float* ha = (float*)(ws + o_ha);
    float* hb = (float*)(ws + o_hb);
    float* part = (float*)(ws + o_part);
    float* aff = (float*)(ws + o_aff);
    float* ps = (float*)(ws + o_ps);
    int* cnt = (int*)(ws + o_cnt);
    float* xdv = (float*)(ws + o_xdv);
    float* kT = (float*)(ws + o_kT);
    float* cbuf = (float*)(ws + o_c);
    float* xtv = (float*)(ws + o_xtv);
    float* h1 = (float*)(ws + o_h1);
    float* h2 = (float*)(ws + o_h2);
    float* dout = (float*)d_out;

    // --- CSR build ---
    hipMemsetAsync(deg, 0, 4ull * NN, stream);
    k_count<<<EE / 256, 256, 0, stream>>>(dst, deg);
    k_scan1<<<977, 256, 0, stream>>>(deg, rp, bsum);
    k_scan2<<<1, 1024, 0, stream>>>(bsum, 977);
    k_scan3<<<977, 256, 0, stream>>>(rp, bsum);
    k_copy<<<(NN + 255) / 256, 256, 0, stream>>>(fill, rp);
    k_fill<<<EE / 256, 256, 0, stream>>>(src, dst, fill, col);

    // --- GIN layers ---
    k_p1<<<2048, 256, 0, stream>>>(xd, g1w1, ha);
    k_gin<1><<<2048, 256, 0, stream>>>(ha, rp, col, aff, g1w1, g1b1, g1w2, g1b2, hb, part);
    k_reduce<<<1, 256, 0, stream>>>(part, 2048, bng, bnb, aff);
    const float* srcbuf = hb;
    float* dstbuf = ha;
    for (int i = 0; i < 4; ++i) {
        k_gin<0><<<2048, 256, 0, stream>>>(srcbuf, rp, col, aff,
                                           grw1 + (size_t)i * 1024, grb1 + (size_t)i * 32,
                                           grw2 + (size_t)i * 1024, grb2 + (size_t)i * 32,
                                           dstbuf, part);
        k_reduce<<<1, 256, 0, stream>>>(part, 2048, bng + (i + 1) * 32, bnb + (i + 1) * 32, aff);
        const float* tmp = srcbuf;
        srcbuf = dstbuf;
        dstbuf = (float*)tmp;
    }
    // after loop: srcbuf == hb (layer-5 output), aff == layer-5 affine

    // --- pooling + xdv ---
    hipMemsetAsync(ps, 0, 4ull * BB * 32, stream);
    k_pool<<<1024, 256, 0, stream>>>(srcbuf, batch, ps);
    k_counts<<<4, 256, 0, stream>>>(batch, cnt);
    k_xdv<<<BB, 128, 0, stream>>>(ps, cnt, aff, fcdw, fcdb, xdv);

    // --- conv branch ---
    k_kT<<<LL, 256, 0, stream>>>(convk, kT);
    k_conv<<<BB, 256, 0, stream>>>(xt, kT, emb, convb, cbuf);
    k_xtv<<<BB / 8, 128, 0, stream>>>(cbuf, fctw, fctb, xtv);

    // --- classifier ---
    k_cls1<<<BB / 8, 1024, 0, stream>>>(xdv, xtv, cw1, cb1, h1);
    k_cls2<<<BB / 8, 256, 0, stream>>>(h1, cw2, cb2, h2);
    k_cls3<<<256, 256, 0, stream>>>(h2, cw3, cb3, y, dout);
}

// Round 2
// 3879.991 us; speedup vs baseline: 1.2298x; 1.2298x over previous
//
#include <hip/hip_runtime.h>
#include <hip/hip_bf16.h>

#define NN 1000000
#define EE 4000000
#define BB 1024
#define DIM 32
#define FXDIM 55
#define EMBD 128
#define VOCAB 26
#define LL 1000
#define NF 32
#define KK 8
#define CF 3872   // 32*121

// ---------------- CSR build ----------------
__global__ void k_count(const int* __restrict__ dst, int* __restrict__ deg) {
    int e = blockIdx.x * blockDim.x + threadIdx.x;
    if (e < EE) atomicAdd(&deg[dst[e]], 1);
}

__global__ void k_scan1(const int* __restrict__ deg, int* __restrict__ rowptr, int* __restrict__ bsum) {
    __shared__ int sh[256];
    int t = threadIdx.x;
    size_t base = (size_t)blockIdx.x * 1024 + (size_t)t * 4;
    int v[4];
#pragma unroll
    for (int j = 0; j < 4; ++j) v[j] = (base + j < NN) ? deg[base + j] : 0;
    int tsum = v[0] + v[1] + v[2] + v[3];
    sh[t] = tsum;
    __syncthreads();
    for (int off = 1; off < 256; off <<= 1) {
        int add = (t >= off) ? sh[t - off] : 0;
        __syncthreads();
        sh[t] += add;
        __syncthreads();
    }
    int run = sh[t] - tsum;  // exclusive prefix
#pragma unroll
    for (int j = 0; j < 4; ++j) {
        if (base + j < NN) rowptr[base + j] = run;
        run += v[j];
    }
    if (t == 255) bsum[blockIdx.x] = sh[255];
}

__global__ void k_scan2(int* __restrict__ bs, int nb) {
    __shared__ int sh[1024];
    int t = threadIdx.x;
    int v = (t < nb) ? bs[t] : 0;
    sh[t] = v;
    __syncthreads();
    for (int off = 1; off < 1024; off <<= 1) {
        int add = (t >= off) ? sh[t - off] : 0;
        __syncthreads();
        sh[t] += add;
        __syncthreads();
    }
    if (t < nb) bs[t] = sh[t] - v;  // exclusive
}

__global__ void k_scan3(int* __restrict__ rowptr, const int* __restrict__ bs) {
    size_t base = (size_t)blockIdx.x * 1024 + (size_t)threadIdx.x * 4;
    int off = bs[blockIdx.x];
#pragma unroll
    for (int j = 0; j < 4; ++j)
        if (base + j < NN) rowptr[base + j] += off;
    if (blockIdx.x == 0 && threadIdx.x == 0) rowptr[NN] = EE;
}

__global__ void k_copy(int* __restrict__ f, const int* __restrict__ r) {
    int i = blockIdx.x * blockDim.x + threadIdx.x;
    if (i < NN) f[i] = r[i];
}

__global__ void k_fill(const int* __restrict__ src, const int* __restrict__ dst,
                       int* __restrict__ fill, int* __restrict__ col) {
    int e = blockIdx.x * blockDim.x + threadIdx.x;
    if (e < EE) {
        int d = dst[e];
        int pos = atomicAdd(&fill[d], 1);
        col[pos] = src[e];
    }
}

// ---------------- layer-1 projection p = xd @ w1 ----------------
__global__ __launch_bounds__(256) void k_p1(const float* __restrict__ xd,
                                            const float* __restrict__ w1,
                                            float* __restrict__ out) {
    int lane = threadIdx.x & 31;
    float wc[FXDIM];
#pragma unroll
    for (int k = 0; k < FXDIM; ++k) wc[k] = w1[k * 32 + lane];
    int gid = (blockIdx.x * blockDim.x + threadIdx.x) >> 5;
    int ng = (gridDim.x * blockDim.x) >> 5;
    for (int i = gid; i < NN; i += ng) {
        const float* row = xd + (size_t)i * FXDIM;
        float x0 = row[lane];
        float x1 = (lane < FXDIM - 32) ? row[32 + lane] : 0.f;
        float acc = 0.f;
#pragma unroll
        for (int k = 0; k < 32; ++k) acc += __shfl(x0, k, 32) * wc[k];
#pragma unroll
        for (int k = 0; k < FXDIM - 32; ++k) acc += __shfl(x1, k, 32) * wc[32 + k];
        out[(size_t)i * 32 + lane] = acc;
    }
}

// ---------------- fused GIN layer: gather-agg + MLP + BN stats ----------------
// Edge loop unrolled x4 with 4 independent accumulators so 4 row-gathers are
// in flight before any waitcnt (latency-bound -> MLP-bound).
template <int FIRST>
__global__ __launch_bounds__(256) void k_gin(const float* __restrict__ hsrc,
                                             const int* __restrict__ rowptr,
                                             const int* __restrict__ colidx,
                                             const float* __restrict__ aff,
                                             const float* __restrict__ w1,
                                             const float* __restrict__ b1,
                                             const float* __restrict__ w2,
                                             const float* __restrict__ b2,
                                             float* __restrict__ hdst,
                                             float* __restrict__ partial) {
    const int lane = threadIdx.x & 31;
    float w1c[32], w2c[32];
    if (!FIRST) {
#pragma unroll
        for (int k = 0; k < 32; ++k) w1c[k] = w1[k * 32 + lane];
    }
#pragma unroll
    for (int k = 0; k < 32; ++k) w2c[k] = w2[k * 32 + lane];
    float b1v = b1[lane], b2v = b2[lane];
    float sA = 1.f, tA = 0.f;
    if (!FIRST) { sA = aff[lane]; tA = aff[32 + lane]; }

    float psum = 0.f, psq = 0.f;
    int gid = (blockIdx.x * blockDim.x + threadIdx.x) >> 5;
    int ng = (gridDim.x * blockDim.x) >> 5;
    for (int i = gid; i < NN; i += ng) {
        int r0 = rowptr[i], r1 = rowptr[i + 1];
        float a0 = hsrc[(size_t)i * 32 + lane];
        float a1 = 0.f, a2 = 0.f, a3 = 0.f;
        int e = r0;
        for (; e + 4 <= r1; e += 4) {
            int s0 = colidx[e];
            int s1 = colidx[e + 1];
            int s2 = colidx[e + 2];
            int s3 = colidx[e + 3];
            float v0 = hsrc[(size_t)s0 * 32 + lane];
            float v1 = hsrc[(size_t)s1 * 32 + lane];
            float v2 = hsrc[(size_t)s2 * 32 + lane];
            float v3 = hsrc[(size_t)s3 * 32 + lane];
            a0 += v0; a1 += v1; a2 += v2; a3 += v3;
        }
        if (e + 2 <= r1) {
            int s0 = colidx[e];
            int s1 = colidx[e + 1];
            float v0 = hsrc[(size_t)s0 * 32 + lane];
            float v1 = hsrc[(size_t)s1 * 32 + lane];
            a1 += v0; a2 += v1;
            e += 2;
        }
        if (e < r1) a3 += hsrc[(size_t)colidx[e] * 32 + lane];
        float acc = (a0 + a1) + (a2 + a3);
        float z;
        if (FIRST) {
            z = fmaxf(acc + b1v, 0.f);
        } else {
            float u = sA * acc + (float)(r1 - r0 + 1) * tA;
            float a1m = b1v;
#pragma unroll
            for (int k = 0; k < 32; ++k) a1m += __shfl(u, k, 32) * w1c[k];
            z = fmaxf(a1m, 0.f);
        }
        float a2m = b2v;
#pragma unroll
        for (int k = 0; k < 32; ++k) a2m += __shfl(z, k, 32) * w2c[k];
        float h = fmaxf(a2m, 0.f);
        hdst[(size_t)i * 32 + lane] = h;
        psum += h;
        psq += h * h;
    }
    __shared__ float red[8][64];
    int wid = threadIdx.x >> 5;
    red[wid][lane] = psum;
    red[wid][32 + lane] = psq;
    __syncthreads();
    if (threadIdx.x < 64) {
        float s = 0.f;
#pragma unroll
        for (int w = 0; w < 8; ++w) s += red[w][threadIdx.x];
        partial[(size_t)blockIdx.x * 64 + threadIdx.x] = s;
    }
}

// ---------------- finalize BN stats -> affine s,t (parallel: 1 block/channel) ----------------
__global__ __launch_bounds__(256) void k_reduce(const float* __restrict__ partial, int nblocks,
                                                const float* __restrict__ g, const float* __restrict__ bt,
                                                float* __restrict__ aff) {
    int c = blockIdx.x;   // channel 0..31
    int t = threadIdx.x;
    double s = 0.0, q = 0.0;
    for (int b = t; b < nblocks; b += 256) {
        s += (double)partial[(size_t)b * 64 + c];
        q += (double)partial[(size_t)b * 64 + 32 + c];
    }
    __shared__ double shs[256], shq[256];
    shs[t] = s; shq[t] = q;
    __syncthreads();
    for (int off = 128; off; off >>= 1) {
        if (t < off) { shs[t] += shs[t + off]; shq[t] += shq[t + off]; }
        __syncthreads();
    }
    if (t == 0) {
        double mean = shs[0] / (double)NN;
        double var = shq[0] / (double)NN - mean * mean;
        float r = (float)rsqrt(var + 1e-5);
        float sv = g[c] * r;
        aff[c] = sv;
        aff[32 + c] = bt[c] - (float)mean * sv;
    }
}

// ---------------- pooling (xd_batch sorted -> run-length + atomics) ----------------
__global__ __launch_bounds__(256) void k_pool(const float* __restrict__ h,
                                              const int* __restrict__ batch,
                                              float* __restrict__ ps) {
    int lane = threadIdx.x & 31;
    int g = threadIdx.x >> 5;
    const int chunk = (NN + gridDim.x - 1) / gridDim.x;
    int s0 = blockIdx.x * chunk;
    int s1 = min(NN, s0 + chunk);
    int curb = -1;
    float acc = 0.f;
    for (int i = s0 + g; i < s1; i += 8) {
        int b = batch[i];
        if (b != curb) {
            if (curb >= 0) atomicAdd(&ps[curb * 32 + lane], acc);
            acc = 0.f;
            curb = b;
        }
        acc += h[(size_t)i * 32 + lane];
    }
    if (curb >= 0) atomicAdd(&ps[curb * 32 + lane], acc);
}

__device__ int lowerb(const int* a, int n, int key) {
    int lo = 0, hi = n;
    while (lo < hi) {
        int m = (lo + hi) >> 1;
        if (a[m] < key) lo = m + 1;
        else hi = m;
    }
    return lo;
}

__global__ void k_counts(const int* __restrict__ batch, int* __restrict__ cnt) {
    int b = blockIdx.x * blockDim.x + threadIdx.x;
    if (b < BB) cnt[b] = lowerb(batch, NN, b + 1) - lowerb(batch, NN, b);
}

// ---------------- xdv = ReLU(pooled' @ fcd_w + fcd_b) ----------------
__global__ __launch_bounds__(128) void k_xdv(const float* __restrict__ ps,
                                             const int* __restrict__ cnt,
                                             const float* __restrict__ aff,
                                             const float* __restrict__ w,
                                             const float* __restrict__ bb,
                                             float* __restrict__ xdv) {
    int b = blockIdx.x;
    int j = threadIdx.x;
    __shared__ float p[32];
    if (j < 32) p[j] = aff[j] * ps[b * 32 + j] + (float)cnt[b] * aff[32 + j];
    __syncthreads();
    float acc = bb[j];
#pragma unroll
    for (int c = 0; c < 32; ++c) acc += p[c] * w[c * 128 + j];
    xdv[b * 128 + j] = fmaxf(acc, 0.f);
}

// ---------------- conv branch ----------------
__global__ void k_kT(const float* __restrict__ ck, float* __restrict__ kT) {
    int i = blockIdx.x;
    int t = threadIdx.x;
    int o = t >> 3, k = t & 7;
    kT[(size_t)i * 256 + t] = ck[(size_t)o * (LL * KK) + (size_t)i * KK + k];
}

__global__ __launch_bounds__(256) void k_conv(const int* __restrict__ xt,
                                              const float* __restrict__ kT,
                                              const float* __restrict__ emb,
                                              const float* __restrict__ cb,
                                              float* __restrict__ cbuf) {
    __shared__ float S[VOCAB * 256];
    __shared__ float Em[VOCAB * EMBD];
    int t = threadIdx.x;
    int b = blockIdx.x;
    for (int v = t; v < VOCAB * 256; v += 256) S[v] = 0.f;
    for (int v = t; v < VOCAB * EMBD; v += 256) Em[v] = emb[v];
    __syncthreads();
    const int* row = xt + (size_t)b * LL;
#pragma unroll 4
    for (int i = 0; i < LL; ++i) {
        int v = row[i];
        S[v * 256 + t] += kT[(size_t)i * 256 + t];
    }
    __syncthreads();
    int h = t & 127, half = t >> 7;
    if (h < 121) {
        float acc[16];
        int o0 = half * 16;
#pragma unroll
        for (int o = 0; o < 16; ++o) acc[o] = cb[o0 + o];
        for (int v = 0; v < VOCAB; ++v) {
            float e[8];
#pragma unroll
            for (int k = 0; k < 8; ++k) e[k] = Em[v * EMBD + h + k];
#pragma unroll
            for (int o = 0; o < 16; ++o) {
                float a = acc[o];
#pragma unroll
                for (int k = 0; k < 8; ++k) a += S[v * 256 + (o0 + o) * 8 + k] * e[k];
                acc[o] = a;
            }
        }
#pragma unroll
        for (int o = 0; o < 16; ++o)
            cbuf[(size_t)b * CF + (size_t)(o0 + o) * 121 + h] = acc[o];
    }
}

// ---------------- xtv = c_flat @ fct_w + fct_b ----------------
__global__ __launch_bounds__(128) void k_xtv(const float* __restrict__ c,
                                             const float* __restrict__ w,
                                             const float* __restrict__ bb,
                                             float* __restrict__ xtv) {
    int j = threadIdx.x;
    int b0 = blockIdx.x * 8;
    float acc[8];
#pragma unroll
    for (int r = 0; r < 8; ++r) acc[r] = bb[j];
    for (int f = 0; f < CF; ++f) {
        float wv = w[(size_t)f * 128 + j];
#pragma unroll
        for (int r = 0; r < 8; ++r) acc[r] += c[(size_t)(b0 + r) * CF + f] * wv;
    }
#pragma unroll
    for (int r = 0; r < 8; ++r) xtv[(b0 + r) * 128 + j] = acc[r];
}

// ---------------- classifier ----------------
__global__ __launch_bounds__(1024) void k_cls1(const float* __restrict__ xdv,
                                               const float* __restrict__ xtv,
                                               const float* __restrict__ w,
                                               const float* __restrict__ bb,
                                               float* __restrict__ h1) {
    __shared__ float X[8][256];
    int j = threadIdx.x;
    int b0 = blockIdx.x * 8;
    for (int idx = j; idx < 8 * 256; idx += 1024) {
        int r = idx >> 8, k = idx & 255;
        X[r][k] = (k < 128) ? xdv[(b0 + r) * 128 + k] : xtv[(b0 + r) * 128 + (k - 128)];
    }
    __syncthreads();
    float acc[8];
#pragma unroll
    for (int r = 0; r < 8; ++r) acc[r] = bb[j];
    for (int k = 0; k < 256; ++k) {
        float wv = w[(size_t)k * 1024 + j];
#pragma unroll
        for (int r = 0; r < 8; ++r) acc[r] += X[r][k] * wv;
    }
#pragma unroll
    for (int r = 0; r < 8; ++r) h1[(size_t)(b0 + r) * 1024 + j] = fmaxf(acc[r], 0.f);
}

__global__ __launch_bounds__(256) void k_cls2(const float* __restrict__ h1,
                                              const float* __restrict__ w,
                                              const float* __restrict__ bb,
                                              float* __restrict__ h2) {
    __shared__ float X[8][1024];
    int j = threadIdx.x;
    int b0 = blockIdx.x * 8;
    for (int idx = j; idx < 8 * 1024; idx += 256) {
        int r = idx >> 10, k = idx & 1023;
        X[r][k] = h1[(size_t)(b0 + r) * 1024 + k];
    }
    __syncthreads();
    float acc[8];
#pragma unroll
    for (int r = 0; r < 8; ++r) acc[r] = bb[j];
    for (int k = 0; k < 1024; ++k) {
        float wv = w[(size_t)k * 256 + j];
#pragma unroll
        for (int r = 0; r < 8; ++r) acc[r] += X[r][k] * wv;
    }
#pragma unroll
    for (int r = 0; r < 8; ++r) h2[(size_t)(b0 + r) * 256 + j] = fmaxf(acc[r], 0.f);
}

__global__ __launch_bounds__(256) void k_cls3(const float* __restrict__ h2,
                                              const float* __restrict__ w,
                                              const float* __restrict__ bb,
                                              const float* __restrict__ y,
                                              float* __restrict__ dout) {
    int lane = threadIdx.x & 63;
    int b = (blockIdx.x * blockDim.x + threadIdx.x) >> 6;
    if (b >= BB) return;
    float acc = 0.f;
    for (int k = lane; k < 256; k += 64) acc += h2[(size_t)b * 256 + k] * w[k];
#pragma unroll
    for (int off = 32; off; off >>= 1) acc += __shfl_xor(acc, off, 64);
    if (lane == 0) dout[b] = acc + bb[0];
    if (lane == 1) dout[BB + b] = y[b];
}

// ---------------- launch ----------------
extern "C" void kernel_launch(void* const* d_in, const int* in_sizes, int n_in,
                              void* d_out, int out_size, void* d_ws, size_t ws_size,
                              hipStream_t stream) {
    const float* xd = (const float*)d_in[0];
    const int* ei = (const int*)d_in[1];
    const int* batch = (const int*)d_in[2];
    const int* xt = (const int*)d_in[3];
    const float* y = (const float*)d_in[4];
    const float* g1w1 = (const float*)d_in[5];
    const float* g1b1 = (const float*)d_in[6];
    const float* g1w2 = (const float*)d_in[7];
    const float* g1b2 = (const float*)d_in[8];
    const float* grw1 = (const float*)d_in[9];
    const float* grb1 = (const float*)d_in[10];
    const float* grw2 = (const float*)d_in[11];
    const float* grb2 = (const float*)d_in[12];
    const float* bng = (const float*)d_in[13];
    const float* bnb = (const float*)d_in[14];
    const float* fcdw = (const float*)d_in[15];
    const float* fcdb = (const float*)d_in[16];
    const float* emb = (const float*)d_in[17];
    const float* convk = (const float*)d_in[18];
    const float* convb = (const float*)d_in[19];
    const float* fctw = (const float*)d_in[20];
    const float* fctb = (const float*)d_in[21];
    const float* cw1 = (const float*)d_in[22];
    const float* cb1 = (const float*)d_in[23];
    const float* cw2 = (const float*)d_in[24];
    const float* cb2 = (const float*)d_in[25];
    const float* cw3 = (const float*)d_in[26];
    const float* cb3 = (const float*)d_in[27];

    const int* src = ei;
    const int* dst = ei + EE;

    size_t off = 0;
    auto alloc = [&](size_t bytes) {
        size_t o = off;
        off = (off + bytes + 255) & ~(size_t)255;
        return o;
    };
    char* ws = (char*)d_ws;
    size_t o_deg = alloc(4ull * NN);
    size_t o_rp = alloc(4ull * (NN + 1));
    size_t o_fill = alloc(4ull * NN);
    size_t o_col = alloc(4ull * EE);
    size_t o_bsum = alloc(4ull * 1024);
    size_t o_ha = alloc(4ull * NN * 32);
    size_t o_hb = alloc(4ull * NN * 32);
    size_t o_part = alloc(4ull * 2048 * 64);
    size_t o_aff = alloc(4ull * 64);
    size_t o_ps = alloc(4ull * BB * 32);
    size_t o_cnt = alloc(4ull * BB);
    size_t o_xdv = alloc(4ull * BB * 128);
    size_t o_kT = alloc(4ull * LL * 256);
    size_t o_c = alloc(4ull * BB * CF);
    size_t o_xtv = alloc(4ull * BB * 128);
    size_t o_h1 = alloc(4ull * BB * 1024);
    size_t o_h2 = alloc(4ull * BB * 256);

    int* deg = (int*)(ws + o_deg);
    int* rp = (int*)(ws + o_rp);
    int* fill = (int*)(ws + o_fill);
    int* col = (int*)(ws + o_col);
    int* bsum = (int*)(ws + o_bsum);
    float* ha = (float*)(ws + o_ha);
    float* hb = (float*)(ws + o_hb);
    float* part = (float*)(ws + o_part);
    float* aff = (float*)(ws + o_aff);
    float* ps = (float*)(ws + o_ps);
    int* cnt = (int*)(ws + o_cnt);
    float* xdv = (float*)(ws + o_xdv);
    float* kT = (float*)(ws + o_kT);
    float* cbuf = (float*)(ws + o_c);
    float* xtv = (float*)(ws + o_xtv);
    float* h1 = (float*)(ws + o_h1);
    float* h2 = (float*)(ws + o_h2);
    float* dout = (float*)d_out;

    // --- CSR build ---
    hipMemsetAsync(deg, 0, 4ull * NN, stream);
    k_count<<<EE / 256, 256, 0, stream>>>(dst, deg);
    k_scan1<<<977, 256, 0, stream>>>(deg, rp, bsum);
    k_scan2<<<1, 1024, 0, stream>>>(bsum, 977);
    k_scan3<<<977, 256, 0, stream>>>(rp, bsum);
    k_copy<<<(NN + 255) / 256, 256, 0, stream>>>(fill, rp);
    k_fill<<<EE / 256, 256, 0, stream>>>(src, dst, fill, col);

    // --- GIN layers ---
    k_p1<<<2048, 256, 0, stream>>>(xd, g1w1, ha);
    k_gin<1><<<2048, 256, 0, stream>>>(ha, rp, col, aff, g1w1, g1b1, g1w2, g1b2, hb, part);
    k_reduce<<<32, 256, 0, stream>>>(part, 2048, bng, bnb, aff);
    const float* srcbuf = hb;
    float* dstbuf = ha;
    for (int i = 0; i < 4; ++i) {
        k_gin<0><<<2048, 256, 0, stream>>>(srcbuf, rp, col, aff,
                                           grw1 + (size_t)i * 1024, grb1 + (size_t)i * 32,
                                           grw2 + (size_t)i * 1024, grb2 + (size_t)i * 32,
                                           dstbuf, part);
        k_reduce<<<32, 256, 0, stream>>>(part, 2048, bng + (i + 1) * 32, bnb + (i + 1) * 32, aff);
        const float* tmp = srcbuf;
        srcbuf = dstbuf;
        dstbuf = (float*)tmp;
    }
    // after loop: srcbuf == hb (layer-5 output), aff == layer-5 affine

    // --- pooling + xdv ---
    hipMemsetAsync(ps, 0, 4ull * BB * 32, stream);
    k_pool<<<1024, 256, 0, stream>>>(srcbuf, batch, ps);
    k_counts<<<4, 256, 0, stream>>>(batch, cnt);
    k_xdv<<<BB, 128, 0, stream>>>(ps, cnt, aff, fcdw, fcdb, xdv);

    // --- conv branch ---
    k_kT<<<LL, 256, 0, stream>>>(convk, kT);
    k_conv<<<BB, 256, 0, stream>>>(xt, kT, emb, convb, cbuf);
    k_xtv<<<BB / 8, 128, 0, stream>>>(cbuf, fctw, fctb, xtv);

    // --- classifier ---
    k_cls1<<<BB / 8, 1024, 0, stream>>>(xdv, xtv, cw1, cb1, h1);
    k_cls2<<<BB / 8, 256, 0, stream>>>(h1, cw2, cb2, h2);
    k_cls3<<<256, 256, 0, stream>>>(h2, cw3, cb3, y, dout);
}

// Round 3
// 2912.788 us; speedup vs baseline: 1.6381x; 1.3321x over previous
//
#include <hip/hip_runtime.h>
#include <hip/hip_bf16.h>
#include <hip/hip_fp16.h>

#define NN 1000000
#define EE 4000000
#define BB 1024
#define DIM 32
#define FXDIM 55
#define EMBD 128
#define VOCAB 26
#define LL 1000
#define NF 32
#define KK 8
#define CF 3872   // 32*121

typedef _Float16 h2_t __attribute__((ext_vector_type(2)));

__device__ inline float fdot2u(unsigned a, unsigned b, float c) {
#if defined(__has_builtin) && __has_builtin(__builtin_amdgcn_fdot2)
    h2_t ha = __builtin_bit_cast(h2_t, a);
    h2_t hb = __builtin_bit_cast(h2_t, b);
    return __builtin_amdgcn_fdot2(ha, hb, c, false);
#else
    __half2 ha = __builtin_bit_cast(__half2, a);
    __half2 hb = __builtin_bit_cast(__half2, b);
    return fmaf(__low2float(ha), __low2float(hb),
                fmaf(__high2float(ha), __high2float(hb), c));
#endif
}

// every lane ends up holding packed f16 pair (v[2*(lane>>1)], v[2*(lane>>1)+1])
__device__ inline unsigned packpair(float v, int lane) {
    float o = __shfl_xor(v, 1, 32);
    float lo = (lane & 1) ? o : v;
    float hi = (lane & 1) ? v : o;
    __half2 p = __floats2half2_rn(lo, hi);
    return __builtin_bit_cast(unsigned, p);
}

// ---------------- CSR build ----------------
__global__ void k_count(const int* __restrict__ dst, int* __restrict__ deg) {
    int e = blockIdx.x * blockDim.x + threadIdx.x;
    if (e < EE) atomicAdd(&deg[dst[e]], 1);
}

__global__ void k_scan1(const int* __restrict__ deg, int* __restrict__ rowptr, int* __restrict__ bsum) {
    __shared__ int sh[256];
    int t = threadIdx.x;
    size_t base = (size_t)blockIdx.x * 1024 + (size_t)t * 4;
    int v[4];
#pragma unroll
    for (int j = 0; j < 4; ++j) v[j] = (base + j < NN) ? deg[base + j] : 0;
    int tsum = v[0] + v[1] + v[2] + v[3];
    sh[t] = tsum;
    __syncthreads();
    for (int off = 1; off < 256; off <<= 1) {
        int add = (t >= off) ? sh[t - off] : 0;
        __syncthreads();
        sh[t] += add;
        __syncthreads();
    }
    int run = sh[t] - tsum;  // exclusive prefix
#pragma unroll
    for (int j = 0; j < 4; ++j) {
        if (base + j < NN) rowptr[base + j] = run;
        run += v[j];
    }
    if (t == 255) bsum[blockIdx.x] = sh[255];
}

__global__ void k_scan2(int* __restrict__ bs, int nb) {
    __shared__ int sh[1024];
    int t = threadIdx.x;
    int v = (t < nb) ? bs[t] : 0;
    sh[t] = v;
    __syncthreads();
    for (int off = 1; off < 1024; off <<= 1) {
        int add = (t >= off) ? sh[t - off] : 0;
        __syncthreads();
        sh[t] += add;
        __syncthreads();
    }
    if (t < nb) bs[t] = sh[t] - v;  // exclusive
}

__global__ void k_scan3(int* __restrict__ rowptr, const int* __restrict__ bs) {
    size_t base = (size_t)blockIdx.x * 1024 + (size_t)threadIdx.x * 4;
    int off = bs[blockIdx.x];
#pragma unroll
    for (int j = 0; j < 4; ++j)
        if (base + j < NN) rowptr[base + j] += off;
    if (blockIdx.x == 0 && threadIdx.x == 0) rowptr[NN] = EE;
}

__global__ void k_copy(int* __restrict__ f, const int* __restrict__ r) {
    int i = blockIdx.x * blockDim.x + threadIdx.x;
    if (i < NN) f[i] = r[i];
}

__global__ void k_fill(const int* __restrict__ src, const int* __restrict__ dst,
                       int* __restrict__ fill, int* __restrict__ col) {
    int e = blockIdx.x * blockDim.x + threadIdx.x;
    if (e < EE) {
        int d = dst[e];
        int pos = atomicAdd(&fill[d], 1);
        col[pos] = src[e];
    }
}

// ---------------- layer-1 projection p = xd @ w1 (fp32 compute, f16 store) ----------------
__global__ __launch_bounds__(256) void k_p1(const float* __restrict__ xd,
                                            const float* __restrict__ w1,
                                            __half* __restrict__ out) {
    int lane = threadIdx.x & 31;
    float wc[FXDIM];
#pragma unroll
    for (int k = 0; k < FXDIM; ++k) wc[k] = w1[k * 32 + lane];
    int gid = (blockIdx.x * blockDim.x + threadIdx.x) >> 5;
    int ng = (gridDim.x * blockDim.x) >> 5;
    for (int i = gid; i < NN; i += ng) {
        const float* row = xd + (size_t)i * FXDIM;
        float x0 = row[lane];
        float x1 = (lane < FXDIM - 32) ? row[32 + lane] : 0.f;
        float acc = 0.f;
#pragma unroll
        for (int k = 0; k < 32; ++k) acc += __shfl(x0, k, 32) * wc[k];
#pragma unroll
        for (int k = 0; k < FXDIM - 32; ++k) acc += __shfl(x1, k, 32) * wc[32 + k];
        out[(size_t)i * 32 + lane] = __float2half_rn(acc);
    }
}

// ---------------- aggregation: agg[i] = h[i] + sum_{j->i} h[j]  (f16 rows, 64B) ----------------
// 16 lanes per node, each lane handles 2 channels via __half2. Minimal VGPR -> max waves.
__global__ __launch_bounds__(256) void k_agg(const __half2* __restrict__ hsrc,
                                             const int* __restrict__ rowptr,
                                             const int* __restrict__ colidx,
                                             __half2* __restrict__ agg) {
    int l = threadIdx.x & 15;
    int gid = (blockIdx.x * blockDim.x + threadIdx.x) >> 4;
    int ng = (gridDim.x * blockDim.x) >> 4;
    for (int i = gid; i < NN; i += ng) {
        int r0 = rowptr[i], r1 = rowptr[i + 1];
        __half2 s = hsrc[(size_t)i * 16 + l];
        float ax0 = __low2float(s), ay0 = __high2float(s);
        float ax1 = 0.f, ay1 = 0.f, ax2 = 0.f, ay2 = 0.f, ax3 = 0.f, ay3 = 0.f;
        int e = r0;
        for (; e + 4 <= r1; e += 4) {
            int s0 = colidx[e], s1 = colidx[e + 1], s2 = colidx[e + 2], s3 = colidx[e + 3];
            __half2 v0 = hsrc[(size_t)s0 * 16 + l];
            __half2 v1 = hsrc[(size_t)s1 * 16 + l];
            __half2 v2 = hsrc[(size_t)s2 * 16 + l];
            __half2 v3 = hsrc[(size_t)s3 * 16 + l];
            ax0 += __low2float(v0); ay0 += __high2float(v0);
            ax1 += __low2float(v1); ay1 += __high2float(v1);
            ax2 += __low2float(v2); ay2 += __high2float(v2);
            ax3 += __low2float(v3); ay3 += __high2float(v3);
        }
        if (e + 2 <= r1) {
            int s0 = colidx[e], s1 = colidx[e + 1];
            __half2 v0 = hsrc[(size_t)s0 * 16 + l];
            __half2 v1 = hsrc[(size_t)s1 * 16 + l];
            ax1 += __low2float(v0); ay1 += __high2float(v0);
            ax2 += __low2float(v1); ay2 += __high2float(v1);
            e += 2;
        }
        if (e < r1) {
            __half2 v0 = hsrc[(size_t)colidx[e] * 16 + l];
            ax3 += __low2float(v0); ay3 += __high2float(v0);
        }
        float sx = (ax0 + ax1) + (ax2 + ax3);
        float sy = (ay0 + ay1) + (ay2 + ay3);
        agg[(size_t)i * 16 + l] = __floats2half2_rn(sx, sy);
    }
}

// ---------------- MLP + BN-stat kernel (streaming, dot2-f16) ----------------
template <int FIRST>
__global__ __launch_bounds__(256) void k_mlp(const __half* __restrict__ agg,
                                             const int* __restrict__ rowptr,
                                             const float* __restrict__ aff,
                                             const float* __restrict__ w1,
                                             const float* __restrict__ b1,
                                             const float* __restrict__ w2,
                                             const float* __restrict__ b2,
                                             __half* __restrict__ hdst,
                                             float* __restrict__ partial) {
    const int lane = threadIdx.x & 31;
    unsigned wp1[16], wp2[16];
    if (!FIRST) {
#pragma unroll
        for (int kp = 0; kp < 16; ++kp) {
            __half2 p = __floats2half2_rn(w1[(2 * kp) * 32 + lane], w1[(2 * kp + 1) * 32 + lane]);
            wp1[kp] = __builtin_bit_cast(unsigned, p);
        }
    }
#pragma unroll
    for (int kp = 0; kp < 16; ++kp) {
        __half2 p = __floats2half2_rn(w2[(2 * kp) * 32 + lane], w2[(2 * kp + 1) * 32 + lane]);
        wp2[kp] = __builtin_bit_cast(unsigned, p);
    }
    float b1v = b1[lane], b2v = b2[lane];
    float sA = 1.f, tA = 0.f;
    if (!FIRST) { sA = aff[lane]; tA = aff[32 + lane]; }

    float psum = 0.f, psq = 0.f;
    int gid = (blockIdx.x * blockDim.x + threadIdx.x) >> 5;
    int ng = (gridDim.x * blockDim.x) >> 5;
    for (int i = gid; i < NN; i += ng) {
        float u = __half2float(agg[(size_t)i * 32 + lane]);
        float z;
        if (FIRST) {
            z = fmaxf(u + b1v, 0.f);
        } else {
            int d = rowptr[i + 1] - rowptr[i];
            u = sA * u + (float)(d + 1) * tA;
            unsigned pu = packpair(u, lane);
            float a = b1v;
#pragma unroll
            for (int kp = 0; kp < 16; ++kp)
                a = fdot2u(__shfl(pu, 2 * kp, 32), wp1[kp], a);
            z = fmaxf(a, 0.f);
        }
        unsigned pz = packpair(z, lane);
        float a2 = b2v;
#pragma unroll
        for (int kp = 0; kp < 16; ++kp)
            a2 = fdot2u(__shfl(pz, 2 * kp, 32), wp2[kp], a2);
        float hv = fmaxf(a2, 0.f);
        hdst[(size_t)i * 32 + lane] = __float2half_rn(hv);
        psum += hv;
        psq += hv * hv;
    }
    __shared__ float red[8][64];
    int wid = threadIdx.x >> 5;
    red[wid][lane] = psum;
    red[wid][32 + lane] = psq;
    __syncthreads();
    if (threadIdx.x < 64) {
        float s = 0.f;
#pragma unroll
        for (int w = 0; w < 8; ++w) s += red[w][threadIdx.x];
        partial[(size_t)blockIdx.x * 64 + threadIdx.x] = s;
    }
}

// ---------------- finalize BN stats -> affine s,t (1 block/channel) ----------------
__global__ __launch_bounds__(256) void k_reduce(const float* __restrict__ partial, int nblocks,
                                                const float* __restrict__ g, const float* __restrict__ bt,
                                                float* __restrict__ aff) {
    int c = blockIdx.x;   // channel 0..31
    int t = threadIdx.x;
    double s = 0.0, q = 0.0;
    for (int b = t; b < nblocks; b += 256) {
        s += (double)partial[(size_t)b * 64 + c];
        q += (double)partial[(size_t)b * 64 + 32 + c];
    }
    __shared__ double shs[256], shq[256];
    shs[t] = s; shq[t] = q;
    __syncthreads();
    for (int off = 128; off; off >>= 1) {
        if (t < off) { shs[t] += shs[t + off]; shq[t] += shq[t + off]; }
        __syncthreads();
    }
    if (t == 0) {
        double mean = shs[0] / (double)NN;
        double var = shq[0] / (double)NN - mean * mean;
        float r = (float)rsqrt(var + 1e-5);
        float sv = g[c] * r;
        aff[c] = sv;
        aff[32 + c] = bt[c] - (float)mean * sv;
    }
}

// ---------------- pooling (xd_batch sorted -> run-length + atomics) ----------------
__global__ __launch_bounds__(256) void k_pool(const __half* __restrict__ h,
                                              const int* __restrict__ batch,
                                              float* __restrict__ ps) {
    int lane = threadIdx.x & 31;
    int g = threadIdx.x >> 5;
    const int chunk = (NN + gridDim.x - 1) / gridDim.x;
    int s0 = blockIdx.x * chunk;
    int s1 = min(NN, s0 + chunk);
    int curb = -1;
    float acc = 0.f;
    for (int i = s0 + g; i < s1; i += 8) {
        int b = batch[i];
        if (b != curb) {
            if (curb >= 0) atomicAdd(&ps[curb * 32 + lane], acc);
            acc = 0.f;
            curb = b;
        }
        acc += __half2float(h[(size_t)i * 32 + lane]);
    }
    if (curb >= 0) atomicAdd(&ps[curb * 32 + lane], acc);
}

__device__ int lowerb(const int* a, int n, int key) {
    int lo = 0, hi = n;
    while (lo < hi) {
        int m = (lo + hi) >> 1;
        if (a[m] < key) lo = m + 1;
        else hi = m;
    }
    return lo;
}

__global__ void k_counts(const int* __restrict__ batch, int* __restrict__ cnt) {
    int b = blockIdx.x * blockDim.x + threadIdx.x;
    if (b < BB) cnt[b] = lowerb(batch, NN, b + 1) - lowerb(batch, NN, b);
}

// ---------------- xdv = ReLU(pooled' @ fcd_w + fcd_b) ----------------
__global__ __launch_bounds__(128) void k_xdv(const float* __restrict__ ps,
                                             const int* __restrict__ cnt,
                                             const float* __restrict__ aff,
                                             const float* __restrict__ w,
                                             const float* __restrict__ bb,
                                             float* __restrict__ xdv) {
    int b = blockIdx.x;
    int j = threadIdx.x;
    __shared__ float p[32];
    if (j < 32) p[j] = aff[j] * ps[b * 32 + j] + (float)cnt[b] * aff[32 + j];
    __syncthreads();
    float acc = bb[j];
#pragma unroll
    for (int c = 0; c < 32; ++c) acc += p[c] * w[c * 128 + j];
    xdv[b * 128 + j] = fmaxf(acc, 0.f);
}

// ---------------- conv branch ----------------
__global__ void k_kT(const float* __restrict__ ck, float* __restrict__ kT) {
    int i = blockIdx.x;
    int t = threadIdx.x;
    int o = t >> 3, k = t & 7;
    kT[(size_t)i * 256 + t] = ck[(size_t)o * (LL * KK) + (size_t)i * KK + k];
}

__global__ __launch_bounds__(256) void k_conv(const int* __restrict__ xt,
                                              const float* __restrict__ kT,
                                              const float* __restrict__ emb,
                                              const float* __restrict__ cb,
                                              float* __restrict__ cbuf) {
    __shared__ float S[VOCAB * 256];
    __shared__ float Em[VOCAB * EMBD];
    int t = threadIdx.x;
    int b = blockIdx.x;
    for (int v = t; v < VOCAB * 256; v += 256) S[v] = 0.f;
    for (int v = t; v < VOCAB * EMBD; v += 256) Em[v] = emb[v];
    __syncthreads();
    const int* row = xt + (size_t)b * LL;
#pragma unroll 4
    for (int i = 0; i < LL; ++i) {
        int v = row[i];
        S[v * 256 + t] += kT[(size_t)i * 256 + t];
    }
    __syncthreads();
    int h = t & 127, half = t >> 7;
    if (h < 121) {
        float acc[16];
        int o0 = half * 16;
#pragma unroll
        for (int o = 0; o < 16; ++o) acc[o] = cb[o0 + o];
        for (int v = 0; v < VOCAB; ++v) {
            float e[8];
#pragma unroll
            for (int k = 0; k < 8; ++k) e[k] = Em[v * EMBD + h + k];
#pragma unroll
            for (int o = 0; o < 16; ++o) {
                float a = acc[o];
#pragma unroll
                for (int k = 0; k < 8; ++k) a += S[v * 256 + (o0 + o) * 8 + k] * e[k];
                acc[o] = a;
            }
        }
#pragma unroll
        for (int o = 0; o < 16; ++o)
            cbuf[(size_t)b * CF + (size_t)(o0 + o) * 121 + h] = acc[o];
    }
}

// ---------------- xtv = c_flat @ fct_w + fct_b ----------------
__global__ __launch_bounds__(128) void k_xtv(const float* __restrict__ c,
                                             const float* __restrict__ w,
                                             const float* __restrict__ bb,
                                             float* __restrict__ xtv) {
    int j = threadIdx.x;
    int b0 = blockIdx.x * 8;
    float acc[8];
#pragma unroll
    for (int r = 0; r < 8; ++r) acc[r] = bb[j];
    for (int f = 0; f < CF; ++f) {
        float wv = w[(size_t)f * 128 + j];
#pragma unroll
        for (int r = 0; r < 8; ++r) acc[r] += c[(size_t)(b0 + r) * CF + f] * wv;
    }
#pragma unroll
    for (int r = 0; r < 8; ++r) xtv[(b0 + r) * 128 + j] = acc[r];
}

// ---------------- classifier ----------------
__global__ __launch_bounds__(1024) void k_cls1(const float* __restrict__ xdv,
                                               const float* __restrict__ xtv,
                                               const float* __restrict__ w,
                                               const float* __restrict__ bb,
                                               float* __restrict__ h1) {
    __shared__ float X[8][256];
    int j = threadIdx.x;
    int b0 = blockIdx.x * 8;
    for (int idx = j; idx < 8 * 256; idx += 1024) {
        int r = idx >> 8, k = idx & 255;
        X[r][k] = (k < 128) ? xdv[(b0 + r) * 128 + k] : xtv[(b0 + r) * 128 + (k - 128)];
    }
    __syncthreads();
    float acc[8];
#pragma unroll
    for (int r = 0; r < 8; ++r) acc[r] = bb[j];
    for (int k = 0; k < 256; ++k) {
        float wv = w[(size_t)k * 1024 + j];
#pragma unroll
        for (int r = 0; r < 8; ++r) acc[r] += X[r][k] * wv;
    }
#pragma unroll
    for (int r = 0; r < 8; ++r) h1[(size_t)(b0 + r) * 1024 + j] = fmaxf(acc[r], 0.f);
}

__global__ __launch_bounds__(256) void k_cls2(const float* __restrict__ h1,
                                              const float* __restrict__ w,
                                              const float* __restrict__ bb,
                                              float* __restrict__ h2) {
    __shared__ float X[8][1024];
    int j = threadIdx.x;
    int b0 = blockIdx.x * 8;
    for (int idx = j; idx < 8 * 1024; idx += 256) {
        int r = idx >> 10, k = idx & 1023;
        X[r][k] = h1[(size_t)(b0 + r) * 1024 + k];
    }
    __syncthreads();
    float acc[8];
#pragma unroll
    for (int r = 0; r < 8; ++r) acc[r] = bb[j];
    for (int k = 0; k < 1024; ++k) {
        float wv = w[(size_t)k * 256 + j];
#pragma unroll
        for (int r = 0; r < 8; ++r) acc[r] += X[r][k] * wv;
    }
#pragma unroll
    for (int r = 0; r < 8; ++r) h2[(size_t)(b0 + r) * 256 + j] = fmaxf(acc[r], 0.f);
}

__global__ __launch_bounds__(256) void k_cls3(const float* __restrict__ h2,
                                              const float* __restrict__ w,
                                              const float* __restrict__ bb,
                                              const float* __restrict__ y,
                                              float* __restrict__ dout) {
    int lane = threadIdx.x & 63;
    int b = (blockIdx.x * blockDim.x + threadIdx.x) >> 6;
    if (b >= BB) return;
    float acc = 0.f;
    for (int k = lane; k < 256; k += 64) acc += h2[(size_t)b * 256 + k] * w[k];
#pragma unroll
    for (int off = 32; off; off >>= 1) acc += __shfl_xor(acc, off, 64);
    if (lane == 0) dout[b] = acc + bb[0];
    if (lane == 1) dout[BB + b] = y[b];
}

// ---------------- launch ----------------
extern "C" void kernel_launch(void* const* d_in, const int* in_sizes, int n_in,
                              void* d_out, int out_size, void* d_ws, size_t ws_size,
                              hipStream_t stream) {
    const float* xd = (const float*)d_in[0];
    const int* ei = (const int*)d_in[1];
    const int* batch = (const int*)d_in[2];
    const int* xt = (const int*)d_in[3];
    const float* y = (const float*)d_in[4];
    const float* g1w1 = (const float*)d_in[5];
    const float* g1b1 = (const float*)d_in[6];
    const float* g1w2 = (const float*)d_in[7];
    const float* g1b2 = (const float*)d_in[8];
    const float* grw1 = (const float*)d_in[9];
    const float* grb1 = (const float*)d_in[10];
    const float* grw2 = (const float*)d_in[11];
    const float* grb2 = (const float*)d_in[12];
    const float* bng = (const float*)d_in[13];
    const float* bnb = (const float*)d_in[14];
    const float* fcdw = (const float*)d_in[15];
    const float* fcdb = (const float*)d_in[16];
    const float* emb = (const float*)d_in[17];
    const float* convk = (const float*)d_in[18];
    const float* convb = (const float*)d_in[19];
    const float* fctw = (const float*)d_in[20];
    const float* fctb = (const float*)d_in[21];
    const float* cw1 = (const float*)d_in[22];
    const float* cb1 = (const float*)d_in[23];
    const float* cw2 = (const float*)d_in[24];
    const float* cb2 = (const float*)d_in[25];
    const float* cw3 = (const float*)d_in[26];
    const float* cb3 = (const float*)d_in[27];

    const int* src = ei;
    const int* dst = ei + EE;

    size_t off = 0;
    auto alloc = [&](size_t bytes) {
        size_t o = off;
        off = (off + bytes + 255) & ~(size_t)255;
        return o;
    };
    char* ws = (char*)d_ws;
    size_t o_deg = alloc(4ull * NN);
    size_t o_rp = alloc(4ull * (NN + 1));
    size_t o_fill = alloc(4ull * NN);
    size_t o_col = alloc(4ull * EE);
    size_t o_bsum = alloc(4ull * 1024);
    size_t o_ha = alloc(2ull * NN * 32);
    size_t o_hb = alloc(2ull * NN * 32);
    size_t o_ag = alloc(2ull * NN * 32);
    size_t o_part = alloc(4ull * 2048 * 64);
    size_t o_aff = alloc(4ull * 64);
    size_t o_ps = alloc(4ull * BB * 32);
    size_t o_cnt = alloc(4ull * BB);
    size_t o_xdv = alloc(4ull * BB * 128);
    size_t o_kT = alloc(4ull * LL * 256);
    size_t o_c = alloc(4ull * BB * CF);
    size_t o_xtv = alloc(4ull * BB * 128);
    size_t o_h1 = alloc(4ull * BB * 1024);
    size_t o_h2 = alloc(4ull * BB * 256);

    int* deg = (int*)(ws + o_deg);
    int* rp = (int*)(ws + o_rp);
    int* fill = (int*)(ws + o_fill);
    int* col = (int*)(ws + o_col);
    int* bsum = (int*)(ws + o_bsum);
    __half* ha = (__half*)(ws + o_ha);
    __half* hb = (__half*)(ws + o_hb);
    __half* ag = (__half*)(ws + o_ag);
    float* part = (float*)(ws + o_part);
    float* aff = (float*)(ws + o_aff);
    float* ps = (float*)(ws + o_ps);
    int* cnt = (int*)(ws + o_cnt);
    float* xdv = (float*)(ws + o_xdv);
    float* kT = (float*)(ws + o_kT);
    float* cbuf = (float*)(ws + o_c);
    float* xtv = (float*)(ws + o_xtv);
    float* h1 = (float*)(ws + o_h1);
    float* h2 = (float*)(ws + o_h2);
    float* dout = (float*)d_out;

    // --- CSR build ---
    hipMemsetAsync(deg, 0, 4ull * NN, stream);
    k_count<<<EE / 256, 256, 0, stream>>>(dst, deg);
    k_scan1<<<977, 256, 0, stream>>>(deg, rp, bsum);
    k_scan2<<<1, 1024, 0, stream>>>(bsum, 977);
    k_scan3<<<977, 256, 0, stream>>>(rp, bsum);
    k_copy<<<(NN + 255) / 256, 256, 0, stream>>>(fill, rp);
    k_fill<<<EE / 256, 256, 0, stream>>>(src, dst, fill, col);

    // --- GIN layers (split agg / mlp) ---
    k_p1<<<2048, 256, 0, stream>>>(xd, g1w1, ha);

    // layer 1
    k_agg<<<2048, 256, 0, stream>>>((const __half2*)ha, rp, col, (__half2*)ag);
    k_mlp<1><<<2048, 256, 0, stream>>>(ag, rp, aff, g1w1, g1b1, g1w2, g1b2, hb, part);
    k_reduce<<<32, 256, 0, stream>>>(part, 2048, bng, bnb, aff);

    const __half* srcbuf = hb;
    __half* dstbuf = ha;
    for (int i = 0; i < 4; ++i) {
        k_agg<<<2048, 256, 0, stream>>>((const __half2*)srcbuf, rp, col, (__half2*)ag);
        k_mlp<0><<<2048, 256, 0, stream>>>(ag, rp, aff,
                                           grw1 + (size_t)i * 1024, grb1 + (size_t)i * 32,
                                           grw2 + (size_t)i * 1024, grb2 + (size_t)i * 32,
                                           dstbuf, part);
        k_reduce<<<32, 256, 0, stream>>>(part, 2048, bng + (i + 1) * 32, bnb + (i + 1) * 32, aff);
        const __half* tmp = srcbuf;
        srcbuf = dstbuf;
        dstbuf = (__half*)tmp;
    }
    // after loop: srcbuf == layer-5 output, aff == layer-5 affine

    // --- pooling + xdv ---
    hipMemsetAsync(ps, 0, 4ull * BB * 32, stream);
    k_pool<<<1024, 256, 0, stream>>>(srcbuf, batch, ps);
    k_counts<<<4, 256, 0, stream>>>(batch, cnt);
    k_xdv<<<BB, 128, 0, stream>>>(ps, cnt, aff, fcdw, fcdb, xdv);

    // --- conv branch ---
    k_kT<<<LL, 256, 0, stream>>>(convk, kT);
    k_conv<<<BB, 256, 0, stream>>>(xt, kT, emb, convb, cbuf);
    k_xtv<<<BB / 8, 128, 0, stream>>>(cbuf, fctw, fctb, xtv);

    // --- classifier ---
    k_cls1<<<BB / 8, 1024, 0, stream>>>(xdv, xtv, cw1, cb1, h1);
    k_cls2<<<BB / 8, 256, 0, stream>>>(h1, cw2, cb2, h2);
    k_cls3<<<256, 256, 0, stream>>>(h2, cw3, cb3, y, dout);
}

// Round 4
// 2449.320 us; speedup vs baseline: 1.9481x; 1.1892x over previous
//
#include <hip/hip_runtime.h>
#include <hip/hip_bf16.h>
#include <hip/hip_fp16.h>

#define NN 1000000
#define EE 4000000
#define BB 1024
#define DIM 32
#define FXDIM 55
#define EMBD 128
#define VOCAB 26
#define LL 1000
#define NF 32
#define KK 8
#define CF 3872   // 32*121

typedef _Float16 h2_t __attribute__((ext_vector_type(2)));

__device__ inline float fdot2u(unsigned a, unsigned b, float c) {
#if defined(__has_builtin) && __has_builtin(__builtin_amdgcn_fdot2)
    h2_t ha = __builtin_bit_cast(h2_t, a);
    h2_t hb = __builtin_bit_cast(h2_t, b);
    return __builtin_amdgcn_fdot2(ha, hb, c, false);
#else
    __half2 ha = __builtin_bit_cast(__half2, a);
    __half2 hb = __builtin_bit_cast(__half2, b);
    return fmaf(__low2float(ha), __low2float(hb),
                fmaf(__high2float(ha), __high2float(hb), c));
#endif
}

// every lane ends up holding packed f16 pair (v[2*(lane>>1)], v[2*(lane>>1)+1])
__device__ inline unsigned packpair(float v, int lane) {
    float o = __shfl_xor(v, 1, 32);
    float lo = (lane & 1) ? o : v;
    float hi = (lane & 1) ? v : o;
    __half2 p = __floats2half2_rn(lo, hi);
    return __builtin_bit_cast(unsigned, p);
}

// ---------------- CSR build ----------------
__global__ void k_count(const int* __restrict__ dst, int* __restrict__ deg) {
    int e = blockIdx.x * blockDim.x + threadIdx.x;
    if (e < EE) atomicAdd(&deg[dst[e]], 1);
}

__global__ void k_scan1(const int* __restrict__ deg, int* __restrict__ rowptr, int* __restrict__ bsum) {
    __shared__ int sh[256];
    int t = threadIdx.x;
    size_t base = (size_t)blockIdx.x * 1024 + (size_t)t * 4;
    int v[4];
#pragma unroll
    for (int j = 0; j < 4; ++j) v[j] = (base + j < NN) ? deg[base + j] : 0;
    int tsum = v[0] + v[1] + v[2] + v[3];
    sh[t] = tsum;
    __syncthreads();
    for (int off = 1; off < 256; off <<= 1) {
        int add = (t >= off) ? sh[t - off] : 0;
        __syncthreads();
        sh[t] += add;
        __syncthreads();
    }
    int run = sh[t] - tsum;  // exclusive prefix
#pragma unroll
    for (int j = 0; j < 4; ++j) {
        if (base + j < NN) rowptr[base + j] = run;
        run += v[j];
    }
    if (t == 255) bsum[blockIdx.x] = sh[255];
}

__global__ void k_scan2(int* __restrict__ bs, int nb) {
    __shared__ int sh[1024];
    int t = threadIdx.x;
    int v = (t < nb) ? bs[t] : 0;
    sh[t] = v;
    __syncthreads();
    for (int off = 1; off < 1024; off <<= 1) {
        int add = (t >= off) ? sh[t - off] : 0;
        __syncthreads();
        sh[t] += add;
        __syncthreads();
    }
    if (t < nb) bs[t] = sh[t] - v;  // exclusive
}

__global__ void k_scan3(int* __restrict__ rowptr, const int* __restrict__ bs) {
    size_t base = (size_t)blockIdx.x * 1024 + (size_t)threadIdx.x * 4;
    int off = bs[blockIdx.x];
#pragma unroll
    for (int j = 0; j < 4; ++j)
        if (base + j < NN) rowptr[base + j] += off;
    if (blockIdx.x == 0 && threadIdx.x == 0) rowptr[NN] = EE;
}

__global__ void k_copy(int* __restrict__ f, const int* __restrict__ r) {
    int i = blockIdx.x * blockDim.x + threadIdx.x;
    if (i < NN) f[i] = r[i];
}

__global__ void k_fill(const int* __restrict__ src, const int* __restrict__ dst,
                       int* __restrict__ fill, int* __restrict__ col) {
    int e = blockIdx.x * blockDim.x + threadIdx.x;
    if (e < EE) {
        int d = dst[e];
        int pos = atomicAdd(&fill[d], 1);
        col[pos] = src[e];
    }
}

// ---------------- layer-1 projection p = xd @ w1 (fp32 compute, f16 store) ----------------
__global__ __launch_bounds__(256) void k_p1(const float* __restrict__ xd,
                                            const float* __restrict__ w1,
                                            __half* __restrict__ out) {
    int lane = threadIdx.x & 31;
    float wc[FXDIM];
#pragma unroll
    for (int k = 0; k < FXDIM; ++k) wc[k] = w1[k * 32 + lane];
    int gid = (blockIdx.x * blockDim.x + threadIdx.x) >> 5;
    int ng = (gridDim.x * blockDim.x) >> 5;
    for (int i = gid; i < NN; i += ng) {
        const float* row = xd + (size_t)i * FXDIM;
        float x0 = row[lane];
        float x1 = (lane < FXDIM - 32) ? row[32 + lane] : 0.f;
        float acc = 0.f;
#pragma unroll
        for (int k = 0; k < 32; ++k) acc += __shfl(x0, k, 32) * wc[k];
#pragma unroll
        for (int k = 0; k < FXDIM - 32; ++k) acc += __shfl(x1, k, 32) * wc[32 + k];
        out[(size_t)i * 32 + lane] = __float2half_rn(acc);
    }
}

// ---------------- aggregation: agg[i] = h[i] + sum_{j->i} h[j]  (f16 rows, 64B) ----------------
__global__ __launch_bounds__(256) void k_agg(const __half2* __restrict__ hsrc,
                                             const int* __restrict__ rowptr,
                                             const int* __restrict__ colidx,
                                             __half2* __restrict__ agg) {
    int l = threadIdx.x & 15;
    int gid = (blockIdx.x * blockDim.x + threadIdx.x) >> 4;
    int ng = (gridDim.x * blockDim.x) >> 4;
    for (int i = gid; i < NN; i += ng) {
        int r0 = rowptr[i], r1 = rowptr[i + 1];
        __half2 s = hsrc[(size_t)i * 16 + l];
        float ax0 = __low2float(s), ay0 = __high2float(s);
        float ax1 = 0.f, ay1 = 0.f, ax2 = 0.f, ay2 = 0.f, ax3 = 0.f, ay3 = 0.f;
        int e = r0;
        for (; e + 4 <= r1; e += 4) {
            int s0 = colidx[e], s1 = colidx[e + 1], s2 = colidx[e + 2], s3 = colidx[e + 3];
            __half2 v0 = hsrc[(size_t)s0 * 16 + l];
            __half2 v1 = hsrc[(size_t)s1 * 16 + l];
            __half2 v2 = hsrc[(size_t)s2 * 16 + l];
            __half2 v3 = hsrc[(size_t)s3 * 16 + l];
            ax0 += __low2float(v0); ay0 += __high2float(v0);
            ax1 += __low2float(v1); ay1 += __high2float(v1);
            ax2 += __low2float(v2); ay2 += __high2float(v2);
            ax3 += __low2float(v3); ay3 += __high2float(v3);
        }
        if (e + 2 <= r1) {
            int s0 = colidx[e], s1 = colidx[e + 1];
            __half2 v0 = hsrc[(size_t)s0 * 16 + l];
            __half2 v1 = hsrc[(size_t)s1 * 16 + l];
            ax1 += __low2float(v0); ay1 += __high2float(v0);
            ax2 += __low2float(v1); ay2 += __high2float(v1);
            e += 2;
        }
        if (e < r1) {
            __half2 v0 = hsrc[(size_t)colidx[e] * 16 + l];
            ax3 += __low2float(v0); ay3 += __high2float(v0);
        }
        float sx = (ax0 + ax1) + (ax2 + ax3);
        float sy = (ay0 + ay1) + (ay2 + ay3);
        agg[(size_t)i * 16 + l] = __floats2half2_rn(sx, sy);
    }
}

// ---------------- MLP + BN-stat kernel (streaming, dot2-f16) ----------------
template <int FIRST>
__global__ __launch_bounds__(256) void k_mlp(const __half* __restrict__ agg,
                                             const int* __restrict__ rowptr,
                                             const float* __restrict__ aff,
                                             const float* __restrict__ w1,
                                             const float* __restrict__ b1,
                                             const float* __restrict__ w2,
                                             const float* __restrict__ b2,
                                             __half* __restrict__ hdst,
                                             float* __restrict__ partial) {
    const int lane = threadIdx.x & 31;
    unsigned wp1[16], wp2[16];
    if (!FIRST) {
#pragma unroll
        for (int kp = 0; kp < 16; ++kp) {
            __half2 p = __floats2half2_rn(w1[(2 * kp) * 32 + lane], w1[(2 * kp + 1) * 32 + lane]);
            wp1[kp] = __builtin_bit_cast(unsigned, p);
        }
    }
#pragma unroll
    for (int kp = 0; kp < 16; ++kp) {
        __half2 p = __floats2half2_rn(w2[(2 * kp) * 32 + lane], w2[(2 * kp + 1) * 32 + lane]);
        wp2[kp] = __builtin_bit_cast(unsigned, p);
    }
    float b1v = b1[lane], b2v = b2[lane];
    float sA = 1.f, tA = 0.f;
    if (!FIRST) { sA = aff[lane]; tA = aff[32 + lane]; }

    float psum = 0.f, psq = 0.f;
    int gid = (blockIdx.x * blockDim.x + threadIdx.x) >> 5;
    int ng = (gridDim.x * blockDim.x) >> 5;
    for (int i = gid; i < NN; i += ng) {
        float u = __half2float(agg[(size_t)i * 32 + lane]);
        float z;
        if (FIRST) {
            z = fmaxf(u + b1v, 0.f);
        } else {
            int d = rowptr[i + 1] - rowptr[i];
            u = sA * u + (float)(d + 1) * tA;
            unsigned pu = packpair(u, lane);
            float a = b1v;
#pragma unroll
            for (int kp = 0; kp < 16; ++kp)
                a = fdot2u(__shfl(pu, 2 * kp, 32), wp1[kp], a);
            z = fmaxf(a, 0.f);
        }
        unsigned pz = packpair(z, lane);
        float a2 = b2v;
#pragma unroll
        for (int kp = 0; kp < 16; ++kp)
            a2 = fdot2u(__shfl(pz, 2 * kp, 32), wp2[kp], a2);
        float hv = fmaxf(a2, 0.f);
        hdst[(size_t)i * 32 + lane] = __float2half_rn(hv);
        psum += hv;
        psq += hv * hv;
    }
    __shared__ float red[8][64];
    int wid = threadIdx.x >> 5;
    red[wid][lane] = psum;
    red[wid][32 + lane] = psq;
    __syncthreads();
    if (threadIdx.x < 64) {
        float s = 0.f;
#pragma unroll
        for (int w = 0; w < 8; ++w) s += red[w][threadIdx.x];
        partial[(size_t)blockIdx.x * 64 + threadIdx.x] = s;
    }
}

// ---------------- finalize BN stats -> affine s,t (1 block/channel) ----------------
__global__ __launch_bounds__(256) void k_reduce(const float* __restrict__ partial, int nblocks,
                                                const float* __restrict__ g, const float* __restrict__ bt,
                                                float* __restrict__ aff) {
    int c = blockIdx.x;   // channel 0..31
    int t = threadIdx.x;
    double s = 0.0, q = 0.0;
    for (int b = t; b < nblocks; b += 256) {
        s += (double)partial[(size_t)b * 64 + c];
        q += (double)partial[(size_t)b * 64 + 32 + c];
    }
    __shared__ double shs[256], shq[256];
    shs[t] = s; shq[t] = q;
    __syncthreads();
    for (int off = 128; off; off >>= 1) {
        if (t < off) { shs[t] += shs[t + off]; shq[t] += shq[t + off]; }
        __syncthreads();
    }
    if (t == 0) {
        double mean = shs[0] / (double)NN;
        double var = shq[0] / (double)NN - mean * mean;
        float r = (float)rsqrt(var + 1e-5);
        float sv = g[c] * r;
        aff[c] = sv;
        aff[32 + c] = bt[c] - (float)mean * sv;
    }
}

// ---------------- pooling (xd_batch sorted -> run-length + atomics) ----------------
__global__ __launch_bounds__(256) void k_pool(const __half* __restrict__ h,
                                              const int* __restrict__ batch,
                                              float* __restrict__ ps) {
    int lane = threadIdx.x & 31;
    int g = threadIdx.x >> 5;
    const int chunk = (NN + gridDim.x - 1) / gridDim.x;
    int s0 = blockIdx.x * chunk;
    int s1 = min(NN, s0 + chunk);
    int curb = -1;
    float acc = 0.f;
    for (int i = s0 + g; i < s1; i += 8) {
        int b = batch[i];
        if (b != curb) {
            if (curb >= 0) atomicAdd(&ps[curb * 32 + lane], acc);
            acc = 0.f;
            curb = b;
        }
        acc += __half2float(h[(size_t)i * 32 + lane]);
    }
    if (curb >= 0) atomicAdd(&ps[curb * 32 + lane], acc);
}

__device__ int lowerb(const int* a, int n, int key) {
    int lo = 0, hi = n;
    while (lo < hi) {
        int m = (lo + hi) >> 1;
        if (a[m] < key) lo = m + 1;
        else hi = m;
    }
    return lo;
}

__global__ void k_counts(const int* __restrict__ batch, int* __restrict__ cnt) {
    int b = blockIdx.x * blockDim.x + threadIdx.x;
    if (b < BB) cnt[b] = lowerb(batch, NN, b + 1) - lowerb(batch, NN, b);
}

// ---------------- xdv = ReLU(pooled' @ fcd_w + fcd_b) ----------------
__global__ __launch_bounds__(128) void k_xdv(const float* __restrict__ ps,
                                             const int* __restrict__ cnt,
                                             const float* __restrict__ aff,
                                             const float* __restrict__ w,
                                             const float* __restrict__ bb,
                                             float* __restrict__ xdv) {
    int b = blockIdx.x;
    int j = threadIdx.x;
    __shared__ float p[32];
    if (j < 32) p[j] = aff[j] * ps[b * 32 + j] + (float)cnt[b] * aff[32 + j];
    __syncthreads();
    float acc = bb[j];
#pragma unroll
    for (int c = 0; c < 32; ++c) acc += p[c] * w[c * 128 + j];
    xdv[b * 128 + j] = fmaxf(acc, 0.f);
}

// ---------------- conv branch ----------------
__global__ void k_kT(const float* __restrict__ ck, float* __restrict__ kT) {
    int i = blockIdx.x;
    int t = threadIdx.x;
    int o = t >> 3, k = t & 7;
    kT[(size_t)i * 256 + t] = ck[(size_t)o * (LL * KK) + (size_t)i * KK + k];
}

__global__ __launch_bounds__(256) void k_conv(const int* __restrict__ xt,
                                              const float* __restrict__ kT,
                                              const float* __restrict__ emb,
                                              const float* __restrict__ cb,
                                              float* __restrict__ cbuf) {
    __shared__ float S[VOCAB * 256];
    __shared__ float Em[VOCAB * EMBD];
    int t = threadIdx.x;
    int b = blockIdx.x;
    for (int v = t; v < VOCAB * 256; v += 256) S[v] = 0.f;
    for (int v = t; v < VOCAB * EMBD; v += 256) Em[v] = emb[v];
    __syncthreads();
    const int* row = xt + (size_t)b * LL;
#pragma unroll 4
    for (int i = 0; i < LL; ++i) {
        int v = row[i];
        S[v * 256 + t] += kT[(size_t)i * 256 + t];
    }
    __syncthreads();
    int h = t & 127, half = t >> 7;
    if (h < 121) {
        float acc[16];
        int o0 = half * 16;
#pragma unroll
        for (int o = 0; o < 16; ++o) acc[o] = cb[o0 + o];
        for (int v = 0; v < VOCAB; ++v) {
            float e[8];
#pragma unroll
            for (int k = 0; k < 8; ++k) e[k] = Em[v * EMBD + h + k];
#pragma unroll
            for (int o = 0; o < 16; ++o) {
                float a = acc[o];
#pragma unroll
                for (int k = 0; k < 8; ++k) a += S[v * 256 + (o0 + o) * 8 + k] * e[k];
                acc[o] = a;
            }
        }
#pragma unroll
        for (int o = 0; o < 16; ++o)
            cbuf[(size_t)b * CF + (size_t)(o0 + o) * 121 + h] = acc[o];
    }
}

// ---------------- bias init (rows of `cols` columns get bias[j]) ----------------
__global__ void k_binit(const float* __restrict__ bias, float* __restrict__ out, int mask) {
    int i = blockIdx.x * blockDim.x + threadIdx.x;
    out[i] = bias[i & mask];
}

// ---------------- xtv += c_tile @ w_tile (split-K, LDS-tiled, atomic accumulate) ----------------
// grid: 64 row-blocks (16 rows) x 8 K-chunks (484). out must be pre-initialized with bias.
__global__ __launch_bounds__(256) void k_xtv(const float* __restrict__ c,
                                             const float* __restrict__ w,
                                             float* __restrict__ xtv) {
    __shared__ float ct[16][484];
    int rb = blockIdx.x >> 3, kc = blockIdx.x & 7;
    int b0 = rb * 16, k0 = kc * 484;
    int tid = threadIdx.x;
#pragma unroll
    for (int r = 0; r < 16; ++r)
        for (int k = tid; k < 484; k += 256)
            ct[r][k] = c[(size_t)(b0 + r) * CF + k0 + k];
    __syncthreads();
    int j = tid & 127, rh = tid >> 7;
    float acc[8];
#pragma unroll
    for (int r = 0; r < 8; ++r) acc[r] = 0.f;
    const float2* ct2 = (const float2*)&ct[0][0];   // row stride = 242 float2
    for (int k2 = 0; k2 < 242; ++k2) {
        float w0 = w[(size_t)(k0 + 2 * k2) * 128 + j];
        float w1 = w[(size_t)(k0 + 2 * k2 + 1) * 128 + j];
#pragma unroll
        for (int r = 0; r < 8; ++r) {
            float2 cv = ct2[(rh * 8 + r) * 242 + k2];
            acc[r] = fmaf(cv.x, w0, fmaf(cv.y, w1, acc[r]));
        }
    }
#pragma unroll
    for (int r = 0; r < 8; ++r)
        atomicAdd(&xtv[(size_t)(b0 + rh * 8 + r) * 128 + j], acc[r]);
}

// ---------------- classifier ----------------
__global__ __launch_bounds__(1024) void k_cls1(const float* __restrict__ xdv,
                                               const float* __restrict__ xtv,
                                               const float* __restrict__ w,
                                               const float* __restrict__ bb,
                                               float* __restrict__ h1) {
    __shared__ float X[8][256];
    int j = threadIdx.x;
    int b0 = blockIdx.x * 8;
    for (int idx = j; idx < 8 * 256; idx += 1024) {
        int r = idx >> 8, k = idx & 255;
        X[r][k] = (k < 128) ? xdv[(b0 + r) * 128 + k] : xtv[(b0 + r) * 128 + (k - 128)];
    }
    __syncthreads();
    float acc[8];
#pragma unroll
    for (int r = 0; r < 8; ++r) acc[r] = bb[j];
    for (int k = 0; k < 256; ++k) {
        float wv = w[(size_t)k * 1024 + j];
#pragma unroll
        for (int r = 0; r < 8; ++r) acc[r] += X[r][k] * wv;
    }
#pragma unroll
    for (int r = 0; r < 8; ++r) h1[(size_t)(b0 + r) * 1024 + j] = fmaxf(acc[r], 0.f);
}

// h2pre += h1_tile @ w_tile (split-K, atomic). out pre-initialized with bias; ReLU in k_cls3.
// grid: 128 row-blocks (8 rows) x 4 K-chunks (256 each).
__global__ __launch_bounds__(256) void k_cls2(const float* __restrict__ h1,
                                              const float* __restrict__ w,
                                              float* __restrict__ h2) {
    __shared__ float X[8][256];
    int rb = blockIdx.x >> 2, kc = blockIdx.x & 3;
    int b0 = rb * 8, k0 = kc * 256;
    int tid = threadIdx.x;
#pragma unroll
    for (int r = 0; r < 8; ++r)
        X[r][tid] = h1[(size_t)(b0 + r) * 1024 + k0 + tid];
    __syncthreads();
    int j = tid;
    float acc[8];
#pragma unroll
    for (int r = 0; r < 8; ++r) acc[r] = 0.f;
    const float2* X2 = (const float2*)&X[0][0];   // row stride = 128 float2
    for (int k2 = 0; k2 < 128; ++k2) {
        float w0 = w[(size_t)(k0 + 2 * k2) * 256 + j];
        float w1 = w[(size_t)(k0 + 2 * k2 + 1) * 256 + j];
#pragma unroll
        for (int r = 0; r < 8; ++r) {
            float2 xv = X2[r * 128 + k2];
            acc[r] = fmaf(xv.x, w0, fmaf(xv.y, w1, acc[r]));
        }
    }
#pragma unroll
    for (int r = 0; r < 8; ++r)
        atomicAdd(&h2[(size_t)(b0 + r) * 256 + j], acc[r]);
}

__global__ __launch_bounds__(256) void k_cls3(const float* __restrict__ h2,
                                              const float* __restrict__ w,
                                              const float* __restrict__ bb,
                                              const float* __restrict__ y,
                                              float* __restrict__ dout) {
    int lane = threadIdx.x & 63;
    int b = (blockIdx.x * blockDim.x + threadIdx.x) >> 6;
    if (b >= BB) return;
    float acc = 0.f;
    for (int k = lane; k < 256; k += 64) acc += fmaxf(h2[(size_t)b * 256 + k], 0.f) * w[k];
#pragma unroll
    for (int off = 32; off; off >>= 1) acc += __shfl_xor(acc, off, 64);
    if (lane == 0) dout[b] = acc + bb[0];
    if (lane == 1) dout[BB + b] = y[b];
}

// ---------------- launch ----------------
extern "C" void kernel_launch(void* const* d_in, const int* in_sizes, int n_in,
                              void* d_out, int out_size, void* d_ws, size_t ws_size,
                              hipStream_t stream) {
    const float* xd = (const float*)d_in[0];
    const int* ei = (const int*)d_in[1];
    const int* batch = (const int*)d_in[2];
    const int* xt = (const int*)d_in[3];
    const float* y = (const float*)d_in[4];
    const float* g1w1 = (const float*)d_in[5];
    const float* g1b1 = (const float*)d_in[6];
    const float* g1w2 = (const float*)d_in[7];
    const float* g1b2 = (const float*)d_in[8];
    const float* grw1 = (const float*)d_in[9];
    const float* grb1 = (const float*)d_in[10];
    const float* grw2 = (const float*)d_in[11];
    const float* grb2 = (const float*)d_in[12];
    const float* bng = (const float*)d_in[13];
    const float* bnb = (const float*)d_in[14];
    const float* fcdw = (const float*)d_in[15];
    const float* fcdb = (const float*)d_in[16];
    const float* emb = (const float*)d_in[17];
    const float* convk = (const float*)d_in[18];
    const float* convb = (const float*)d_in[19];
    const float* fctw = (const float*)d_in[20];
    const float* fctb = (const float*)d_in[21];
    const float* cw1 = (const float*)d_in[22];
    const float* cb1 = (const float*)d_in[23];
    const float* cw2 = (const float*)d_in[24];
    const float* cb2 = (const float*)d_in[25];
    const float* cw3 = (const float*)d_in[26];
    const float* cb3 = (const float*)d_in[27];

    const int* src = ei;
    const int* dst = ei + EE;

    size_t off = 0;
    auto alloc = [&](size_t bytes) {
        size_t o = off;
        off = (off + bytes + 255) & ~(size_t)255;
        return o;
    };
    char* ws = (char*)d_ws;
    size_t o_deg = alloc(4ull * NN);
    size_t o_rp = alloc(4ull * (NN + 1));
    size_t o_fill = alloc(4ull * NN);
    size_t o_col = alloc(4ull * EE);
    size_t o_bsum = alloc(4ull * 1024);
    size_t o_ha = alloc(2ull * NN * 32);
    size_t o_hb = alloc(2ull * NN * 32);
    size_t o_ag = alloc(2ull * NN * 32);
    size_t o_part = alloc(4ull * 2048 * 64);
    size_t o_aff = alloc(4ull * 64);
    size_t o_ps = alloc(4ull * BB * 32);
    size_t o_cnt = alloc(4ull * BB);
    size_t o_xdv = alloc(4ull * BB * 128);
    size_t o_kT = alloc(4ull * LL * 256);
    size_t o_c = alloc(4ull * BB * CF);
    size_t o_xtv = alloc(4ull * BB * 128);
    size_t o_h1 = alloc(4ull * BB * 1024);
    size_t o_h2 = alloc(4ull * BB * 256);

    int* deg = (int*)(ws + o_deg);
    int* rp = (int*)(ws + o_rp);
    int* fill = (int*)(ws + o_fill);
    int* col = (int*)(ws + o_col);
    int* bsum = (int*)(ws + o_bsum);
    __half* ha = (__half*)(ws + o_ha);
    __half* hb = (__half*)(ws + o_hb);
    __half* ag = (__half*)(ws + o_ag);
    float* part = (float*)(ws + o_part);
    float* aff = (float*)(ws + o_aff);
    float* ps = (float*)(ws + o_ps);
    int* cnt = (int*)(ws + o_cnt);
    float* xdv = (float*)(ws + o_xdv);
    float* kT = (float*)(ws + o_kT);
    float* cbuf = (float*)(ws + o_c);
    float* xtv = (float*)(ws + o_xtv);
    float* h1 = (float*)(ws + o_h1);
    float* h2 = (float*)(ws + o_h2);
    float* dout = (float*)d_out;

    // --- CSR build ---
    hipMemsetAsync(deg, 0, 4ull * NN, stream);
    k_count<<<EE / 256, 256, 0, stream>>>(dst, deg);
    k_scan1<<<977, 256, 0, stream>>>(deg, rp, bsum);
    k_scan2<<<1, 1024, 0, stream>>>(bsum, 977);
    k_scan3<<<977, 256, 0, stream>>>(rp, bsum);
    k_copy<<<(NN + 255) / 256, 256, 0, stream>>>(fill, rp);
    k_fill<<<EE / 256, 256, 0, stream>>>(src, dst, fill, col);

    // --- GIN layers (split agg / mlp) ---
    k_p1<<<2048, 256, 0, stream>>>(xd, g1w1, ha);

    // layer 1
    k_agg<<<2048, 256, 0, stream>>>((const __half2*)ha, rp, col, (__half2*)ag);
    k_mlp<1><<<2048, 256, 0, stream>>>(ag, rp, aff, g1w1, g1b1, g1w2, g1b2, hb, part);
    k_reduce<<<32, 256, 0, stream>>>(part, 2048, bng, bnb, aff);

    const __half* srcbuf = hb;
    __half* dstbuf = ha;
    for (int i = 0; i < 4; ++i) {
        k_agg<<<2048, 256, 0, stream>>>((const __half2*)srcbuf, rp, col, (__half2*)ag);
        k_mlp<0><<<2048, 256, 0, stream>>>(ag, rp, aff,
                                           grw1 + (size_t)i * 1024, grb1 + (size_t)i * 32,
                                           grw2 + (size_t)i * 1024, grb2 + (size_t)i * 32,
                                           dstbuf, part);
        k_reduce<<<32, 256, 0, stream>>>(part, 2048, bng + (i + 1) * 32, bnb + (i + 1) * 32, aff);
        const __half* tmp = srcbuf;
        srcbuf = dstbuf;
        dstbuf = (__half*)tmp;
    }
    // after loop: srcbuf == layer-5 output, aff == layer-5 affine

    // --- pooling + xdv ---
    hipMemsetAsync(ps, 0, 4ull * BB * 32, stream);
    k_pool<<<1024, 256, 0, stream>>>(srcbuf, batch, ps);
    k_counts<<<4, 256, 0, stream>>>(batch, cnt);
    k_xdv<<<BB, 128, 0, stream>>>(ps, cnt, aff, fcdw, fcdb, xdv);

    // --- conv branch ---
    k_kT<<<LL, 256, 0, stream>>>(convk, kT);
    k_conv<<<BB, 256, 0, stream>>>(xt, kT, emb, convb, cbuf);
    k_binit<<<BB * 128 / 256, 256, 0, stream>>>(fctb, xtv, 127);
    k_xtv<<<512, 256, 0, stream>>>(cbuf, fctw, xtv);

    // --- classifier ---
    k_cls1<<<BB / 8, 1024, 0, stream>>>(xdv, xtv, cw1, cb1, h1);
    k_binit<<<BB * 256 / 256, 256, 0, stream>>>(cb2, h2, 255);
    k_cls2<<<512, 256, 0, stream>>>(h1, cw2, h2);
    k_cls3<<<256, 256, 0, stream>>>(h2, cw3, cb3, y, dout);
}

// Round 5
// 2146.931 us; speedup vs baseline: 2.2225x; 1.1408x over previous
//
#include <hip/hip_runtime.h>
#include <hip/hip_bf16.h>
#include <hip/hip_fp16.h>

#define NN 1000000
#define EE 4000000
#define BB 1024
#define DIM 32
#define FXDIM 55
#define EMBD 128
#define VOCAB 26
#define LL 1000
#define NF 32
#define KK 8
#define CF 3872   // 32*121
#define BSH 12
#define NB 245          // ceil(NN / 4096)
#define ESLOT 20480     // padded records per bucket (mean 16.3K, +32 sigma)

typedef _Float16 h2_t __attribute__((ext_vector_type(2)));

__device__ inline float fdot2u(unsigned a, unsigned b, float c) {
#if defined(__has_builtin) && __has_builtin(__builtin_amdgcn_fdot2)
    h2_t ha = __builtin_bit_cast(h2_t, a);
    h2_t hb = __builtin_bit_cast(h2_t, b);
    return __builtin_amdgcn_fdot2(ha, hb, c, false);
#else
    __half2 ha = __builtin_bit_cast(__half2, a);
    __half2 hb = __builtin_bit_cast(__half2, b);
    return fmaf(__low2float(ha), __low2float(hb),
                fmaf(__high2float(ha), __high2float(hb), c));
#endif
}

// every lane ends up holding packed f16 pair (v[2*(lane>>1)], v[2*(lane>>1)+1])
__device__ inline unsigned packpair(float v, int lane) {
    float o = __shfl_xor(v, 1, 32);
    float lo = (lane & 1) ? o : v;
    float hi = (lane & 1) ? v : o;
    __half2 p = __floats2half2_rn(lo, hi);
    return __builtin_bit_cast(unsigned, p);
}

// ---------------- CSR build: bucketed two-pass (write-coalescing-friendly) ----------------
// Pass 1: LDS-bin 4096 edges/block into NB buckets, burst-write 8B records to padded regions.
__global__ __launch_bounds__(256) void k_bscatter(const int* __restrict__ src,
                                                  const int* __restrict__ dst,
                                                  int* __restrict__ bcur,
                                                  unsigned long long* __restrict__ ebuf) {
    __shared__ unsigned long long rec[4096];
    __shared__ short bid[4096];
    __shared__ int cnt[NB], pref[NB], gb[NB];
    __shared__ int sc[256];
    int t = threadIdx.x;
    for (int i = t; i < NB; i += 256) cnt[i] = 0;
    __syncthreads();
    size_t base = (size_t)blockIdx.x * 4096;
    int b_[16], s_[16], d_[16];
#pragma unroll
    for (int j = 0; j < 16; ++j) {
        size_t e = base + (size_t)j * 256 + t;
        if (e < EE) {
            int d = dst[e];
            b_[j] = d >> BSH;
            d_[j] = d;
            s_[j] = src[e];
            atomicAdd(&cnt[b_[j]], 1);
        } else b_[j] = -1;
    }
    __syncthreads();
    int v = (t < NB) ? cnt[t] : 0;
    sc[t] = v;
    __syncthreads();
    for (int off = 1; off < 256; off <<= 1) {
        int a = (t >= off) ? sc[t - off] : 0;
        __syncthreads();
        sc[t] += a;
        __syncthreads();
    }
    if (t < NB) {
        pref[t] = sc[t] - v;
        gb[t] = (v > 0) ? atomicAdd(&bcur[t], v) : 0;
        cnt[t] = 0;
    }
    __syncthreads();
#pragma unroll
    for (int j = 0; j < 16; ++j) {
        if (b_[j] >= 0) {
            int r = atomicAdd(&cnt[b_[j]], 1);
            int p = pref[b_[j]] + r;
            rec[p] = ((unsigned long long)(unsigned)d_[j] << 32) | (unsigned)s_[j];
            bid[p] = (short)b_[j];
        }
    }
    __syncthreads();
    int total = sc[NB - 1];
    for (int p = t; p < total; p += 256) {
        int b = bid[p];
        size_t gp = (size_t)b * ESLOT + gb[b] + (p - pref[b]);
        ebuf[gp] = rec[p];
    }
}

__global__ void k_bscan(const int* __restrict__ bcnt, int* __restrict__ bbase) {
    __shared__ int sh[256];
    int t = threadIdx.x;
    int v = (t < NB) ? bcnt[t] : 0;
    sh[t] = v;
    __syncthreads();
    for (int off = 1; off < 256; off <<= 1) {
        int a = (t >= off) ? sh[t - off] : 0;
        __syncthreads();
        sh[t] += a;
        __syncthreads();
    }
    if (t < NB) bbase[t] = sh[t] - v;
}

// Pass 2: one block owns one bucket -> local count/scan -> rowptr + col (L2-private region).
__global__ __launch_bounds__(256) void k_build(const unsigned long long* __restrict__ ebuf,
                                               const int* __restrict__ bbase,
                                               const int* __restrict__ bcnt,
                                               int* __restrict__ rowptr,
                                               int* __restrict__ col) {
    __shared__ int cnt[4096];
    __shared__ int pref[4096];
    __shared__ int part[256];
    int b = blockIdx.x, t = threadIdx.x;
    int n0 = b << BSH;
    int nmax = min(4096, NN - n0);
    for (int i = t; i < 4096; i += 256) cnt[i] = 0;
    __syncthreads();
    int e0 = bbase[b];
    int ne = bcnt[b];
    const unsigned long long* eb = ebuf + (size_t)b * ESLOT;
    for (int e = t; e < ne; e += 256) {
        int d = (int)(eb[e] >> 32) & 4095;
        atomicAdd(&cnt[d], 1);
    }
    __syncthreads();
    int s = 0, loc[16];
    int bi = t * 16;
#pragma unroll
    for (int j = 0; j < 16; ++j) { loc[j] = s; s += cnt[bi + j]; }
    part[t] = s;
    __syncthreads();
    for (int off = 1; off < 256; off <<= 1) {
        int a = (t >= off) ? part[t - off] : 0;
        __syncthreads();
        part[t] += a;
        __syncthreads();
    }
    int pb = part[t] - s;
#pragma unroll
    for (int j = 0; j < 16; ++j) pref[bi + j] = pb + loc[j];
    __syncthreads();
    for (int i = t; i < nmax; i += 256) rowptr[n0 + i] = e0 + pref[i];
    if (b == NB - 1 && t == 0) rowptr[NN] = EE;
    __syncthreads();
    for (int e = t; e < ne; e += 256) {
        unsigned long long r = eb[e];
        int d = (int)(r >> 32) & 4095;
        int p = atomicAdd(&pref[d], 1);
        col[e0 + p] = (int)(r & 0xffffffffu);
    }
}

// ---------------- layer-1 projection p = xd @ w1 (fp32 compute, f16 store) ----------------
__global__ __launch_bounds__(256) void k_p1(const float* __restrict__ xd,
                                            const float* __restrict__ w1,
                                            __half* __restrict__ out) {
    int lane = threadIdx.x & 31;
    float wc[FXDIM];
#pragma unroll
    for (int k = 0; k < FXDIM; ++k) wc[k] = w1[k * 32 + lane];
    int gid = (blockIdx.x * blockDim.x + threadIdx.x) >> 5;
    int ng = (gridDim.x * blockDim.x) >> 5;
    for (int i = gid; i < NN; i += ng) {
        const float* row = xd + (size_t)i * FXDIM;
        float x0 = row[lane];
        float x1 = (lane < FXDIM - 32) ? row[32 + lane] : 0.f;
        float acc = 0.f;
#pragma unroll
        for (int k = 0; k < 32; ++k) acc += __shfl(x0, k, 32) * wc[k];
#pragma unroll
        for (int k = 0; k < FXDIM - 32; ++k) acc += __shfl(x1, k, 32) * wc[32 + k];
        out[(size_t)i * 32 + lane] = __float2half_rn(acc);
    }
}

// ---------------- aggregation: agg[i] = h[i] + sum_{j->i} h[j]  (f16 rows, 64B) ----------------
__global__ __launch_bounds__(256) void k_agg(const __half2* __restrict__ hsrc,
                                             const int* __restrict__ rowptr,
                                             const int* __restrict__ colidx,
                                             __half2* __restrict__ agg) {
    int l = threadIdx.x & 15;
    int gid = (blockIdx.x * blockDim.x + threadIdx.x) >> 4;
    int ng = (gridDim.x * blockDim.x) >> 4;
    for (int i = gid; i < NN; i += ng) {
        int r0 = rowptr[i], r1 = rowptr[i + 1];
        __half2 s = hsrc[(size_t)i * 16 + l];
        float ax0 = __low2float(s), ay0 = __high2float(s);
        float ax1 = 0.f, ay1 = 0.f, ax2 = 0.f, ay2 = 0.f, ax3 = 0.f, ay3 = 0.f;
        int e = r0;
        for (; e + 4 <= r1; e += 4) {
            int s0 = colidx[e], s1 = colidx[e + 1], s2 = colidx[e + 2], s3 = colidx[e + 3];
            __half2 v0 = hsrc[(size_t)s0 * 16 + l];
            __half2 v1 = hsrc[(size_t)s1 * 16 + l];
            __half2 v2 = hsrc[(size_t)s2 * 16 + l];
            __half2 v3 = hsrc[(size_t)s3 * 16 + l];
            ax0 += __low2float(v0); ay0 += __high2float(v0);
            ax1 += __low2float(v1); ay1 += __high2float(v1);
            ax2 += __low2float(v2); ay2 += __high2float(v2);
            ax3 += __low2float(v3); ay3 += __high2float(v3);
        }
        if (e + 2 <= r1) {
            int s0 = colidx[e], s1 = colidx[e + 1];
            __half2 v0 = hsrc[(size_t)s0 * 16 + l];
            __half2 v1 = hsrc[(size_t)s1 * 16 + l];
            ax1 += __low2float(v0); ay1 += __high2float(v0);
            ax2 += __low2float(v1); ay2 += __high2float(v1);
            e += 2;
        }
        if (e < r1) {
            __half2 v0 = hsrc[(size_t)colidx[e] * 16 + l];
            ax3 += __low2float(v0); ay3 += __high2float(v0);
        }
        float sx = (ax0 + ax1) + (ax2 + ax3);
        float sy = (ay0 + ay1) + (ay2 + ay3);
        agg[(size_t)i * 16 + l] = __floats2half2_rn(sx, sy);
    }
}

// ---------------- MLP + BN-stat kernel (streaming, dot2-f16) ----------------
template <int FIRST>
__global__ __launch_bounds__(256) void k_mlp(const __half* __restrict__ agg,
                                             const int* __restrict__ rowptr,
                                             const float* __restrict__ aff,
                                             const float* __restrict__ w1,
                                             const float* __restrict__ b1,
                                             const float* __restrict__ w2,
                                             const float* __restrict__ b2,
                                             __half* __restrict__ hdst,
                                             float* __restrict__ partial) {
    const int lane = threadIdx.x & 31;
    unsigned wp1[16], wp2[16];
    if (!FIRST) {
#pragma unroll
        for (int kp = 0; kp < 16; ++kp) {
            __half2 p = __floats2half2_rn(w1[(2 * kp) * 32 + lane], w1[(2 * kp + 1) * 32 + lane]);
            wp1[kp] = __builtin_bit_cast(unsigned, p);
        }
    }
#pragma unroll
    for (int kp = 0; kp < 16; ++kp) {
        __half2 p = __floats2half2_rn(w2[(2 * kp) * 32 + lane], w2[(2 * kp + 1) * 32 + lane]);
        wp2[kp] = __builtin_bit_cast(unsigned, p);
    }
    float b1v = b1[lane], b2v = b2[lane];
    float sA = 1.f, tA = 0.f;
    if (!FIRST) { sA = aff[lane]; tA = aff[32 + lane]; }

    float psum = 0.f, psq = 0.f;
    int gid = (blockIdx.x * blockDim.x + threadIdx.x) >> 5;
    int ng = (gridDim.x * blockDim.x) >> 5;
    for (int i = gid; i < NN; i += ng) {
        float u = __half2float(agg[(size_t)i * 32 + lane]);
        float z;
        if (FIRST) {
            z = fmaxf(u + b1v, 0.f);
        } else {
            int d = rowptr[i + 1] - rowptr[i];
            u = sA * u + (float)(d + 1) * tA;
            unsigned pu = packpair(u, lane);
            float a = b1v;
#pragma unroll
            for (int kp = 0; kp < 16; ++kp)
                a = fdot2u(__shfl(pu, 2 * kp, 32), wp1[kp], a);
            z = fmaxf(a, 0.f);
        }
        unsigned pz = packpair(z, lane);
        float a2 = b2v;
#pragma unroll
        for (int kp = 0; kp < 16; ++kp)
            a2 = fdot2u(__shfl(pz, 2 * kp, 32), wp2[kp], a2);
        float hv = fmaxf(a2, 0.f);
        hdst[(size_t)i * 32 + lane] = __float2half_rn(hv);
        psum += hv;
        psq += hv * hv;
    }
    __shared__ float red[8][64];
    int wid = threadIdx.x >> 5;
    red[wid][lane] = psum;
    red[wid][32 + lane] = psq;
    __syncthreads();
    if (threadIdx.x < 64) {
        float s = 0.f;
#pragma unroll
        for (int w = 0; w < 8; ++w) s += red[w][threadIdx.x];
        partial[(size_t)blockIdx.x * 64 + threadIdx.x] = s;
    }
}

// ---------------- finalize BN stats -> affine s,t (1 block/channel) ----------------
__global__ __launch_bounds__(256) void k_reduce(const float* __restrict__ partial, int nblocks,
                                                const float* __restrict__ g, const float* __restrict__ bt,
                                                float* __restrict__ aff) {
    int c = blockIdx.x;   // channel 0..31
    int t = threadIdx.x;
    double s = 0.0, q = 0.0;
    for (int b = t; b < nblocks; b += 256) {
        s += (double)partial[(size_t)b * 64 + c];
        q += (double)partial[(size_t)b * 64 + 32 + c];
    }
    __shared__ double shs[256], shq[256];
    shs[t] = s; shq[t] = q;
    __syncthreads();
    for (int off = 128; off; off >>= 1) {
        if (t < off) { shs[t] += shs[t + off]; shq[t] += shq[t + off]; }
        __syncthreads();
    }
    if (t == 0) {
        double mean = shs[0] / (double)NN;
        double var = shq[0] / (double)NN - mean * mean;
        float r = (float)rsqrt(var + 1e-5);
        float sv = g[c] * r;
        aff[c] = sv;
        aff[32 + c] = bt[c] - (float)mean * sv;
    }
}

// ---------------- pooling (xd_batch sorted -> run-length + atomics) ----------------
__global__ __launch_bounds__(256) void k_pool(const __half* __restrict__ h,
                                              const int* __restrict__ batch,
                                              float* __restrict__ ps) {
    int lane = threadIdx.x & 31;
    int g = threadIdx.x >> 5;
    const int chunk = (NN + gridDim.x - 1) / gridDim.x;
    int s0 = blockIdx.x * chunk;
    int s1 = min(NN, s0 + chunk);
    int curb = -1;
    float acc = 0.f;
    for (int i = s0 + g; i < s1; i += 8) {
        int b = batch[i];
        if (b != curb) {
            if (curb >= 0) atomicAdd(&ps[curb * 32 + lane], acc);
            acc = 0.f;
            curb = b;
        }
        acc += __half2float(h[(size_t)i * 32 + lane]);
    }
    if (curb >= 0) atomicAdd(&ps[curb * 32 + lane], acc);
}

__device__ int lowerb(const int* a, int n, int key) {
    int lo = 0, hi = n;
    while (lo < hi) {
        int m = (lo + hi) >> 1;
        if (a[m] < key) lo = m + 1;
        else hi = m;
    }
    return lo;
}

__global__ void k_counts(const int* __restrict__ batch, int* __restrict__ cnt) {
    int b = blockIdx.x * blockDim.x + threadIdx.x;
    if (b < BB) cnt[b] = lowerb(batch, NN, b + 1) - lowerb(batch, NN, b);
}

// ---------------- xdv = ReLU(pooled' @ fcd_w + fcd_b) ----------------
__global__ __launch_bounds__(128) void k_xdv(const float* __restrict__ ps,
                                             const int* __restrict__ cnt,
                                             const float* __restrict__ aff,
                                             const float* __restrict__ w,
                                             const float* __restrict__ bb,
                                             float* __restrict__ xdv) {
    int b = blockIdx.x;
    int j = threadIdx.x;
    __shared__ float p[32];
    if (j < 32) p[j] = aff[j] * ps[b * 32 + j] + (float)cnt[b] * aff[32 + j];
    __syncthreads();
    float acc = bb[j];
#pragma unroll
    for (int c = 0; c < 32; ++c) acc += p[c] * w[c * 128 + j];
    xdv[b * 128 + j] = fmaxf(acc, 0.f);
}

// ---------------- conv branch ----------------
__global__ void k_kT(const float* __restrict__ ck, float* __restrict__ kT) {
    int i = blockIdx.x;
    int t = threadIdx.x;
    int o = t >> 3, k = t & 7;
    kT[(size_t)i * 256 + t] = ck[(size_t)o * (LL * KK) + (size_t)i * KK + k];
}

__global__ __launch_bounds__(256) void k_conv(const int* __restrict__ xt,
                                              const float* __restrict__ kT,
                                              const float* __restrict__ emb,
                                              const float* __restrict__ cb,
                                              float* __restrict__ cbuf) {
    __shared__ float S[VOCAB * 256];
    __shared__ float Em[VOCAB * EMBD];
    int t = threadIdx.x;
    int b = blockIdx.x;
    for (int v = t; v < VOCAB * 256; v += 256) S[v] = 0.f;
    for (int v = t; v < VOCAB * EMBD; v += 256) Em[v] = emb[v];
    __syncthreads();
    const int* row = xt + (size_t)b * LL;
#pragma unroll 4
    for (int i = 0; i < LL; ++i) {
        int v = row[i];
        S[v * 256 + t] += kT[(size_t)i * 256 + t];
    }
    __syncthreads();
    int h = t & 127, half = t >> 7;
    if (h < 121) {
        float acc[16];
        int o0 = half * 16;
#pragma unroll
        for (int o = 0; o < 16; ++o) acc[o] = cb[o0 + o];
        for (int v = 0; v < VOCAB; ++v) {
            float e[8];
#pragma unroll
            for (int k = 0; k < 8; ++k) e[k] = Em[v * EMBD + h + k];
#pragma unroll
            for (int o = 0; o < 16; ++o) {
                float a = acc[o];
#pragma unroll
                for (int k = 0; k < 8; ++k) a += S[v * 256 + (o0 + o) * 8 + k] * e[k];
                acc[o] = a;
            }
        }
#pragma unroll
        for (int o = 0; o < 16; ++o)
            cbuf[(size_t)b * CF + (size_t)(o0 + o) * 121 + h] = acc[o];
    }
}

// ---------------- bias init (rows of `cols` columns get bias[j]) ----------------
__global__ void k_binit(const float* __restrict__ bias, float* __restrict__ out, int mask) {
    int i = blockIdx.x * blockDim.x + threadIdx.x;
    out[i] = bias[i & mask];
}

// ---------------- xtv += c_tile @ w_tile (split-K, LDS-tiled, atomic accumulate) ----------------
__global__ __launch_bounds__(256) void k_xtv(const float* __restrict__ c,
                                             const float* __restrict__ w,
                                             float* __restrict__ xtv) {
    __shared__ float ct[16][484];
    int rb = blockIdx.x >> 3, kc = blockIdx.x & 7;
    int b0 = rb * 16, k0 = kc * 484;
    int tid = threadIdx.x;
#pragma unroll
    for (int r = 0; r < 16; ++r)
        for (int k = tid; k < 484; k += 256)
            ct[r][k] = c[(size_t)(b0 + r) * CF + k0 + k];
    __syncthreads();
    int j = tid & 127, rh = tid >> 7;
    float acc[8];
#pragma unroll
    for (int r = 0; r < 8; ++r) acc[r] = 0.f;
    const float2* ct2 = (const float2*)&ct[0][0];   // row stride = 242 float2
    for (int k2 = 0; k2 < 242; ++k2) {
        float w0 = w[(size_t)(k0 + 2 * k2) * 128 + j];
        float w1 = w[(size_t)(k0 + 2 * k2 + 1) * 128 + j];
#pragma unroll
        for (int r = 0; r < 8; ++r) {
            float2 cv = ct2[(rh * 8 + r) * 242 + k2];
            acc[r] = fmaf(cv.x, w0, fmaf(cv.y, w1, acc[r]));
        }
    }
#pragma unroll
    for (int r = 0; r < 8; ++r)
        atomicAdd(&xtv[(size_t)(b0 + rh * 8 + r) * 128 + j], acc[r]);
}

// ---------------- classifier ----------------
__global__ __launch_bounds__(1024) void k_cls1(const float* __restrict__ xdv,
                                               const float* __restrict__ xtv,
                                               const float* __restrict__ w,
                                               const float* __restrict__ bb,
                                               float* __restrict__ h1) {
    __shared__ float X[8][256];
    int j = threadIdx.x;
    int b0 = blockIdx.x * 8;
    for (int idx = j; idx < 8 * 256; idx += 1024) {
        int r = idx >> 8, k = idx & 255;
        X[r][k] = (k < 128) ? xdv[(b0 + r) * 128 + k] : xtv[(b0 + r) * 128 + (k - 128)];
    }
    __syncthreads();
    float acc[8];
#pragma unroll
    for (int r = 0; r < 8; ++r) acc[r] = bb[j];
    for (int k = 0; k < 256; ++k) {
        float wv = w[(size_t)k * 1024 + j];
#pragma unroll
        for (int r = 0; r < 8; ++r) acc[r] += X[r][k] * wv;
    }
#pragma unroll
    for (int r = 0; r < 8; ++r) h1[(size_t)(b0 + r) * 1024 + j] = fmaxf(acc[r], 0.f);
}

// h2pre += h1_tile @ w_tile (split-K, atomic). out pre-initialized with bias; ReLU in k_cls3.
__global__ __launch_bounds__(256) void k_cls2(const float* __restrict__ h1,
                                              const float* __restrict__ w,
                                              float* __restrict__ h2) {
    __shared__ float X[8][256];
    int rb = blockIdx.x >> 2, kc = blockIdx.x & 3;
    int b0 = rb * 8, k0 = kc * 256;
    int tid = threadIdx.x;
#pragma unroll
    for (int r = 0; r < 8; ++r)
        X[r][tid] = h1[(size_t)(b0 + r) * 1024 + k0 + tid];
    __syncthreads();
    int j = tid;
    float acc[8];
#pragma unroll
    for (int r = 0; r < 8; ++r) acc[r] = 0.f;
    const float2* X2 = (const float2*)&X[0][0];   // row stride = 128 float2
    for (int k2 = 0; k2 < 128; ++k2) {
        float w0 = w[(size_t)(k0 + 2 * k2) * 256 + j];
        float w1 = w[(size_t)(k0 + 2 * k2 + 1) * 256 + j];
#pragma unroll
        for (int r = 0; r < 8; ++r) {
            float2 xv = X2[r * 128 + k2];
            acc[r] = fmaf(xv.x, w0, fmaf(xv.y, w1, acc[r]));
        }
    }
#pragma unroll
    for (int r = 0; r < 8; ++r)
        atomicAdd(&h2[(size_t)(b0 + r) * 256 + j], acc[r]);
}

__global__ __launch_bounds__(256) void k_cls3(const float* __restrict__ h2,
                                              const float* __restrict__ w,
                                              const float* __restrict__ bb,
                                              const float* __restrict__ y,
                                              float* __restrict__ dout) {
    int lane = threadIdx.x & 63;
    int b = (blockIdx.x * blockDim.x + threadIdx.x) >> 6;
    if (b >= BB) return;
    float acc = 0.f;
    for (int k = lane; k < 256; k += 64) acc += fmaxf(h2[(size_t)b * 256 + k], 0.f) * w[k];
#pragma unroll
    for (int off = 32; off; off >>= 1) acc += __shfl_xor(acc, off, 64);
    if (lane == 0) dout[b] = acc + bb[0];
    if (lane == 1) dout[BB + b] = y[b];
}

// ---------------- launch ----------------
extern "C" void kernel_launch(void* const* d_in, const int* in_sizes, int n_in,
                              void* d_out, int out_size, void* d_ws, size_t ws_size,
                              hipStream_t stream) {
    const float* xd = (const float*)d_in[0];
    const int* ei = (const int*)d_in[1];
    const int* batch = (const int*)d_in[2];
    const int* xt = (const int*)d_in[3];
    const float* y = (const float*)d_in[4];
    const float* g1w1 = (const float*)d_in[5];
    const float* g1b1 = (const float*)d_in[6];
    const float* g1w2 = (const float*)d_in[7];
    const float* g1b2 = (const float*)d_in[8];
    const float* grw1 = (const float*)d_in[9];
    const float* grb1 = (const float*)d_in[10];
    const float* grw2 = (const float*)d_in[11];
    const float* grb2 = (const float*)d_in[12];
    const float* bng = (const float*)d_in[13];
    const float* bnb = (const float*)d_in[14];
    const float* fcdw = (const float*)d_in[15];
    const float* fcdb = (const float*)d_in[16];
    const float* emb = (const float*)d_in[17];
    const float* convk = (const float*)d_in[18];
    const float* convb = (const float*)d_in[19];
    const float* fctw = (const float*)d_in[20];
    const float* fctb = (const float*)d_in[21];
    const float* cw1 = (const float*)d_in[22];
    const float* cb1 = (const float*)d_in[23];
    const float* cw2 = (const float*)d_in[24];
    const float* cb2 = (const float*)d_in[25];
    const float* cw3 = (const float*)d_in[26];
    const float* cb3 = (const float*)d_in[27];

    const int* src = ei;
    const int* dst = ei + EE;

    size_t off = 0;
    auto alloc = [&](size_t bytes) {
        size_t o = off;
        off = (off + bytes + 255) & ~(size_t)255;
        return o;
    };
    char* ws = (char*)d_ws;
    size_t o_rp = alloc(4ull * (NN + 1));
    size_t o_col = alloc(4ull * EE);
    size_t o_bc = alloc(4ull * 256);
    size_t o_bb = alloc(4ull * 256);
    size_t o_ha = alloc(2ull * NN * 32);
    size_t o_hb = alloc(2ull * NN * 32);
    size_t o_ag = alloc(2ull * NN * 32);   // also aliased as ebuf (40.1 MB <= 64 MB)
    size_t o_part = alloc(4ull * 2048 * 64);
    size_t o_aff = alloc(4ull * 64);
    size_t o_ps = alloc(4ull * BB * 32);
    size_t o_cnt = alloc(4ull * BB);
    size_t o_xdv = alloc(4ull * BB * 128);
    size_t o_kT = alloc(4ull * LL * 256);
    size_t o_c = alloc(4ull * BB * CF);
    size_t o_xtv = alloc(4ull * BB * 128);
    size_t o_h1 = alloc(4ull * BB * 1024);
    size_t o_h2 = alloc(4ull * BB * 256);

    int* rp = (int*)(ws + o_rp);
    int* col = (int*)(ws + o_col);
    int* bcur = (int*)(ws + o_bc);
    int* bbase = (int*)(ws + o_bb);
    __half* ha = (__half*)(ws + o_ha);
    __half* hb = (__half*)(ws + o_hb);
    __half* ag = (__half*)(ws + o_ag);
    unsigned long long* ebuf = (unsigned long long*)(ws + o_ag);  // alias: dead before first k_agg
    float* part = (float*)(ws + o_part);
    float* aff = (float*)(ws + o_aff);
    float* ps = (float*)(ws + o_ps);
    int* cnt = (int*)(ws + o_cnt);
    float* xdv = (float*)(ws + o_xdv);
    float* kT = (float*)(ws + o_kT);
    float* cbuf = (float*)(ws + o_c);
    float* xtv = (float*)(ws + o_xtv);
    float* h1 = (float*)(ws + o_h1);
    float* h2 = (float*)(ws + o_h2);
    float* dout = (float*)d_out;

    // --- CSR build (bucketed two-pass) ---
    hipMemsetAsync(bcur, 0, 4ull * NB, stream);
    k_bscatter<<<977, 256, 0, stream>>>(src, dst, bcur, ebuf);
    k_bscan<<<1, 256, 0, stream>>>(bcur, bbase);
    k_build<<<NB, 256, 0, stream>>>(ebuf, bbase, bcur, rp, col);

    // --- GIN layers (split agg / mlp) ---
    k_p1<<<2048, 256, 0, stream>>>(xd, g1w1, ha);

    // layer 1
    k_agg<<<2048, 256, 0, stream>>>((const __half2*)ha, rp, col, (__half2*)ag);
    k_mlp<1><<<2048, 256, 0, stream>>>(ag, rp, aff, g1w1, g1b1, g1w2, g1b2, hb, part);
    k_reduce<<<32, 256, 0, stream>>>(part, 2048, bng, bnb, aff);

    const __half* srcbuf = hb;
    __half* dstbuf = ha;
    for (int i = 0; i < 4; ++i) {
        k_agg<<<2048, 256, 0, stream>>>((const __half2*)srcbuf, rp, col, (__half2*)ag);
        k_mlp<0><<<2048, 256, 0, stream>>>(ag, rp, aff,
                                           grw1 + (size_t)i * 1024, grb1 + (size_t)i * 32,
                                           grw2 + (size_t)i * 1024, grb2 + (size_t)i * 32,
                                           dstbuf, part);
        k_reduce<<<32, 256, 0, stream>>>(part, 2048, bng + (i + 1) * 32, bnb + (i + 1) * 32, aff);
        const __half* tmp = srcbuf;
        srcbuf = dstbuf;
        dstbuf = (__half*)tmp;
    }
    // after loop: srcbuf == layer-5 output, aff == layer-5 affine

    // --- pooling + xdv ---
    hipMemsetAsync(ps, 0, 4ull * BB * 32, stream);
    k_pool<<<1024, 256, 0, stream>>>(srcbuf, batch, ps);
    k_counts<<<4, 256, 0, stream>>>(batch, cnt);
    k_xdv<<<BB, 128, 0, stream>>>(ps, cnt, aff, fcdw, fcdb, xdv);

    // --- conv branch ---
    k_kT<<<LL, 256, 0, stream>>>(convk, kT);
    k_conv<<<BB, 256, 0, stream>>>(xt, kT, emb, convb, cbuf);
    k_binit<<<BB * 128 / 256, 256, 0, stream>>>(fctb, xtv, 127);
    k_xtv<<<512, 256, 0, stream>>>(cbuf, fctw, xtv);

    // --- classifier ---
    k_cls1<<<BB / 8, 1024, 0, stream>>>(xdv, xtv, cw1, cb1, h1);
    k_binit<<<BB * 256 / 256, 256, 0, stream>>>(cb2, h2, 255);
    k_cls2<<<512, 256, 0, stream>>>(h1, cw2, h2);
    k_cls3<<<256, 256, 0, stream>>>(h2, cw3, cb3, y, dout);
}

// Round 6
// 1970.820 us; speedup vs baseline: 2.4211x; 1.0894x over previous
//
#include <hip/hip_runtime.h>
#include <hip/hip_bf16.h>
#include <hip/hip_fp16.h>

#define NN 1000000
#define EE 4000000
#define BB 1024
#define DIM 32
#define FXDIM 55
#define EMBD 128
#define VOCAB 26
#define LL 1000
#define NF 32
#define KK 8
#define CF 3872   // 32*121
#define BSH 12
#define NB 245          // ceil(NN / 4096)
#define ESLOT 20480     // padded records per bucket (mean 16.3K, +32 sigma)

typedef _Float16 h2_t __attribute__((ext_vector_type(2)));

__device__ inline float fdot2u(unsigned a, unsigned b, float c) {
#if defined(__has_builtin) && __has_builtin(__builtin_amdgcn_fdot2)
    h2_t ha = __builtin_bit_cast(h2_t, a);
    h2_t hb = __builtin_bit_cast(h2_t, b);
    return __builtin_amdgcn_fdot2(ha, hb, c, false);
#else
    __half2 ha = __builtin_bit_cast(__half2, a);
    __half2 hb = __builtin_bit_cast(__half2, b);
    return fmaf(__low2float(ha), __low2float(hb),
                fmaf(__high2float(ha), __high2float(hb), c));
#endif
}

// every lane ends up holding packed f16 pair (v[2*(lane>>1)], v[2*(lane>>1)+1])
__device__ inline unsigned packpair(float v, int lane) {
    float o = __shfl_xor(v, 1, 32);
    float lo = (lane & 1) ? o : v;
    float hi = (lane & 1) ? v : o;
    __half2 p = __floats2half2_rn(lo, hi);
    return __builtin_bit_cast(unsigned, p);
}

// ---------------- CSR build: bucketed two-pass (write-coalescing-friendly) ----------------
__global__ __launch_bounds__(256) void k_bscatter(const int* __restrict__ src,
                                                  const int* __restrict__ dst,
                                                  int* __restrict__ bcur,
                                                  unsigned long long* __restrict__ ebuf) {
    __shared__ unsigned long long rec[4096];
    __shared__ short bid[4096];
    __shared__ int cnt[NB], pref[NB], gb[NB];
    __shared__ int sc[256];
    int t = threadIdx.x;
    for (int i = t; i < NB; i += 256) cnt[i] = 0;
    __syncthreads();
    size_t base = (size_t)blockIdx.x * 4096;
    int b_[16], s_[16], d_[16];
#pragma unroll
    for (int j = 0; j < 16; ++j) {
        size_t e = base + (size_t)j * 256 + t;
        if (e < EE) {
            int d = dst[e];
            b_[j] = d >> BSH;
            d_[j] = d;
            s_[j] = src[e];
            atomicAdd(&cnt[b_[j]], 1);
        } else b_[j] = -1;
    }
    __syncthreads();
    int v = (t < NB) ? cnt[t] : 0;
    sc[t] = v;
    __syncthreads();
    for (int off = 1; off < 256; off <<= 1) {
        int a = (t >= off) ? sc[t - off] : 0;
        __syncthreads();
        sc[t] += a;
        __syncthreads();
    }
    if (t < NB) {
        pref[t] = sc[t] - v;
        gb[t] = (v > 0) ? atomicAdd(&bcur[t], v) : 0;
        cnt[t] = 0;
    }
    __syncthreads();
#pragma unroll
    for (int j = 0; j < 16; ++j) {
        if (b_[j] >= 0) {
            int r = atomicAdd(&cnt[b_[j]], 1);
            int p = pref[b_[j]] + r;
            rec[p] = ((unsigned long long)(unsigned)d_[j] << 32) | (unsigned)s_[j];
            bid[p] = (short)b_[j];
        }
    }
    __syncthreads();
    int total = sc[NB - 1];
    for (int p = t; p < total; p += 256) {
        int b = bid[p];
        size_t gp = (size_t)b * ESLOT + gb[b] + (p - pref[b]);
        ebuf[gp] = rec[p];
    }
}

__global__ void k_bscan(const int* __restrict__ bcnt, int* __restrict__ bbase) {
    __shared__ int sh[256];
    int t = threadIdx.x;
    int v = (t < NB) ? bcnt[t] : 0;
    sh[t] = v;
    __syncthreads();
    for (int off = 1; off < 256; off <<= 1) {
        int a = (t >= off) ? sh[t - off] : 0;
        __syncthreads();
        sh[t] += a;
        __syncthreads();
    }
    if (t < NB) bbase[t] = sh[t] - v;
}

__global__ __launch_bounds__(256) void k_build(const unsigned long long* __restrict__ ebuf,
                                               const int* __restrict__ bbase,
                                               const int* __restrict__ bcnt,
                                               int* __restrict__ rowptr,
                                               int* __restrict__ col) {
    __shared__ int cnt[4096];
    __shared__ int pref[4096];
    __shared__ int part[256];
    int b = blockIdx.x, t = threadIdx.x;
    int n0 = b << BSH;
    int nmax = min(4096, NN - n0);
    for (int i = t; i < 4096; i += 256) cnt[i] = 0;
    __syncthreads();
    int e0 = bbase[b];
    int ne = bcnt[b];
    const unsigned long long* eb = ebuf + (size_t)b * ESLOT;
    for (int e = t; e < ne; e += 256) {
        int d = (int)(eb[e] >> 32) & 4095;
        atomicAdd(&cnt[d], 1);
    }
    __syncthreads();
    int s = 0, loc[16];
    int bi = t * 16;
#pragma unroll
    for (int j = 0; j < 16; ++j) { loc[j] = s; s += cnt[bi + j]; }
    part[t] = s;
    __syncthreads();
    for (int off = 1; off < 256; off <<= 1) {
        int a = (t >= off) ? part[t - off] : 0;
        __syncthreads();
        part[t] += a;
        __syncthreads();
    }
    int pb = part[t] - s;
#pragma unroll
    for (int j = 0; j < 16; ++j) pref[bi + j] = pb + loc[j];
    __syncthreads();
    for (int i = t; i < nmax; i += 256) rowptr[n0 + i] = e0 + pref[i];
    if (b == NB - 1 && t == 0) rowptr[NN] = EE;
    __syncthreads();
    for (int e = t; e < ne; e += 256) {
        unsigned long long r = eb[e];
        int d = (int)(r >> 32) & 4095;
        int p = atomicAdd(&pref[d], 1);
        col[e0 + p] = (int)(r & 0xffffffffu);
    }
}

// ---------------- layer-1 projection p = xd @ w1 (LDS-transposed, shfl-free) ----------------
// Tile of 256 nodes staged transposed into LDS (stride 257 -> conflict-free).
// Each lane owns one node, accumulates all 32 channels; w1 reads are wave-uniform -> s_load.
__global__ __launch_bounds__(256) void k_p1(const float* __restrict__ xd,
                                            const float* __restrict__ w1,
                                            __half* __restrict__ out) {
    __shared__ float xT[FXDIM * 257];
    int tid = threadIdx.x;
    int lane = tid & 63;
    int wid = tid >> 6;
    const int ntiles = (NN + 255) / 256;
    for (int tile = blockIdx.x; tile < ntiles; tile += gridDim.x) {
        int n0 = tile * 256;
        int nrem = min(256, NN - n0);
        int total = nrem * FXDIM;
        const float* gsrc = xd + (size_t)n0 * FXDIM;
        __syncthreads();
        for (int idx = tid; idx < total; idx += 256) {
            int n = idx / FXDIM;
            int k = idx - n * FXDIM;
            xT[k * 257 + n] = gsrc[idx];
        }
        __syncthreads();
        int n = wid * 64 + lane;
        if (n < nrem) {
            float acc[32];
#pragma unroll
            for (int c = 0; c < 32; ++c) acc[c] = 0.f;
            for (int k = 0; k < FXDIM; ++k) {
                float x = xT[k * 257 + n];
                const float* wr = w1 + k * 32;
#pragma unroll
                for (int c = 0; c < 32; ++c) acc[c] = fmaf(x, wr[c], acc[c]);
            }
            unsigned pk[16];
#pragma unroll
            for (int c = 0; c < 16; ++c) {
                __half2 p = __floats2half2_rn(acc[2 * c], acc[2 * c + 1]);
                pk[c] = __builtin_bit_cast(unsigned, p);
            }
            uint4* dst = (uint4*)(out + (size_t)(n0 + n) * 32);
            const uint4* s4 = (const uint4*)pk;
#pragma unroll
            for (int q = 0; q < 4; ++q) dst[q] = s4[q];
        }
    }
}

// ---------------- aggregation: agg[i] = h[i] + sum_{j->i} h[j]  (f16 rows, 64B) ----------------
__global__ __launch_bounds__(256) void k_agg(const __half2* __restrict__ hsrc,
                                             const int* __restrict__ rowptr,
                                             const int* __restrict__ colidx,
                                             __half2* __restrict__ agg) {
    int l = threadIdx.x & 15;
    int gid = (blockIdx.x * blockDim.x + threadIdx.x) >> 4;
    int ng = (gridDim.x * blockDim.x) >> 4;
    for (int i = gid; i < NN; i += ng) {
        int r0 = rowptr[i], r1 = rowptr[i + 1];
        __half2 s = hsrc[(size_t)i * 16 + l];
        float ax0 = __low2float(s), ay0 = __high2float(s);
        float ax1 = 0.f, ay1 = 0.f, ax2 = 0.f, ay2 = 0.f, ax3 = 0.f, ay3 = 0.f;
        int e = r0;
        for (; e + 4 <= r1; e += 4) {
            int s0 = colidx[e], s1 = colidx[e + 1], s2 = colidx[e + 2], s3 = colidx[e + 3];
            __half2 v0 = hsrc[(size_t)s0 * 16 + l];
            __half2 v1 = hsrc[(size_t)s1 * 16 + l];
            __half2 v2 = hsrc[(size_t)s2 * 16 + l];
            __half2 v3 = hsrc[(size_t)s3 * 16 + l];
            ax0 += __low2float(v0); ay0 += __high2float(v0);
            ax1 += __low2float(v1); ay1 += __high2float(v1);
            ax2 += __low2float(v2); ay2 += __high2float(v2);
            ax3 += __low2float(v3); ay3 += __high2float(v3);
        }
        if (e + 2 <= r1) {
            int s0 = colidx[e], s1 = colidx[e + 1];
            __half2 v0 = hsrc[(size_t)s0 * 16 + l];
            __half2 v1 = hsrc[(size_t)s1 * 16 + l];
            ax1 += __low2float(v0); ay1 += __high2float(v0);
            ax2 += __low2float(v1); ay2 += __high2float(v1);
            e += 2;
        }
        if (e < r1) {
            __half2 v0 = hsrc[(size_t)colidx[e] * 16 + l];
            ax3 += __low2float(v0); ay3 += __high2float(v0);
        }
        float sx = (ax0 + ax1) + (ax2 + ax3);
        float sy = (ay0 + ay1) + (ay2 + ay3);
        agg[(size_t)i * 16 + l] = __floats2half2_rn(sx, sy);
    }
}

// ---------------- MLP + BN-stat kernel (streaming, dot2-f16) ----------------
template <int FIRST>
__global__ __launch_bounds__(256) void k_mlp(const __half* __restrict__ agg,
                                             const int* __restrict__ rowptr,
                                             const float* __restrict__ aff,
                                             const float* __restrict__ w1,
                                             const float* __restrict__ b1,
                                             const float* __restrict__ w2,
                                             const float* __restrict__ b2,
                                             __half* __restrict__ hdst,
                                             float* __restrict__ partial) {
    const int lane = threadIdx.x & 31;
    unsigned wp1[16], wp2[16];
    if (!FIRST) {
#pragma unroll
        for (int kp = 0; kp < 16; ++kp) {
            __half2 p = __floats2half2_rn(w1[(2 * kp) * 32 + lane], w1[(2 * kp + 1) * 32 + lane]);
            wp1[kp] = __builtin_bit_cast(unsigned, p);
        }
    }
#pragma unroll
    for (int kp = 0; kp < 16; ++kp) {
        __half2 p = __floats2half2_rn(w2[(2 * kp) * 32 + lane], w2[(2 * kp + 1) * 32 + lane]);
        wp2[kp] = __builtin_bit_cast(unsigned, p);
    }
    float b1v = b1[lane], b2v = b2[lane];
    float sA = 1.f, tA = 0.f;
    if (!FIRST) { sA = aff[lane]; tA = aff[32 + lane]; }

    float psum = 0.f, psq = 0.f;
    int gid = (blockIdx.x * blockDim.x + threadIdx.x) >> 5;
    int ng = (gridDim.x * blockDim.x) >> 5;
    for (int i = gid; i < NN; i += ng) {
        float u = __half2float(agg[(size_t)i * 32 + lane]);
        float z;
        if (FIRST) {
            z = fmaxf(u + b1v, 0.f);
        } else {
            int d = rowptr[i + 1] - rowptr[i];
            u = sA * u + (float)(d + 1) * tA;
            unsigned pu = packpair(u, lane);
            float a = b1v;
#pragma unroll
            for (int kp = 0; kp < 16; ++kp)
                a = fdot2u(__shfl(pu, 2 * kp, 32), wp1[kp], a);
            z = fmaxf(a, 0.f);
        }
        unsigned pz = packpair(z, lane);
        float a2 = b2v;
#pragma unroll
        for (int kp = 0; kp < 16; ++kp)
            a2 = fdot2u(__shfl(pz, 2 * kp, 32), wp2[kp], a2);
        float hv = fmaxf(a2, 0.f);
        hdst[(size_t)i * 32 + lane] = __float2half_rn(hv);
        psum += hv;
        psq += hv * hv;
    }
    __shared__ float red[8][64];
    int wid = threadIdx.x >> 5;
    red[wid][lane] = psum;
    red[wid][32 + lane] = psq;
    __syncthreads();
    if (threadIdx.x < 64) {
        float s = 0.f;
#pragma unroll
        for (int w = 0; w < 8; ++w) s += red[w][threadIdx.x];
        partial[(size_t)blockIdx.x * 64 + threadIdx.x] = s;
    }
}

// ---------------- finalize BN stats -> affine s,t (1 block/channel) ----------------
__global__ __launch_bounds__(256) void k_reduce(const float* __restrict__ partial, int nblocks,
                                                const float* __restrict__ g, const float* __restrict__ bt,
                                                float* __restrict__ aff) {
    int c = blockIdx.x;   // channel 0..31
    int t = threadIdx.x;
    double s = 0.0, q = 0.0;
    for (int b = t; b < nblocks; b += 256) {
        s += (double)partial[(size_t)b * 64 + c];
        q += (double)partial[(size_t)b * 64 + 32 + c];
    }
    __shared__ double shs[256], shq[256];
    shs[t] = s; shq[t] = q;
    __syncthreads();
    for (int off = 128; off; off >>= 1) {
        if (t < off) { shs[t] += shs[t + off]; shq[t] += shq[t + off]; }
        __syncthreads();
    }
    if (t == 0) {
        double mean = shs[0] / (double)NN;
        double var = shq[0] / (double)NN - mean * mean;
        float r = (float)rsqrt(var + 1e-5);
        float sv = g[c] * r;
        aff[c] = sv;
        aff[32 + c] = bt[c] - (float)mean * sv;
    }
}

// ---------------- pooling (xd_batch sorted -> run-length + atomics) ----------------
__global__ __launch_bounds__(256) void k_pool(const __half* __restrict__ h,
                                              const int* __restrict__ batch,
                                              float* __restrict__ ps) {
    int lane = threadIdx.x & 31;
    int g = threadIdx.x >> 5;
    const int chunk = (NN + gridDim.x - 1) / gridDim.x;
    int s0 = blockIdx.x * chunk;
    int s1 = min(NN, s0 + chunk);
    int curb = -1;
    float acc = 0.f;
    for (int i = s0 + g; i < s1; i += 8) {
        int b = batch[i];
        if (b != curb) {
            if (curb >= 0) atomicAdd(&ps[curb * 32 + lane], acc);
            acc = 0.f;
            curb = b;
        }
        acc += __half2float(h[(size_t)i * 32 + lane]);
    }
    if (curb >= 0) atomicAdd(&ps[curb * 32 + lane], acc);
}

__device__ int lowerb(const int* a, int n, int key) {
    int lo = 0, hi = n;
    while (lo < hi) {
        int m = (lo + hi) >> 1;
        if (a[m] < key) lo = m + 1;
        else hi = m;
    }
    return lo;
}

__global__ void k_counts(const int* __restrict__ batch, int* __restrict__ cnt) {
    int b = blockIdx.x * blockDim.x + threadIdx.x;
    if (b < BB) cnt[b] = lowerb(batch, NN, b + 1) - lowerb(batch, NN, b);
}

// ---------------- xdv = ReLU(pooled' @ fcd_w + fcd_b) ----------------
__global__ __launch_bounds__(128) void k_xdv(const float* __restrict__ ps,
                                             const int* __restrict__ cnt,
                                             const float* __restrict__ aff,
                                             const float* __restrict__ w,
                                             const float* __restrict__ bb,
                                             float* __restrict__ xdv) {
    int b = blockIdx.x;
    int j = threadIdx.x;
    __shared__ float p[32];
    if (j < 32) p[j] = aff[j] * ps[b * 32 + j] + (float)cnt[b] * aff[32 + j];
    __syncthreads();
    float acc = bb[j];
#pragma unroll
    for (int c = 0; c < 32; ++c) acc += p[c] * w[c * 128 + j];
    xdv[b * 128 + j] = fmaxf(acc, 0.f);
}

// ---------------- conv branch ----------------
__global__ void k_kT(const float* __restrict__ ck, float* __restrict__ kT) {
    int i = blockIdx.x;
    int t = threadIdx.x;
    int o = t >> 3, k = t & 7;
    kT[(size_t)i * 256 + t] = ck[(size_t)o * (LL * KK) + (size_t)i * KK + k];
}

__global__ __launch_bounds__(256) void k_conv(const int* __restrict__ xt,
                                              const float* __restrict__ kT,
                                              const float* __restrict__ emb,
                                              const float* __restrict__ cb,
                                              float* __restrict__ cbuf) {
    __shared__ float S[VOCAB * 256];
    __shared__ float Em[VOCAB * EMBD];
    int t = threadIdx.x;
    int b = blockIdx.x;
    for (int v = t; v < VOCAB * 256; v += 256) S[v] = 0.f;
    for (int v = t; v < VOCAB * EMBD; v += 256) Em[v] = emb[v];
    __syncthreads();
    const int* row = xt + (size_t)b * LL;
#pragma unroll 4
    for (int i = 0; i < LL; ++i) {
        int v = row[i];
        S[v * 256 + t] += kT[(size_t)i * 256 + t];
    }
    __syncthreads();
    int h = t & 127, half = t >> 7;
    if (h < 121) {
        float acc[16];
        int o0 = half * 16;
#pragma unroll
        for (int o = 0; o < 16; ++o) acc[o] = cb[o0 + o];
        for (int v = 0; v < VOCAB; ++v) {
            float e[8];
#pragma unroll
            for (int k = 0; k < 8; ++k) e[k] = Em[v * EMBD + h + k];
#pragma unroll
            for (int o = 0; o < 16; ++o) {
                float a = acc[o];
#pragma unroll
                for (int k = 0; k < 8; ++k) a += S[v * 256 + (o0 + o) * 8 + k] * e[k];
                acc[o] = a;
            }
        }
#pragma unroll
        for (int o = 0; o < 16; ++o)
            cbuf[(size_t)b * CF + (size_t)(o0 + o) * 121 + h] = acc[o];
    }
}

// ---------------- bias init (rows of `cols` columns get bias[j]) ----------------
__global__ void k_binit(const float* __restrict__ bias, float* __restrict__ out, int mask) {
    int i = blockIdx.x * blockDim.x + threadIdx.x;
    out[i] = bias[i & mask];
}

// ---------------- xtv += c_tile @ w_tile (split-K, LDS-tiled, atomic accumulate) ----------------
__global__ __launch_bounds__(256) void k_xtv(const float* __restrict__ c,
                                             const float* __restrict__ w,
                                             float* __restrict__ xtv) {
    __shared__ float ct[16][484];
    int rb = blockIdx.x >> 3, kc = blockIdx.x & 7;
    int b0 = rb * 16, k0 = kc * 484;
    int tid = threadIdx.x;
#pragma unroll
    for (int r = 0; r < 16; ++r)
        for (int k = tid; k < 484; k += 256)
            ct[r][k] = c[(size_t)(b0 + r) * CF + k0 + k];
    __syncthreads();
    int j = tid & 127, rh = tid >> 7;
    float acc[8];
#pragma unroll
    for (int r = 0; r < 8; ++r) acc[r] = 0.f;
    const float2* ct2 = (const float2*)&ct[0][0];   // row stride = 242 float2
    for (int k2 = 0; k2 < 242; ++k2) {
        float w0 = w[(size_t)(k0 + 2 * k2) * 128 + j];
        float w1 = w[(size_t)(k0 + 2 * k2 + 1) * 128 + j];
#pragma unroll
        for (int r = 0; r < 8; ++r) {
            float2 cv = ct2[(rh * 8 + r) * 242 + k2];
            acc[r] = fmaf(cv.x, w0, fmaf(cv.y, w1, acc[r]));
        }
    }
#pragma unroll
    for (int r = 0; r < 8; ++r)
        atomicAdd(&xtv[(size_t)(b0 + rh * 8 + r) * 128 + j], acc[r]);
}

// ---------------- classifier ----------------
__global__ __launch_bounds__(1024) void k_cls1(const float* __restrict__ xdv,
                                               const float* __restrict__ xtv,
                                               const float* __restrict__ w,
                                               const float* __restrict__ bb,
                                               float* __restrict__ h1) {
    __shared__ float X[8][256];
    int j = threadIdx.x;
    int b0 = blockIdx.x * 8;
    for (int idx = j; idx < 8 * 256; idx += 1024) {
        int r = idx >> 8, k = idx & 255;
        X[r][k] = (k < 128) ? xdv[(b0 + r) * 128 + k] : xtv[(b0 + r) * 128 + (k - 128)];
    }
    __syncthreads();
    float acc[8];
#pragma unroll
    for (int r = 0; r < 8; ++r) acc[r] = bb[j];
    for (int k = 0; k < 256; ++k) {
        float wv = w[(size_t)k * 1024 + j];
#pragma unroll
        for (int r = 0; r < 8; ++r) acc[r] += X[r][k] * wv;
    }
#pragma unroll
    for (int r = 0; r < 8; ++r) h1[(size_t)(b0 + r) * 1024 + j] = fmaxf(acc[r], 0.f);
}

// h2pre += h1_tile @ w_tile (split-K, atomic). out pre-initialized with bias; ReLU in k_cls3.
__global__ __launch_bounds__(256) void k_cls2(const float* __restrict__ h1,
                                              const float* __restrict__ w,
                                              float* __restrict__ h2) {
    __shared__ float X[8][256];
    int rb = blockIdx.x >> 2, kc = blockIdx.x & 3;
    int b0 = rb * 8, k0 = kc * 256;
    int tid = threadIdx.x;
#pragma unroll
    for (int r = 0; r < 8; ++r)
        X[r][tid] = h1[(size_t)(b0 + r) * 1024 + k0 + tid];
    __syncthreads();
    int j = tid;
    float acc[8];
#pragma unroll
    for (int r = 0; r < 8; ++r) acc[r] = 0.f;
    const float2* X2 = (const float2*)&X[0][0];   // row stride = 128 float2
    for (int k2 = 0; k2 < 128; ++k2) {
        float w0 = w[(size_t)(k0 + 2 * k2) * 256 + j];
        float w1 = w[(size_t)(k0 + 2 * k2 + 1) * 256 + j];
#pragma unroll
        for (int r = 0; r < 8; ++r) {
            float2 xv = X2[r * 128 + k2];
            acc[r] = fmaf(xv.x, w0, fmaf(xv.y, w1, acc[r]));
        }
    }
#pragma unroll
    for (int r = 0; r < 8; ++r)
        atomicAdd(&h2[(size_t)(b0 + r) * 256 + j], acc[r]);
}

__global__ __launch_bounds__(256) void k_cls3(const float* __restrict__ h2,
                                              const float* __restrict__ w,
                                              const float* __restrict__ bb,
                                              const float* __restrict__ y,
                                              float* __restrict__ dout) {
    int lane = threadIdx.x & 63;
    int b = (blockIdx.x * blockDim.x + threadIdx.x) >> 6;
    if (b >= BB) return;
    float acc = 0.f;
    for (int k = lane; k < 256; k += 64) acc += fmaxf(h2[(size_t)b * 256 + k], 0.f) * w[k];
#pragma unroll
    for (int off = 32; off; off >>= 1) acc += __shfl_xor(acc, off, 64);
    if (lane == 0) dout[b] = acc + bb[0];
    if (lane == 1) dout[BB + b] = y[b];
}

// ---------------- launch ----------------
extern "C" void kernel_launch(void* const* d_in, const int* in_sizes, int n_in,
                              void* d_out, int out_size, void* d_ws, size_t ws_size,
                              hipStream_t stream) {
    const float* xd = (const float*)d_in[0];
    const int* ei = (const int*)d_in[1];
    const int* batch = (const int*)d_in[2];
    const int* xt = (const int*)d_in[3];
    const float* y = (const float*)d_in[4];
    const float* g1w1 = (const float*)d_in[5];
    const float* g1b1 = (const float*)d_in[6];
    const float* g1w2 = (const float*)d_in[7];
    const float* g1b2 = (const float*)d_in[8];
    const float* grw1 = (const float*)d_in[9];
    const float* grb1 = (const float*)d_in[10];
    const float* grw2 = (const float*)d_in[11];
    const float* grb2 = (const float*)d_in[12];
    const float* bng = (const float*)d_in[13];
    const float* bnb = (const float*)d_in[14];
    const float* fcdw = (const float*)d_in[15];
    const float* fcdb = (const float*)d_in[16];
    const float* emb = (const float*)d_in[17];
    const float* convk = (const float*)d_in[18];
    const float* convb = (const float*)d_in[19];
    const float* fctw = (const float*)d_in[20];
    const float* fctb = (const float*)d_in[21];
    const float* cw1 = (const float*)d_in[22];
    const float* cb1 = (const float*)d_in[23];
    const float* cw2 = (const float*)d_in[24];
    const float* cb2 = (const float*)d_in[25];
    const float* cw3 = (const float*)d_in[26];
    const float* cb3 = (const float*)d_in[27];

    const int* src = ei;
    const int* dst = ei + EE;

    size_t off = 0;
    auto alloc = [&](size_t bytes) {
        size_t o = off;
        off = (off + bytes + 255) & ~(size_t)255;
        return o;
    };
    char* ws = (char*)d_ws;
    size_t o_rp = alloc(4ull * (NN + 1));
    size_t o_col = alloc(4ull * EE);
    size_t o_bc = alloc(4ull * 256);
    size_t o_bb = alloc(4ull * 256);
    size_t o_ha = alloc(2ull * NN * 32);
    size_t o_hb = alloc(2ull * NN * 32);
    size_t o_ag = alloc(2ull * NN * 32);   // also aliased as ebuf (40.1 MB <= 64 MB)
    size_t o_part = alloc(4ull * 2048 * 64);
    size_t o_aff = alloc(4ull * 64);
    size_t o_ps = alloc(4ull * BB * 32);
    size_t o_cnt = alloc(4ull * BB);
    size_t o_xdv = alloc(4ull * BB * 128);
    size_t o_kT = alloc(4ull * LL * 256);
    size_t o_c = alloc(4ull * BB * CF);
    size_t o_xtv = alloc(4ull * BB * 128);
    size_t o_h1 = alloc(4ull * BB * 1024);
    size_t o_h2 = alloc(4ull * BB * 256);

    int* rp = (int*)(ws + o_rp);
    int* col = (int*)(ws + o_col);
    int* bcur = (int*)(ws + o_bc);
    int* bbase = (int*)(ws + o_bb);
    __half* ha = (__half*)(ws + o_ha);
    __half* hb = (__half*)(ws + o_hb);
    __half* ag = (__half*)(ws + o_ag);
    unsigned long long* ebuf = (unsigned long long*)(ws + o_ag);  // alias: dead before first k_agg
    float* part = (float*)(ws + o_part);
    float* aff = (float*)(ws + o_aff);
    float* ps = (float*)(ws + o_ps);
    int* cnt = (int*)(ws + o_cnt);
    float* xdv = (float*)(ws + o_xdv);
    float* kT = (float*)(ws + o_kT);
    float* cbuf = (float*)(ws + o_c);
    float* xtv = (float*)(ws + o_xtv);
    float* h1 = (float*)(ws + o_h1);
    float* h2 = (float*)(ws + o_h2);
    float* dout = (float*)d_out;

    // --- CSR build (bucketed two-pass) ---
    hipMemsetAsync(bcur, 0, 4ull * NB, stream);
    k_bscatter<<<977, 256, 0, stream>>>(src, dst, bcur, ebuf);
    k_bscan<<<1, 256, 0, stream>>>(bcur, bbase);
    k_build<<<NB, 256, 0, stream>>>(ebuf, bbase, bcur, rp, col);

    // --- GIN layers (split agg / mlp) ---
    k_p1<<<2048, 256, 0, stream>>>(xd, g1w1, ha);

    // layer 1
    k_agg<<<2048, 256, 0, stream>>>((const __half2*)ha, rp, col, (__half2*)ag);
    k_mlp<1><<<2048, 256, 0, stream>>>(ag, rp, aff, g1w1, g1b1, g1w2, g1b2, hb, part);
    k_reduce<<<32, 256, 0, stream>>>(part, 2048, bng, bnb, aff);

    const __half* srcbuf = hb;
    __half* dstbuf = ha;
    for (int i = 0; i < 4; ++i) {
        k_agg<<<2048, 256, 0, stream>>>((const __half2*)srcbuf, rp, col, (__half2*)ag);
        k_mlp<0><<<2048, 256, 0, stream>>>(ag, rp, aff,
                                           grw1 + (size_t)i * 1024, grb1 + (size_t)i * 32,
                                           grw2 + (size_t)i * 1024, grb2 + (size_t)i * 32,
                                           dstbuf, part);
        k_reduce<<<32, 256, 0, stream>>>(part, 2048, bng + (i + 1) * 32, bnb + (i + 1) * 32, aff);
        const __half* tmp = srcbuf;
        srcbuf = dstbuf;
        dstbuf = (__half*)tmp;
    }
    // after loop: srcbuf == layer-5 output, aff == layer-5 affine

    // --- pooling + xdv ---
    hipMemsetAsync(ps, 0, 4ull * BB * 32, stream);
    k_pool<<<1024, 256, 0, stream>>>(srcbuf, batch, ps);
    k_counts<<<4, 256, 0, stream>>>(batch, cnt);
    k_xdv<<<BB, 128, 0, stream>>>(ps, cnt, aff, fcdw, fcdb, xdv);

    // --- conv branch ---
    k_kT<<<LL, 256, 0, stream>>>(convk, kT);
    k_conv<<<BB, 256, 0, stream>>>(xt, kT, emb, convb, cbuf);
    k_binit<<<BB * 128 / 256, 256, 0, stream>>>(fctb, xtv, 127);
    k_xtv<<<512, 256, 0, stream>>>(cbuf, fctw, xtv);

    // --- classifier ---
    k_cls1<<<BB / 8, 1024, 0, stream>>>(xdv, xtv, cw1, cb1, h1);
    k_binit<<<BB * 256 / 256, 256, 0, stream>>>(cb2, h2, 255);
    k_cls2<<<512, 256, 0, stream>>>(h1, cw2, h2);
    k_cls3<<<256, 256, 0, stream>>>(h2, cw3, cb3, y, dout);
}

// Round 7
// 1238.703 us; speedup vs baseline: 3.8520x; 1.5910x over previous
//
#include <hip/hip_runtime.h>
#include <hip/hip_bf16.h>
#include <hip/hip_fp16.h>

#define NN 1000000
#define EE 4000000
#define BB 1024
#define DIM 32
#define FXDIM 55
#define EMBD 128
#define VOCAB 26
#define LL 1000
#define NF 32
#define KK 8
#define CF 3872   // 32*121
#define BSH 12
#define NB 245          // ceil(NN / 4096)
#define ESLOT 20480     // padded records per bucket

typedef _Float16 f16x8 __attribute__((ext_vector_type(8)));
typedef float f32x4 __attribute__((ext_vector_type(4)));

// ---------------- CSR build: bucketed two-pass (write-coalescing-friendly) ----------------
__global__ __launch_bounds__(256) void k_bscatter(const int* __restrict__ src,
                                                  const int* __restrict__ dst,
                                                  int* __restrict__ bcur,
                                                  unsigned long long* __restrict__ ebuf) {
    __shared__ unsigned long long rec[4096];
    __shared__ short bid[4096];
    __shared__ int cnt[NB], pref[NB], gb[NB];
    __shared__ int sc[256];
    int t = threadIdx.x;
    for (int i = t; i < NB; i += 256) cnt[i] = 0;
    __syncthreads();
    size_t base = (size_t)blockIdx.x * 4096;
    int b_[16], s_[16], d_[16];
#pragma unroll
    for (int j = 0; j < 16; ++j) {
        size_t e = base + (size_t)j * 256 + t;
        if (e < EE) {
            int d = dst[e];
            b_[j] = d >> BSH;
            d_[j] = d;
            s_[j] = src[e];
            atomicAdd(&cnt[b_[j]], 1);
        } else b_[j] = -1;
    }
    __syncthreads();
    int v = (t < NB) ? cnt[t] : 0;
    sc[t] = v;
    __syncthreads();
    for (int off = 1; off < 256; off <<= 1) {
        int a = (t >= off) ? sc[t - off] : 0;
        __syncthreads();
        sc[t] += a;
        __syncthreads();
    }
    if (t < NB) {
        pref[t] = sc[t] - v;
        gb[t] = (v > 0) ? atomicAdd(&bcur[t], v) : 0;
        cnt[t] = 0;
    }
    __syncthreads();
#pragma unroll
    for (int j = 0; j < 16; ++j) {
        if (b_[j] >= 0) {
            int r = atomicAdd(&cnt[b_[j]], 1);
            int p = pref[b_[j]] + r;
            rec[p] = ((unsigned long long)(unsigned)d_[j] << 32) | (unsigned)s_[j];
            bid[p] = (short)b_[j];
        }
    }
    __syncthreads();
    int total = sc[NB - 1];
    for (int p = t; p < total; p += 256) {
        int b = bid[p];
        size_t gp = (size_t)b * ESLOT + gb[b] + (p - pref[b]);
        ebuf[gp] = rec[p];
    }
}

__global__ void k_bscan(const int* __restrict__ bcnt, int* __restrict__ bbase) {
    __shared__ int sh[256];
    int t = threadIdx.x;
    int v = (t < NB) ? bcnt[t] : 0;
    sh[t] = v;
    __syncthreads();
    for (int off = 1; off < 256; off <<= 1) {
        int a = (t >= off) ? sh[t - off] : 0;
        __syncthreads();
        sh[t] += a;
        __syncthreads();
    }
    if (t < NB) bbase[t] = sh[t] - v;
}

__global__ __launch_bounds__(256) void k_build(const unsigned long long* __restrict__ ebuf,
                                               const int* __restrict__ bbase,
                                               const int* __restrict__ bcnt,
                                               int* __restrict__ rowptr,
                                               int* __restrict__ col) {
    __shared__ int cnt[4096];
    __shared__ int pref[4096];
    __shared__ int part[256];
    int b = blockIdx.x, t = threadIdx.x;
    int n0 = b << BSH;
    int nmax = min(4096, NN - n0);
    for (int i = t; i < 4096; i += 256) cnt[i] = 0;
    __syncthreads();
    int e0 = bbase[b];
    int ne = bcnt[b];
    const unsigned long long* eb = ebuf + (size_t)b * ESLOT;
    for (int e = t; e < ne; e += 256) {
        int d = (int)(eb[e] >> 32) & 4095;
        atomicAdd(&cnt[d], 1);
    }
    __syncthreads();
    int s = 0, loc[16];
    int bi = t * 16;
#pragma unroll
    for (int j = 0; j < 16; ++j) { loc[j] = s; s += cnt[bi + j]; }
    part[t] = s;
    __syncthreads();
    for (int off = 1; off < 256; off <<= 1) {
        int a = (t >= off) ? part[t - off] : 0;
        __syncthreads();
        part[t] += a;
        __syncthreads();
    }
    int pb = part[t] - s;
#pragma unroll
    for (int j = 0; j < 16; ++j) pref[bi + j] = pb + loc[j];
    __syncthreads();
    for (int i = t; i < nmax; i += 256) rowptr[n0 + i] = e0 + pref[i];
    if (b == NB - 1 && t == 0) rowptr[NN] = EE;
    __syncthreads();
    for (int e = t; e < ne; e += 256) {
        unsigned long long r = eb[e];
        int d = (int)(r >> 32) & 4095;
        int p = atomicAdd(&pref[d], 1);
        col[e0 + p] = (int)(r & 0xffffffffu);
    }
}

// ---------------- layer-1 projection p = xd @ w1 (LDS-transposed, shfl-free) ----------------
__global__ __launch_bounds__(256) void k_p1(const float* __restrict__ xd,
                                            const float* __restrict__ w1,
                                            __half* __restrict__ out) {
    __shared__ float xT[FXDIM * 257];
    int tid = threadIdx.x;
    int lane = tid & 63;
    int wid = tid >> 6;
    const int ntiles = (NN + 255) / 256;
    for (int tile = blockIdx.x; tile < ntiles; tile += gridDim.x) {
        int n0 = tile * 256;
        int nrem = min(256, NN - n0);
        int total = nrem * FXDIM;
        const float* gsrc = xd + (size_t)n0 * FXDIM;
        __syncthreads();
        for (int idx = tid; idx < total; idx += 256) {
            int n = idx / FXDIM;
            int k = idx - n * FXDIM;
            xT[k * 257 + n] = gsrc[idx];
        }
        __syncthreads();
        int n = wid * 64 + lane;
        if (n < nrem) {
            float acc[32];
#pragma unroll
            for (int c = 0; c < 32; ++c) acc[c] = 0.f;
            for (int k = 0; k < FXDIM; ++k) {
                float x = xT[k * 257 + n];
                const float* wr = w1 + k * 32;
#pragma unroll
                for (int c = 0; c < 32; ++c) acc[c] = fmaf(x, wr[c], acc[c]);
            }
            unsigned pk[16];
#pragma unroll
            for (int c = 0; c < 16; ++c) {
                __half2 p = __floats2half2_rn(acc[2 * c], acc[2 * c + 1]);
                pk[c] = __builtin_bit_cast(unsigned, p);
            }
            uint4* dst = (uint4*)(out + (size_t)(n0 + n) * 32);
            const uint4* s4 = (const uint4*)pk;
#pragma unroll
            for (int q = 0; q < 4; ++q) dst[q] = s4[q];
        }
    }
}

// ---------------- aggregation: agg[i] = h[i] + sum_{j->i} h[j]  (f16 rows, 64B) ----------------
__global__ __launch_bounds__(256) void k_agg(const __half2* __restrict__ hsrc,
                                             const int* __restrict__ rowptr,
                                             const int* __restrict__ colidx,
                                             __half2* __restrict__ agg) {
    int l = threadIdx.x & 15;
    int gid = (blockIdx.x * blockDim.x + threadIdx.x) >> 4;
    int ng = (gridDim.x * blockDim.x) >> 4;
    for (int i = gid; i < NN; i += ng) {
        int r0 = rowptr[i], r1 = rowptr[i + 1];
        __half2 s = hsrc[(size_t)i * 16 + l];
        float ax0 = __low2float(s), ay0 = __high2float(s);
        float ax1 = 0.f, ay1 = 0.f, ax2 = 0.f, ay2 = 0.f, ax3 = 0.f, ay3 = 0.f;
        int e = r0;
        for (; e + 4 <= r1; e += 4) {
            int s0 = colidx[e], s1 = colidx[e + 1], s2 = colidx[e + 2], s3 = colidx[e + 3];
            __half2 v0 = hsrc[(size_t)s0 * 16 + l];
            __half2 v1 = hsrc[(size_t)s1 * 16 + l];
            __half2 v2 = hsrc[(size_t)s2 * 16 + l];
            __half2 v3 = hsrc[(size_t)s3 * 16 + l];
            ax0 += __low2float(v0); ay0 += __high2float(v0);
            ax1 += __low2float(v1); ay1 += __high2float(v1);
            ax2 += __low2float(v2); ay2 += __high2float(v2);
            ax3 += __low2float(v3); ay3 += __high2float(v3);
        }
        if (e + 2 <= r1) {
            int s0 = colidx[e], s1 = colidx[e + 1];
            __half2 v0 = hsrc[(size_t)s0 * 16 + l];
            __half2 v1 = hsrc[(size_t)s1 * 16 + l];
            ax1 += __low2float(v0); ay1 += __high2float(v0);
            ax2 += __low2float(v1); ay2 += __high2float(v1);
            e += 2;
        }
        if (e < r1) {
            __half2 v0 = hsrc[(size_t)colidx[e] * 16 + l];
            ax3 += __low2float(v0); ay3 += __high2float(v0);
        }
        float sx = (ax0 + ax1) + (ax2 + ax3);
        float sy = (ay0 + ay1) + (ay2 + ay3);
        agg[(size_t)i * 16 + l] = __floats2half2_rn(sx, sy);
    }
}

// ---------------- per-layer weight fragment prep (BN folded into W1) ----------------
// B-frag layout for mfma_f32_16x16x32_f16: lane l holds B[k=(l>>4)*8+i][j=c*16+(l&15)].
template <int FIRST>
__global__ __launch_bounds__(64) void k_wfrag(const float* __restrict__ aff,
                                              const float* __restrict__ w1,
                                              const float* __restrict__ w2,
                                              __half* __restrict__ wf1,
                                              __half* __restrict__ wf2,
                                              float* __restrict__ tv) {
    int l = threadIdx.x;
    int kbase = (l >> 4) * 8;
    int jj = l & 15;
#pragma unroll
    for (int c = 0; c < 2; ++c) {
        int j = c * 16 + jj;
        __half v1[8], v2[8];
#pragma unroll
        for (int i = 0; i < 8; ++i) {
            int k = kbase + i;
            float s = FIRST ? 1.f : aff[k];
            v1[i] = __float2half_rn(s * w1[k * 32 + j]);
            v2[i] = __float2half_rn(w2[k * 32 + j]);
        }
        *(uint4*)&wf1[(size_t)(c * 64 + l) * 8] = *(const uint4*)v1;
        *(uint4*)&wf2[(size_t)(c * 64 + l) * 8] = *(const uint4*)v2;
    }
    if (!FIRST && l < 32) {
        float acc = 0.f;
        for (int k = 0; k < 32; ++k) acc += aff[32 + k] * w1[k * 32 + l];
        tv[l] = acc;
    }
}

// ---------------- MFMA MLP + BN-stat kernel ----------------
// Per 16-node tile per wave: A-frag from agg, GEMM1 (C init = b1 + cnt*tv), ReLU,
// LDS transpose (within-wave, stride 36), GEMM2 (C init = b2), ReLU + stats, store.
template <int FIRST>
__global__ __launch_bounds__(256) void k_mlp(const __half* __restrict__ agg,
                                             const int* __restrict__ rowptr,
                                             const __half* __restrict__ wf1,
                                             const __half* __restrict__ wf2,
                                             const float* __restrict__ tv,
                                             const float* __restrict__ b1,
                                             const float* __restrict__ b2,
                                             __half* __restrict__ hdst,
                                             float* __restrict__ partial) {
    __shared__ float zb[4][16 * 36];
    __shared__ float sred[4][64];
    int tid = threadIdx.x;
    int l = tid & 63;
    int wid = tid >> 6;
    int rowg = l >> 4;
    int lan16 = l & 15;

    f16x8 bw2_0 = __builtin_bit_cast(f16x8, *(const uint4*)&wf2[(size_t)(0 * 64 + l) * 8]);
    f16x8 bw2_1 = __builtin_bit_cast(f16x8, *(const uint4*)&wf2[(size_t)(1 * 64 + l) * 8]);
    f16x8 bw1_0{}, bw1_1{};
    float tv0 = 0.f, tv1 = 0.f, b1c0 = 0.f, b1c1 = 0.f;
    float b1v[8];
    if (FIRST) {
#pragma unroll
        for (int i = 0; i < 8; ++i) b1v[i] = b1[rowg * 8 + i];
    } else {
        bw1_0 = __builtin_bit_cast(f16x8, *(const uint4*)&wf1[(size_t)(0 * 64 + l) * 8]);
        bw1_1 = __builtin_bit_cast(f16x8, *(const uint4*)&wf1[(size_t)(1 * 64 + l) * 8]);
        tv0 = tv[lan16];
        tv1 = tv[16 + lan16];
        b1c0 = b1[lan16];
        b1c1 = b1[16 + lan16];
    }
    float b2c0 = b2[lan16], b2c1 = b2[16 + lan16];
    float* zw = zb[wid];
    float ps0 = 0.f, ps1 = 0.f, pq0 = 0.f, pq1 = 0.f;
    int gw = (blockIdx.x * 256 + tid) >> 6;
    int ngw = (gridDim.x * 256) >> 6;
    for (int t = gw; t < NN / 16; t += ngw) {
        int n0 = t * 16;
        uint4 au = *(const uint4*)(agg + (size_t)(n0 + lan16) * 32 + rowg * 8);
        f16x8 af = __builtin_bit_cast(f16x8, au);
        f16x8 za;
        if (FIRST) {
#pragma unroll
            for (int i = 0; i < 8; ++i)
                za[i] = (_Float16)fmaxf((float)af[i] + b1v[i], 0.f);
        } else {
            int rbase = n0 + rowg * 4;
            int4 rv = *(const int4*)&rowptr[rbase];
            int rext = rowptr[rbase + 4];
            float c0 = (float)(rv.y - rv.x + 1);
            float c1 = (float)(rv.z - rv.y + 1);
            float c2 = (float)(rv.w - rv.z + 1);
            float c3 = (float)(rext - rv.w + 1);
            f32x4 ac0, ac1;
            ac0[0] = fmaf(c0, tv0, b1c0); ac1[0] = fmaf(c0, tv1, b1c1);
            ac0[1] = fmaf(c1, tv0, b1c0); ac1[1] = fmaf(c1, tv1, b1c1);
            ac0[2] = fmaf(c2, tv0, b1c0); ac1[2] = fmaf(c2, tv1, b1c1);
            ac0[3] = fmaf(c3, tv0, b1c0); ac1[3] = fmaf(c3, tv1, b1c1);
            ac0 = __builtin_amdgcn_mfma_f32_16x16x32_f16(af, bw1_0, ac0, 0, 0, 0);
            ac1 = __builtin_amdgcn_mfma_f32_16x16x32_f16(af, bw1_1, ac1, 0, 0, 0);
#pragma unroll
            for (int r = 0; r < 4; ++r) {
                int node = rowg * 4 + r;
                zw[node * 36 + lan16] = fmaxf(ac0[r], 0.f);
                zw[node * 36 + 16 + lan16] = fmaxf(ac1[r], 0.f);
            }
            f32x4 z0 = *(const f32x4*)&zw[lan16 * 36 + rowg * 8];
            f32x4 z1 = *(const f32x4*)&zw[lan16 * 36 + rowg * 8 + 4];
#pragma unroll
            for (int i = 0; i < 4; ++i) {
                za[i] = (_Float16)z0[i];
                za[4 + i] = (_Float16)z1[i];
            }
        }
        f32x4 h0, h1;
#pragma unroll
        for (int r = 0; r < 4; ++r) { h0[r] = b2c0; h1[r] = b2c1; }
        h0 = __builtin_amdgcn_mfma_f32_16x16x32_f16(za, bw2_0, h0, 0, 0, 0);
        h1 = __builtin_amdgcn_mfma_f32_16x16x32_f16(za, bw2_1, h1, 0, 0, 0);
#pragma unroll
        for (int r = 0; r < 4; ++r) {
            float v0 = fmaxf(h0[r], 0.f);
            float v1 = fmaxf(h1[r], 0.f);
            ps0 += v0; pq0 += v0 * v0;
            ps1 += v1; pq1 += v1 * v1;
            int node = rowg * 4 + r;
            zw[node * 36 + lan16] = v0;
            zw[node * 36 + 16 + lan16] = v1;
        }
        int sn = l >> 2, sc = (l & 3) * 8;
        f32x4 hv0 = *(const f32x4*)&zw[sn * 36 + sc];
        f32x4 hv1 = *(const f32x4*)&zw[sn * 36 + sc + 4];
        __half hh[8];
#pragma unroll
        for (int i = 0; i < 4; ++i) {
            hh[i] = __float2half_rn(hv0[i]);
            hh[4 + i] = __float2half_rn(hv1[i]);
        }
        *(uint4*)(hdst + (size_t)(n0 + sn) * 32 + sc) = *(const uint4*)hh;
    }
    // stats: lane holds chan lan16 (ps0) and 16+lan16 (ps1); reduce across rowg groups
    ps0 += __shfl_xor(ps0, 16, 64); ps0 += __shfl_xor(ps0, 32, 64);
    ps1 += __shfl_xor(ps1, 16, 64); ps1 += __shfl_xor(ps1, 32, 64);
    pq0 += __shfl_xor(pq0, 16, 64); pq0 += __shfl_xor(pq0, 32, 64);
    pq1 += __shfl_xor(pq1, 16, 64); pq1 += __shfl_xor(pq1, 32, 64);
    if (l < 16) {
        sred[wid][lan16] = ps0;
        sred[wid][16 + lan16] = ps1;
        sred[wid][32 + lan16] = pq0;
        sred[wid][48 + lan16] = pq1;
    }
    __syncthreads();
    if (tid < 64) {
        float s = sred[0][tid] + sred[1][tid] + sred[2][tid] + sred[3][tid];
        partial[(size_t)blockIdx.x * 64 + tid] = s;
    }
}

// ---------------- finalize BN stats -> affine s,t (1 block/channel) ----------------
__global__ __launch_bounds__(256) void k_reduce(const float* __restrict__ partial, int nblocks,
                                                const float* __restrict__ g, const float* __restrict__ bt,
                                                float* __restrict__ aff) {
    int c = blockIdx.x;   // channel 0..31
    int t = threadIdx.x;
    double s = 0.0, q = 0.0;
    for (int b = t; b < nblocks; b += 256) {
        s += (double)partial[(size_t)b * 64 + c];
        q += (double)partial[(size_t)b * 64 + 32 + c];
    }
    __shared__ double shs[256], shq[256];
    shs[t] = s; shq[t] = q;
    __syncthreads();
    for (int off = 128; off; off >>= 1) {
        if (t < off) { shs[t] += shs[t + off]; shq[t] += shq[t + off]; }
        __syncthreads();
    }
    if (t == 0) {
        double mean = shs[0] / (double)NN;
        double var = shq[0] / (double)NN - mean * mean;
        float r = (float)rsqrt(var + 1e-5);
        float sv = g[c] * r;
        aff[c] = sv;
        aff[32 + c] = bt[c] - (float)mean * sv;
    }
}

// ---------------- pooling (xd_batch sorted -> run-length + atomics) ----------------
__global__ __launch_bounds__(256) void k_pool(const __half* __restrict__ h,
                                              const int* __restrict__ batch,
                                              float* __restrict__ ps) {
    int lane = threadIdx.x & 31;
    int g = threadIdx.x >> 5;
    const int chunk = (NN + gridDim.x - 1) / gridDim.x;
    int s0 = blockIdx.x * chunk;
    int s1 = min(NN, s0 + chunk);
    int curb = -1;
    float acc = 0.f;
    for (int i = s0 + g; i < s1; i += 8) {
        int b = batch[i];
        if (b != curb) {
            if (curb >= 0) atomicAdd(&ps[curb * 32 + lane], acc);
            acc = 0.f;
            curb = b;
        }
        acc += __half2float(h[(size_t)i * 32 + lane]);
    }
    if (curb >= 0) atomicAdd(&ps[curb * 32 + lane], acc);
}

__device__ int lowerb(const int* a, int n, int key) {
    int lo = 0, hi = n;
    while (lo < hi) {
        int m = (lo + hi) >> 1;
        if (a[m] < key) lo = m + 1;
        else hi = m;
    }
    return lo;
}

__global__ void k_counts(const int* __restrict__ batch, int* __restrict__ cnt) {
    int b = blockIdx.x * blockDim.x + threadIdx.x;
    if (b < BB) cnt[b] = lowerb(batch, NN, b + 1) - lowerb(batch, NN, b);
}

// ---------------- xdv = ReLU(pooled' @ fcd_w + fcd_b) ----------------
__global__ __launch_bounds__(128) void k_xdv(const float* __restrict__ ps,
                                             const int* __restrict__ cnt,
                                             const float* __restrict__ aff,
                                             const float* __restrict__ w,
                                             const float* __restrict__ bb,
                                             float* __restrict__ xdv) {
    int b = blockIdx.x;
    int j = threadIdx.x;
    __shared__ float p[32];
    if (j < 32) p[j] = aff[j] * ps[b * 32 + j] + (float)cnt[b] * aff[32 + j];
    __syncthreads();
    float acc = bb[j];
#pragma unroll
    for (int c = 0; c < 32; ++c) acc += p[c] * w[c * 128 + j];
    xdv[b * 128 + j] = fmaxf(acc, 0.f);
}

// ---------------- conv branch ----------------
__global__ void k_kT(const float* __restrict__ ck, float* __restrict__ kT) {
    int i = blockIdx.x;
    int t = threadIdx.x;
    int o = t >> 3, k = t & 7;
    kT[(size_t)i * 256 + t] = ck[(size_t)o * (LL * KK) + (size_t)i * KK + k];
}

__global__ __launch_bounds__(256) void k_conv(const int* __restrict__ xt,
                                              const float* __restrict__ kT,
                                              const float* __restrict__ emb,
                                              const float* __restrict__ cb,
                                              float* __restrict__ cbuf) {
    __shared__ float S[VOCAB * 256];
    __shared__ float Em[VOCAB * EMBD];
    int t = threadIdx.x;
    int b = blockIdx.x;
    for (int v = t; v < VOCAB * 256; v += 256) S[v] = 0.f;
    for (int v = t; v < VOCAB * EMBD; v += 256) Em[v] = emb[v];
    __syncthreads();
    const int* row = xt + (size_t)b * LL;
#pragma unroll 4
    for (int i = 0; i < LL; ++i) {
        int v = row[i];
        S[v * 256 + t] += kT[(size_t)i * 256 + t];
    }
    __syncthreads();
    int h = t & 127, half = t >> 7;
    if (h < 121) {
        float acc[16];
        int o0 = half * 16;
#pragma unroll
        for (int o = 0; o < 16; ++o) acc[o] = cb[o0 + o];
        for (int v = 0; v < VOCAB; ++v) {
            float e[8];
#pragma unroll
            for (int k = 0; k < 8; ++k) e[k] = Em[v * EMBD + h + k];
#pragma unroll
            for (int o = 0; o < 16; ++o) {
                float a = acc[o];
#pragma unroll
                for (int k = 0; k < 8; ++k) a += S[v * 256 + (o0 + o) * 8 + k] * e[k];
                acc[o] = a;
            }
        }
#pragma unroll
        for (int o = 0; o < 16; ++o)
            cbuf[(size_t)b * CF + (size_t)(o0 + o) * 121 + h] = acc[o];
    }
}

// ---------------- bias init ----------------
__global__ void k_binit(const float* __restrict__ bias, float* __restrict__ out, int mask) {
    int i = blockIdx.x * blockDim.x + threadIdx.x;
    out[i] = bias[i & mask];
}

// ---------------- xtv += c_tile @ w_tile (split-K, LDS-tiled, atomic accumulate) ----------------
__global__ __launch_bounds__(256) void k_xtv(const float* __restrict__ c,
                                             const float* __restrict__ w,
                                             float* __restrict__ xtv) {
    __shared__ float ct[16][484];
    int rb = blockIdx.x >> 3, kc = blockIdx.x & 7;
    int b0 = rb * 16, k0 = kc * 484;
    int tid = threadIdx.x;
#pragma unroll
    for (int r = 0; r < 16; ++r)
        for (int k = tid; k < 484; k += 256)
            ct[r][k] = c[(size_t)(b0 + r) * CF + k0 + k];
    __syncthreads();
    int j = tid & 127, rh = tid >> 7;
    float acc[8];
#pragma unroll
    for (int r = 0; r < 8; ++r) acc[r] = 0.f;
    const float2* ct2 = (const float2*)&ct[0][0];
    for (int k2 = 0; k2 < 242; ++k2) {
        float w0 = w[(size_t)(k0 + 2 * k2) * 128 + j];
        float w1 = w[(size_t)(k0 + 2 * k2 + 1) * 128 + j];
#pragma unroll
        for (int r = 0; r < 8; ++r) {
            float2 cv = ct2[(rh * 8 + r) * 242 + k2];
            acc[r] = fmaf(cv.x, w0, fmaf(cv.y, w1, acc[r]));
        }
    }
#pragma unroll
    for (int r = 0; r < 8; ++r)
        atomicAdd(&xtv[(size_t)(b0 + rh * 8 + r) * 128 + j], acc[r]);
}

// ---------------- classifier ----------------
__global__ __launch_bounds__(1024) void k_cls1(const float* __restrict__ xdv,
                                               const float* __restrict__ xtv,
                                               const float* __restrict__ w,
                                               const float* __restrict__ bb,
                                               float* __restrict__ h1) {
    __shared__ float X[8][256];
    int j = threadIdx.x;
    int b0 = blockIdx.x * 8;
    for (int idx = j; idx < 8 * 256; idx += 1024) {
        int r = idx >> 8, k = idx & 255;
        X[r][k] = (k < 128) ? xdv[(b0 + r) * 128 + k] : xtv[(b0 + r) * 128 + (k - 128)];
    }
    __syncthreads();
    float acc[8];
#pragma unroll
    for (int r = 0; r < 8; ++r) acc[r] = bb[j];
    for (int k = 0; k < 256; ++k) {
        float wv = w[(size_t)k * 1024 + j];
#pragma unroll
        for (int r = 0; r < 8; ++r) acc[r] += X[r][k] * wv;
    }
#pragma unroll
    for (int r = 0; r < 8; ++r) h1[(size_t)(b0 + r) * 1024 + j] = fmaxf(acc[r], 0.f);
}

__global__ __launch_bounds__(256) void k_cls2(const float* __restrict__ h1,
                                              const float* __restrict__ w,
                                              float* __restrict__ h2) {
    __shared__ float X[8][256];
    int rb = blockIdx.x >> 2, kc = blockIdx.x & 3;
    int b0 = rb * 8, k0 = kc * 256;
    int tid = threadIdx.x;
#pragma unroll
    for (int r = 0; r < 8; ++r)
        X[r][tid] = h1[(size_t)(b0 + r) * 1024 + k0 + tid];
    __syncthreads();
    int j = tid;
    float acc[8];
#pragma unroll
    for (int r = 0; r < 8; ++r) acc[r] = 0.f;
    const float2* X2 = (const float2*)&X[0][0];
    for (int k2 = 0; k2 < 128; ++k2) {
        float w0 = w[(size_t)(k0 + 2 * k2) * 256 + j];
        float w1 = w[(size_t)(k0 + 2 * k2 + 1) * 256 + j];
#pragma unroll
        for (int r = 0; r < 8; ++r) {
            float2 xv = X2[r * 128 + k2];
            acc[r] = fmaf(xv.x, w0, fmaf(xv.y, w1, acc[r]));
        }
    }
#pragma unroll
    for (int r = 0; r < 8; ++r)
        atomicAdd(&h2[(size_t)(b0 + r) * 256 + j], acc[r]);
}

__global__ __launch_bounds__(256) void k_cls3(const float* __restrict__ h2,
                                              const float* __restrict__ w,
                                              const float* __restrict__ bb,
                                              const float* __restrict__ y,
                                              float* __restrict__ dout) {
    int lane = threadIdx.x & 63;
    int b = (blockIdx.x * blockDim.x + threadIdx.x) >> 6;
    if (b >= BB) return;
    float acc = 0.f;
    for (int k = lane; k < 256; k += 64) acc += fmaxf(h2[(size_t)b * 256 + k], 0.f) * w[k];
#pragma unroll
    for (int off = 32; off; off >>= 1) acc += __shfl_xor(acc, off, 64);
    if (lane == 0) dout[b] = acc + bb[0];
    if (lane == 1) dout[BB + b] = y[b];
}

// ---------------- launch ----------------
extern "C" void kernel_launch(void* const* d_in, const int* in_sizes, int n_in,
                              void* d_out, int out_size, void* d_ws, size_t ws_size,
                              hipStream_t stream) {
    const float* xd = (const float*)d_in[0];
    const int* ei = (const int*)d_in[1];
    const int* batch = (const int*)d_in[2];
    const int* xt = (const int*)d_in[3];
    const float* y = (const float*)d_in[4];
    const float* g1w1 = (const float*)d_in[5];
    const float* g1b1 = (const float*)d_in[6];
    const float* g1w2 = (const float*)d_in[7];
    const float* g1b2 = (const float*)d_in[8];
    const float* grw1 = (const float*)d_in[9];
    const float* grb1 = (const float*)d_in[10];
    const float* grw2 = (const float*)d_in[11];
    const float* grb2 = (const float*)d_in[12];
    const float* bng = (const float*)d_in[13];
    const float* bnb = (const float*)d_in[14];
    const float* fcdw = (const float*)d_in[15];
    const float* fcdb = (const float*)d_in[16];
    const float* emb = (const float*)d_in[17];
    const float* convk = (const float*)d_in[18];
    const float* convb = (const float*)d_in[19];
    const float* fctw = (const float*)d_in[20];
    const float* fctb = (const float*)d_in[21];
    const float* cw1 = (const float*)d_in[22];
    const float* cb1 = (const float*)d_in[23];
    const float* cw2 = (const float*)d_in[24];
    const float* cb2 = (const float*)d_in[25];
    const float* cw3 = (const float*)d_in[26];
    const float* cb3 = (const float*)d_in[27];

    const int* src = ei;
    const int* dst = ei + EE;

    size_t off = 0;
    auto alloc = [&](size_t bytes) {
        size_t o = off;
        off = (off + bytes + 255) & ~(size_t)255;
        return o;
    };
    char* ws = (char*)d_ws;
    size_t o_rp = alloc(4ull * (NN + 1));
    size_t o_col = alloc(4ull * EE);
    size_t o_bc = alloc(4ull * 256);
    size_t o_bb = alloc(4ull * 256);
    size_t o_ha = alloc(2ull * NN * 32);
    size_t o_hb = alloc(2ull * NN * 32);
    size_t o_ag = alloc(2ull * NN * 32);   // also aliased as ebuf (40.1 MB <= 64 MB)
    size_t o_part = alloc(4ull * 2048 * 64);
    size_t o_aff = alloc(4ull * 64);
    size_t o_wf1 = alloc(2ull * 1024);
    size_t o_wf2 = alloc(2ull * 1024);
    size_t o_tv = alloc(4ull * 32);
    size_t o_ps = alloc(4ull * BB * 32);
    size_t o_cnt = alloc(4ull * BB);
    size_t o_xdv = alloc(4ull * BB * 128);
    size_t o_kT = alloc(4ull * LL * 256);
    size_t o_c = alloc(4ull * BB * CF);
    size_t o_xtv = alloc(4ull * BB * 128);
    size_t o_h1 = alloc(4ull * BB * 1024);
    size_t o_h2 = alloc(4ull * BB * 256);

    int* rp = (int*)(ws + o_rp);
    int* col = (int*)(ws + o_col);
    int* bcur = (int*)(ws + o_bc);
    int* bbase = (int*)(ws + o_bb);
    __half* ha = (__half*)(ws + o_ha);
    __half* hb = (__half*)(ws + o_hb);
    __half* ag = (__half*)(ws + o_ag);
    unsigned long long* ebuf = (unsigned long long*)(ws + o_ag);
    float* part = (float*)(ws + o_part);
    float* aff = (float*)(ws + o_aff);
    __half* wf1 = (__half*)(ws + o_wf1);
    __half* wf2 = (__half*)(ws + o_wf2);
    float* tvb = (float*)(ws + o_tv);
    float* ps = (float*)(ws + o_ps);
    int* cnt = (int*)(ws + o_cnt);
    float* xdv = (float*)(ws + o_xdv);
    float* kT = (float*)(ws + o_kT);
    float* cbuf = (float*)(ws + o_c);
    float* xtv = (float*)(ws + o_xtv);
    float* h1 = (float*)(ws + o_h1);
    float* h2 = (float*)(ws + o_h2);
    float* dout = (float*)d_out;

    // --- CSR build (bucketed two-pass) ---
    hipMemsetAsync(bcur, 0, 4ull * NB, stream);
    k_bscatter<<<977, 256, 0, stream>>>(src, dst, bcur, ebuf);
    k_bscan<<<1, 256, 0, stream>>>(bcur, bbase);
    k_build<<<NB, 256, 0, stream>>>(ebuf, bbase, bcur, rp, col);

    // --- GIN layers (agg / MFMA-mlp) ---
    k_p1<<<2048, 256, 0, stream>>>(xd, g1w1, ha);

    // layer 1
    k_wfrag<1><<<1, 64, 0, stream>>>(aff, g1w1, g1w2, wf1, wf2, tvb);
    k_agg<<<2048, 256, 0, stream>>>((const __half2*)ha, rp, col, (__half2*)ag);
    k_mlp<1><<<1024, 256, 0, stream>>>(ag, rp, wf1, wf2, tvb, g1b1, g1b2, hb, part);
    k_reduce<<<32, 256, 0, stream>>>(part, 1024, bng, bnb, aff);

    const __half* srcbuf = hb;
    __half* dstbuf = ha;
    for (int i = 0; i < 4; ++i) {
        k_wfrag<0><<<1, 64, 0, stream>>>(aff, grw1 + (size_t)i * 1024, grw2 + (size_t)i * 1024,
                                         wf1, wf2, tvb);
        k_agg<<<2048, 256, 0, stream>>>((const __half2*)srcbuf, rp, col, (__half2*)ag);
        k_mlp<0><<<1024, 256, 0, stream>>>(ag, rp, wf1, wf2, tvb,
                                           grb1 + (size_t)i * 32, grb2 + (size_t)i * 32,
                                           dstbuf, part);
        k_reduce<<<32, 256, 0, stream>>>(part, 1024, bng + (i + 1) * 32, bnb + (i + 1) * 32, aff);
        const __half* tmp = srcbuf;
        srcbuf = dstbuf;
        dstbuf = (__half*)tmp;
    }
    // after loop: srcbuf == layer-5 output, aff == layer-5 affine

    // --- pooling + xdv ---
    hipMemsetAsync(ps, 0, 4ull * BB * 32, stream);
    k_pool<<<1024, 256, 0, stream>>>(srcbuf, batch, ps);
    k_counts<<<4, 256, 0, stream>>>(batch, cnt);
    k_xdv<<<BB, 128, 0, stream>>>(ps, cnt, aff, fcdw, fcdb, xdv);

    // --- conv branch ---
    k_kT<<<LL, 256, 0, stream>>>(convk, kT);
    k_conv<<<BB, 256, 0, stream>>>(xt, kT, emb, convb, cbuf);
    k_binit<<<BB * 128 / 256, 256, 0, stream>>>(fctb, xtv, 127);
    k_xtv<<<512, 256, 0, stream>>>(cbuf, fctw, xtv);

    // --- classifier ---
    k_cls1<<<BB / 8, 1024, 0, stream>>>(xdv, xtv, cw1, cb1, h1);
    k_binit<<<BB * 256 / 256, 256, 0, stream>>>(cb2, h2, 255);
    k_cls2<<<512, 256, 0, stream>>>(h1, cw2, h2);
    k_cls3<<<256, 256, 0, stream>>>(h2, cw3, cb3, y, dout);
}

// Round 8
// 1154.311 us; speedup vs baseline: 4.1337x; 1.0731x over previous
//
#include <hip/hip_runtime.h>
#include <hip/hip_bf16.h>
#include <hip/hip_fp16.h>

#define NN 1000000
#define EE 4000000
#define BB 1024
#define DIM 32
#define FXDIM 55
#define EMBD 128
#define VOCAB 26
#define LL 1000
#define NF 32
#define KK 8
#define CF 3872   // 32*121
#define BSH 12
#define NB 245          // ceil(NN / 4096)
#define ESLOT 20480     // padded records per bucket

typedef _Float16 f16x8 __attribute__((ext_vector_type(8)));
typedef float f32x4 __attribute__((ext_vector_type(4)));

// ---------------- CSR build: bucketed two-pass (write-coalescing-friendly) ----------------
__global__ __launch_bounds__(256) void k_bscatter(const int* __restrict__ src,
                                                  const int* __restrict__ dst,
                                                  int* __restrict__ bcur,
                                                  unsigned long long* __restrict__ ebuf) {
    __shared__ unsigned long long rec[4096];
    __shared__ short bid[4096];
    __shared__ int cnt[NB], pref[NB], gb[NB];
    __shared__ int sc[256];
    int t = threadIdx.x;
    for (int i = t; i < NB; i += 256) cnt[i] = 0;
    __syncthreads();
    size_t base = (size_t)blockIdx.x * 4096;
    int b_[16], s_[16], d_[16];
#pragma unroll
    for (int j = 0; j < 16; ++j) {
        size_t e = base + (size_t)j * 256 + t;
        if (e < EE) {
            int d = dst[e];
            b_[j] = d >> BSH;
            d_[j] = d;
            s_[j] = src[e];
            atomicAdd(&cnt[b_[j]], 1);
        } else b_[j] = -1;
    }
    __syncthreads();
    int v = (t < NB) ? cnt[t] : 0;
    sc[t] = v;
    __syncthreads();
    for (int off = 1; off < 256; off <<= 1) {
        int a = (t >= off) ? sc[t - off] : 0;
        __syncthreads();
        sc[t] += a;
        __syncthreads();
    }
    if (t < NB) {
        pref[t] = sc[t] - v;
        gb[t] = (v > 0) ? atomicAdd(&bcur[t], v) : 0;
        cnt[t] = 0;
    }
    __syncthreads();
#pragma unroll
    for (int j = 0; j < 16; ++j) {
        if (b_[j] >= 0) {
            int r = atomicAdd(&cnt[b_[j]], 1);
            int p = pref[b_[j]] + r;
            rec[p] = ((unsigned long long)(unsigned)d_[j] << 32) | (unsigned)s_[j];
            bid[p] = (short)b_[j];
        }
    }
    __syncthreads();
    int total = sc[NB - 1];
    for (int p = t; p < total; p += 256) {
        int b = bid[p];
        size_t gp = (size_t)b * ESLOT + gb[b] + (p - pref[b]);
        ebuf[gp] = rec[p];
    }
}

__global__ void k_bscan(const int* __restrict__ bcnt, int* __restrict__ bbase) {
    __shared__ int sh[256];
    int t = threadIdx.x;
    int v = (t < NB) ? bcnt[t] : 0;
    sh[t] = v;
    __syncthreads();
    for (int off = 1; off < 256; off <<= 1) {
        int a = (t >= off) ? sh[t - off] : 0;
        __syncthreads();
        sh[t] += a;
        __syncthreads();
    }
    if (t < NB) bbase[t] = sh[t] - v;
}

__global__ __launch_bounds__(256) void k_build(const unsigned long long* __restrict__ ebuf,
                                               const int* __restrict__ bbase,
                                               const int* __restrict__ bcnt,
                                               int* __restrict__ rowptr,
                                               int* __restrict__ col) {
    __shared__ int cnt[4096];
    __shared__ int pref[4096];
    __shared__ int part[256];
    int b = blockIdx.x, t = threadIdx.x;
    int n0 = b << BSH;
    int nmax = min(4096, NN - n0);
    for (int i = t; i < 4096; i += 256) cnt[i] = 0;
    __syncthreads();
    int e0 = bbase[b];
    int ne = bcnt[b];
    const unsigned long long* eb = ebuf + (size_t)b * ESLOT;
    for (int e = t; e < ne; e += 256) {
        int d = (int)(eb[e] >> 32) & 4095;
        atomicAdd(&cnt[d], 1);
    }
    __syncthreads();
    int s = 0, loc[16];
    int bi = t * 16;
#pragma unroll
    for (int j = 0; j < 16; ++j) { loc[j] = s; s += cnt[bi + j]; }
    part[t] = s;
    __syncthreads();
    for (int off = 1; off < 256; off <<= 1) {
        int a = (t >= off) ? part[t - off] : 0;
        __syncthreads();
        part[t] += a;
        __syncthreads();
    }
    int pb = part[t] - s;
#pragma unroll
    for (int j = 0; j < 16; ++j) pref[bi + j] = pb + loc[j];
    __syncthreads();
    for (int i = t; i < nmax; i += 256) rowptr[n0 + i] = e0 + pref[i];
    if (b == NB - 1 && t == 0) rowptr[NN] = EE;
    __syncthreads();
    for (int e = t; e < ne; e += 256) {
        unsigned long long r = eb[e];
        int d = (int)(r >> 32) & 4095;
        int p = atomicAdd(&pref[d], 1);
        col[e0 + p] = (int)(r & 0xffffffffu);
    }
}

// ---------------- layer-1 projection p = xd @ w1 (direct per-lane, no LDS) ----------------
// Lane owns one node; wave working set 64 rows x 220B = 14KB (L1/L2). w1 via scalar cache.
__global__ __launch_bounds__(256) void k_p1(const float* __restrict__ xd,
                                            const float* __restrict__ w1,
                                            __half* __restrict__ out) {
    int n = blockIdx.x * 256 + threadIdx.x;
    if (n >= NN) return;
    const float* row = xd + (size_t)n * FXDIM;
    float acc[32];
#pragma unroll
    for (int c = 0; c < 32; ++c) acc[c] = 0.f;
#pragma unroll 5
    for (int k = 0; k < FXDIM; ++k) {
        float x = row[k];
        const float* wr = w1 + k * 32;
#pragma unroll
        for (int c = 0; c < 32; ++c) acc[c] = fmaf(x, wr[c], acc[c]);
    }
    __half hh[32];
#pragma unroll
    for (int c = 0; c < 32; ++c) hh[c] = __float2half_rn(acc[c]);
    uint4* dst = (uint4*)(out + (size_t)n * 32);
    const uint4* s4 = (const uint4*)hh;
#pragma unroll
    for (int q = 0; q < 4; ++q) dst[q] = s4[q];
}

// ---------------- per-layer weight fragment prep (BN folded into W1) ----------------
// B-frag layout for mfma_f32_16x16x32_f16: lane l holds B[k=(l>>4)*8+i][j=c*16+(l&15)].
template <int FIRST>
__global__ __launch_bounds__(64) void k_wfrag(const float* __restrict__ aff,
                                              const float* __restrict__ w1,
                                              const float* __restrict__ w2,
                                              __half* __restrict__ wf1,
                                              __half* __restrict__ wf2,
                                              float* __restrict__ tv) {
    int l = threadIdx.x;
    int kbase = (l >> 4) * 8;
    int jj = l & 15;
#pragma unroll
    for (int c = 0; c < 2; ++c) {
        int j = c * 16 + jj;
        __half v1[8], v2[8];
#pragma unroll
        for (int i = 0; i < 8; ++i) {
            int k = kbase + i;
            float s = FIRST ? 1.f : aff[k];
            v1[i] = __float2half_rn(s * w1[k * 32 + j]);
            v2[i] = __float2half_rn(w2[k * 32 + j]);
        }
        *(uint4*)&wf1[(size_t)(c * 64 + l) * 8] = *(const uint4*)v1;
        *(uint4*)&wf2[(size_t)(c * 64 + l) * 8] = *(const uint4*)v2;
    }
    if (!FIRST && l < 32) {
        float acc = 0.f;
        for (int k = 0; k < 32; ++k) acc += aff[32 + k] * w1[k * 32 + l];
        tv[l] = acc;
    }
}

// ---------------- fused GIN layer: gather-agg + MFMA MLP + BN stats ----------------
// Per 16-node tile per wave: lane l gathers node (n0 + l&15), k-slice (l>>4)*8..+7
// (self + CSR neighbors, f32 accum, 2-way unrolled) directly into the MFMA A-frag.
template <int FIRST>
__global__ __launch_bounds__(256) void k_mlp(const __half* __restrict__ hsrc,
                                             const int* __restrict__ rowptr,
                                             const int* __restrict__ colidx,
                                             const __half* __restrict__ wf1,
                                             const __half* __restrict__ wf2,
                                             const float* __restrict__ tv,
                                             const float* __restrict__ b1,
                                             const float* __restrict__ b2,
                                             __half* __restrict__ hdst,
                                             float* __restrict__ partial) {
    __shared__ float zb[4][16 * 36];
    __shared__ float sred[4][64];
    int tid = threadIdx.x;
    int l = tid & 63;
    int wid = tid >> 6;
    int rowg = l >> 4;
    int lan16 = l & 15;

    f16x8 bw2_0 = __builtin_bit_cast(f16x8, *(const uint4*)&wf2[(size_t)(0 * 64 + l) * 8]);
    f16x8 bw2_1 = __builtin_bit_cast(f16x8, *(const uint4*)&wf2[(size_t)(1 * 64 + l) * 8]);
    f16x8 bw1_0{}, bw1_1{};
    float tv0 = 0.f, tv1 = 0.f, b1c0 = 0.f, b1c1 = 0.f;
    float b1v[8];
    if (FIRST) {
#pragma unroll
        for (int i = 0; i < 8; ++i) b1v[i] = b1[rowg * 8 + i];
    } else {
        bw1_0 = __builtin_bit_cast(f16x8, *(const uint4*)&wf1[(size_t)(0 * 64 + l) * 8]);
        bw1_1 = __builtin_bit_cast(f16x8, *(const uint4*)&wf1[(size_t)(1 * 64 + l) * 8]);
        tv0 = tv[lan16];
        tv1 = tv[16 + lan16];
        b1c0 = b1[lan16];
        b1c1 = b1[16 + lan16];
    }
    float b2c0 = b2[lan16], b2c1 = b2[16 + lan16];
    float* zw = zb[wid];
    float ps0 = 0.f, ps1 = 0.f, pq0 = 0.f, pq1 = 0.f;
    int gw = (blockIdx.x * 256 + tid) >> 6;
    int ngw = (gridDim.x * 256) >> 6;
    for (int t = gw; t < NN / 16; t += ngw) {
        int n0 = t * 16;
        int node = n0 + lan16;
        int r0 = rowptr[node], r1 = rowptr[node + 1];
        // gather: self + neighbors, f32 accumulate, 2 chains
        uint4 su = *(const uint4*)(hsrc + (size_t)node * 32 + rowg * 8);
        f16x8 sf = __builtin_bit_cast(f16x8, su);
        float a0[8], a1[8];
#pragma unroll
        for (int i = 0; i < 8; ++i) { a0[i] = (float)sf[i]; a1[i] = 0.f; }
        int e = r0;
        for (; e + 2 <= r1; e += 2) {
            int s0 = colidx[e], s1 = colidx[e + 1];
            uint4 u0 = *(const uint4*)(hsrc + (size_t)s0 * 32 + rowg * 8);
            uint4 u1 = *(const uint4*)(hsrc + (size_t)s1 * 32 + rowg * 8);
            f16x8 f0 = __builtin_bit_cast(f16x8, u0);
            f16x8 f1 = __builtin_bit_cast(f16x8, u1);
#pragma unroll
            for (int i = 0; i < 8; ++i) { a0[i] += (float)f0[i]; a1[i] += (float)f1[i]; }
        }
        if (e < r1) {
            uint4 u0 = *(const uint4*)(hsrc + (size_t)colidx[e] * 32 + rowg * 8);
            f16x8 f0 = __builtin_bit_cast(f16x8, u0);
#pragma unroll
            for (int i = 0; i < 8; ++i) a1[i] += (float)f0[i];
        }
        f16x8 za;
        if (FIRST) {
#pragma unroll
            for (int i = 0; i < 8; ++i)
                za[i] = (_Float16)fmaxf(a0[i] + a1[i] + b1v[i], 0.f);
        } else {
            f16x8 af;
#pragma unroll
            for (int i = 0; i < 8; ++i) af[i] = (_Float16)(a0[i] + a1[i]);
            int rbase = n0 + rowg * 4;
            int4 rv = *(const int4*)&rowptr[rbase];
            int rext = rowptr[rbase + 4];
            float c0 = (float)(rv.y - rv.x + 1);
            float c1 = (float)(rv.z - rv.y + 1);
            float c2 = (float)(rv.w - rv.z + 1);
            float c3 = (float)(rext - rv.w + 1);
            f32x4 ac0, ac1;
            ac0[0] = fmaf(c0, tv0, b1c0); ac1[0] = fmaf(c0, tv1, b1c1);
            ac0[1] = fmaf(c1, tv0, b1c0); ac1[1] = fmaf(c1, tv1, b1c1);
            ac0[2] = fmaf(c2, tv0, b1c0); ac1[2] = fmaf(c2, tv1, b1c1);
            ac0[3] = fmaf(c3, tv0, b1c0); ac1[3] = fmaf(c3, tv1, b1c1);
            ac0 = __builtin_amdgcn_mfma_f32_16x16x32_f16(af, bw1_0, ac0, 0, 0, 0);
            ac1 = __builtin_amdgcn_mfma_f32_16x16x32_f16(af, bw1_1, ac1, 0, 0, 0);
#pragma unroll
            for (int r = 0; r < 4; ++r) {
                int nd = rowg * 4 + r;
                zw[nd * 36 + lan16] = fmaxf(ac0[r], 0.f);
                zw[nd * 36 + 16 + lan16] = fmaxf(ac1[r], 0.f);
            }
            f32x4 z0 = *(const f32x4*)&zw[lan16 * 36 + rowg * 8];
            f32x4 z1 = *(const f32x4*)&zw[lan16 * 36 + rowg * 8 + 4];
#pragma unroll
            for (int i = 0; i < 4; ++i) {
                za[i] = (_Float16)z0[i];
                za[4 + i] = (_Float16)z1[i];
            }
        }
        f32x4 h0, h1;
#pragma unroll
        for (int r = 0; r < 4; ++r) { h0[r] = b2c0; h1[r] = b2c1; }
        h0 = __builtin_amdgcn_mfma_f32_16x16x32_f16(za, bw2_0, h0, 0, 0, 0);
        h1 = __builtin_amdgcn_mfma_f32_16x16x32_f16(za, bw2_1, h1, 0, 0, 0);
#pragma unroll
        for (int r = 0; r < 4; ++r) {
            float v0 = fmaxf(h0[r], 0.f);
            float v1 = fmaxf(h1[r], 0.f);
            ps0 += v0; pq0 += v0 * v0;
            ps1 += v1; pq1 += v1 * v1;
            int nd = rowg * 4 + r;
            zw[nd * 36 + lan16] = v0;
            zw[nd * 36 + 16 + lan16] = v1;
        }
        int sn = l >> 2, sc = (l & 3) * 8;
        f32x4 hv0 = *(const f32x4*)&zw[sn * 36 + sc];
        f32x4 hv1 = *(const f32x4*)&zw[sn * 36 + sc + 4];
        __half hh[8];
#pragma unroll
        for (int i = 0; i < 4; ++i) {
            hh[i] = __float2half_rn(hv0[i]);
            hh[4 + i] = __float2half_rn(hv1[i]);
        }
        *(uint4*)(hdst + (size_t)(n0 + sn) * 32 + sc) = *(const uint4*)hh;
    }
    // stats: lane holds chan lan16 (ps0) and 16+lan16 (ps1); reduce across rowg groups
    ps0 += __shfl_xor(ps0, 16, 64); ps0 += __shfl_xor(ps0, 32, 64);
    ps1 += __shfl_xor(ps1, 16, 64); ps1 += __shfl_xor(ps1, 32, 64);
    pq0 += __shfl_xor(pq0, 16, 64); pq0 += __shfl_xor(pq0, 32, 64);
    pq1 += __shfl_xor(pq1, 16, 64); pq1 += __shfl_xor(pq1, 32, 64);
    if (l < 16) {
        sred[wid][lan16] = ps0;
        sred[wid][16 + lan16] = ps1;
        sred[wid][32 + lan16] = pq0;
        sred[wid][48 + lan16] = pq1;
    }
    __syncthreads();
    if (tid < 64) {
        float s = sred[0][tid] + sred[1][tid] + sred[2][tid] + sred[3][tid];
        partial[(size_t)blockIdx.x * 64 + tid] = s;
    }
}

// ---------------- finalize BN stats -> affine s,t (1 block/channel) ----------------
__global__ __launch_bounds__(256) void k_reduce(const float* __restrict__ partial, int nblocks,
                                                const float* __restrict__ g, const float* __restrict__ bt,
                                                float* __restrict__ aff) {
    int c = blockIdx.x;   // channel 0..31
    int t = threadIdx.x;
    double s = 0.0, q = 0.0;
    for (int b = t; b < nblocks; b += 256) {
        s += (double)partial[(size_t)b * 64 + c];
        q += (double)partial[(size_t)b * 64 + 32 + c];
    }
    __shared__ double shs[256], shq[256];
    shs[t] = s; shq[t] = q;
    __syncthreads();
    for (int off = 128; off; off >>= 1) {
        if (t < off) { shs[t] += shs[t + off]; shq[t] += shq[t + off]; }
        __syncthreads();
    }
    if (t == 0) {
        double mean = shs[0] / (double)NN;
        double var = shq[0] / (double)NN - mean * mean;
        float r = (float)rsqrt(var + 1e-5);
        float sv = g[c] * r;
        aff[c] = sv;
        aff[32 + c] = bt[c] - (float)mean * sv;
    }
}

// ---------------- pooling (xd_batch sorted -> run-length + atomics) ----------------
__global__ __launch_bounds__(256) void k_pool(const __half* __restrict__ h,
                                              const int* __restrict__ batch,
                                              float* __restrict__ ps) {
    int lane = threadIdx.x & 31;
    int g = threadIdx.x >> 5;
    const int chunk = (NN + gridDim.x - 1) / gridDim.x;
    int s0 = blockIdx.x * chunk;
    int s1 = min(NN, s0 + chunk);
    int curb = -1;
    float acc = 0.f;
    for (int i = s0 + g; i < s1; i += 8) {
        int b = batch[i];
        if (b != curb) {
            if (curb >= 0) atomicAdd(&ps[curb * 32 + lane], acc);
            acc = 0.f;
            curb = b;
        }
        acc += __half2float(h[(size_t)i * 32 + lane]);
    }
    if (curb >= 0) atomicAdd(&ps[curb * 32 + lane], acc);
}

__device__ int lowerb(const int* a, int n, int key) {
    int lo = 0, hi = n;
    while (lo < hi) {
        int m = (lo + hi) >> 1;
        if (a[m] < key) lo = m + 1;
        else hi = m;
    }
    return lo;
}

__global__ void k_counts(const int* __restrict__ batch, int* __restrict__ cnt) {
    int b = blockIdx.x * blockDim.x + threadIdx.x;
    if (b < BB) cnt[b] = lowerb(batch, NN, b + 1) - lowerb(batch, NN, b);
}

// ---------------- xdv = ReLU(pooled' @ fcd_w + fcd_b) ----------------
__global__ __launch_bounds__(128) void k_xdv(const float* __restrict__ ps,
                                             const int* __restrict__ cnt,
                                             const float* __restrict__ aff,
                                             const float* __restrict__ w,
                                             const float* __restrict__ bb,
                                             float* __restrict__ xdv) {
    int b = blockIdx.x;
    int j = threadIdx.x;
    __shared__ float p[32];
    if (j < 32) p[j] = aff[j] * ps[b * 32 + j] + (float)cnt[b] * aff[32 + j];
    __syncthreads();
    float acc = bb[j];
#pragma unroll
    for (int c = 0; c < 32; ++c) acc += p[c] * w[c * 128 + j];
    xdv[b * 128 + j] = fmaxf(acc, 0.f);
}

// ---------------- conv branch ----------------
__global__ void k_kT(const float* __restrict__ ck, float* __restrict__ kT) {
    int i = blockIdx.x;
    int t = threadIdx.x;
    int o = t >> 3, k = t & 7;
    kT[(size_t)i * 256 + t] = ck[(size_t)o * (LL * KK) + (size_t)i * KK + k];
}

__global__ __launch_bounds__(256) void k_conv(const int* __restrict__ xt,
                                              const float* __restrict__ kT,
                                              const float* __restrict__ emb,
                                              const float* __restrict__ cb,
                                              float* __restrict__ cbuf) {
    __shared__ float S[VOCAB * 256];
    __shared__ float Em[VOCAB * EMBD];
    int t = threadIdx.x;
    int b = blockIdx.x;
    for (int v = t; v < VOCAB * 256; v += 256) S[v] = 0.f;
    for (int v = t; v < VOCAB * EMBD; v += 256) Em[v] = emb[v];
    __syncthreads();
    const int* row = xt + (size_t)b * LL;
#pragma unroll 4
    for (int i = 0; i < LL; ++i) {
        int v = row[i];
        S[v * 256 + t] += kT[(size_t)i * 256 + t];
    }
    __syncthreads();
    int h = t & 127, half = t >> 7;
    if (h < 121) {
        float acc[16];
        int o0 = half * 16;
#pragma unroll
        for (int o = 0; o < 16; ++o) acc[o] = cb[o0 + o];
        for (int v = 0; v < VOCAB; ++v) {
            float e[8];
#pragma unroll
            for (int k = 0; k < 8; ++k) e[k] = Em[v * EMBD + h + k];
#pragma unroll
            for (int o = 0; o < 16; ++o) {
                float a = acc[o];
#pragma unroll
                for (int k = 0; k < 8; ++k) a += S[v * 256 + (o0 + o) * 8 + k] * e[k];
                acc[o] = a;
            }
        }
#pragma unroll
        for (int o = 0; o < 16; ++o)
            cbuf[(size_t)b * CF + (size_t)(o0 + o) * 121 + h] = acc[o];
    }
}

// ---------------- bias init ----------------
__global__ void k_binit(const float* __restrict__ bias, float* __restrict__ out, int mask) {
    int i = blockIdx.x * blockDim.x + threadIdx.x;
    out[i] = bias[i & mask];
}

// ---------------- xtv += c_tile @ w_tile (split-K, LDS-tiled, atomic accumulate) ----------------
__global__ __launch_bounds__(256) void k_xtv(const float* __restrict__ c,
                                             const float* __restrict__ w,
                                             float* __restrict__ xtv) {
    __shared__ float ct[16][484];
    int rb = blockIdx.x >> 3, kc = blockIdx.x & 7;
    int b0 = rb * 16, k0 = kc * 484;
    int tid = threadIdx.x;
#pragma unroll
    for (int r = 0; r < 16; ++r)
        for (int k = tid; k < 484; k += 256)
            ct[r][k] = c[(size_t)(b0 + r) * CF + k0 + k];
    __syncthreads();
    int j = tid & 127, rh = tid >> 7;
    float acc[8];
#pragma unroll
    for (int r = 0; r < 8; ++r) acc[r] = 0.f;
    const float2* ct2 = (const float2*)&ct[0][0];
    for (int k2 = 0; k2 < 242; ++k2) {
        float w0 = w[(size_t)(k0 + 2 * k2) * 128 + j];
        float w1 = w[(size_t)(k0 + 2 * k2 + 1) * 128 + j];
#pragma unroll
        for (int r = 0; r < 8; ++r) {
            float2 cv = ct2[(rh * 8 + r) * 242 + k2];
            acc[r] = fmaf(cv.x, w0, fmaf(cv.y, w1, acc[r]));
        }
    }
#pragma unroll
    for (int r = 0; r < 8; ++r)
        atomicAdd(&xtv[(size_t)(b0 + rh * 8 + r) * 128 + j], acc[r]);
}

// ---------------- classifier ----------------
__global__ __launch_bounds__(1024) void k_cls1(const float* __restrict__ xdv,
                                               const float* __restrict__ xtv,
                                               const float* __restrict__ w,
                                               const float* __restrict__ bb,
                                               float* __restrict__ h1) {
    __shared__ float X[8][256];
    int j = threadIdx.x;
    int b0 = blockIdx.x * 8;
    for (int idx = j; idx < 8 * 256; idx += 1024) {
        int r = idx >> 8, k = idx & 255;
        X[r][k] = (k < 128) ? xdv[(b0 + r) * 128 + k] : xtv[(b0 + r) * 128 + (k - 128)];
    }
    __syncthreads();
    float acc[8];
#pragma unroll
    for (int r = 0; r < 8; ++r) acc[r] = bb[j];
    for (int k = 0; k < 256; ++k) {
        float wv = w[(size_t)k * 1024 + j];
#pragma unroll
        for (int r = 0; r < 8; ++r) acc[r] += X[r][k] * wv;
    }
#pragma unroll
    for (int r = 0; r < 8; ++r) h1[(size_t)(b0 + r) * 1024 + j] = fmaxf(acc[r], 0.f);
}

__global__ __launch_bounds__(256) void k_cls2(const float* __restrict__ h1,
                                              const float* __restrict__ w,
                                              float* __restrict__ h2) {
    __shared__ float X[8][256];
    int rb = blockIdx.x >> 2, kc = blockIdx.x & 3;
    int b0 = rb * 8, k0 = kc * 256;
    int tid = threadIdx.x;
#pragma unroll
    for (int r = 0; r < 8; ++r)
        X[r][tid] = h1[(size_t)(b0 + r) * 1024 + k0 + tid];
    __syncthreads();
    int j = tid;
    float acc[8];
#pragma unroll
    for (int r = 0; r < 8; ++r) acc[r] = 0.f;
    const float2* X2 = (const float2*)&X[0][0];
    for (int k2 = 0; k2 < 128; ++k2) {
        float w0 = w[(size_t)(k0 + 2 * k2) * 256 + j];
        float w1 = w[(size_t)(k0 + 2 * k2 + 1) * 256 + j];
#pragma unroll
        for (int r = 0; r < 8; ++r) {
            float2 xv = X2[r * 128 + k2];
            acc[r] = fmaf(xv.x, w0, fmaf(xv.y, w1, acc[r]));
        }
    }
#pragma unroll
    for (int r = 0; r < 8; ++r)
        atomicAdd(&h2[(size_t)(b0 + r) * 256 + j], acc[r]);
}

__global__ __launch_bounds__(256) void k_cls3(const float* __restrict__ h2,
                                              const float* __restrict__ w,
                                              const float* __restrict__ bb,
                                              const float* __restrict__ y,
                                              float* __restrict__ dout) {
    int lane = threadIdx.x & 63;
    int b = (blockIdx.x * blockDim.x + threadIdx.x) >> 6;
    if (b >= BB) return;
    float acc = 0.f;
    for (int k = lane; k < 256; k += 64) acc += fmaxf(h2[(size_t)b * 256 + k], 0.f) * w[k];
#pragma unroll
    for (int off = 32; off; off >>= 1) acc += __shfl_xor(acc, off, 64);
    if (lane == 0) dout[b] = acc + bb[0];
    if (lane == 1) dout[BB + b] = y[b];
}

// ---------------- launch ----------------
extern "C" void kernel_launch(void* const* d_in, const int* in_sizes, int n_in,
                              void* d_out, int out_size, void* d_ws, size_t ws_size,
                              hipStream_t stream) {
    const float* xd = (const float*)d_in[0];
    const int* ei = (const int*)d_in[1];
    const int* batch = (const int*)d_in[2];
    const int* xt = (const int*)d_in[3];
    const float* y = (const float*)d_in[4];
    const float* g1w1 = (const float*)d_in[5];
    const float* g1b1 = (const float*)d_in[6];
    const float* g1w2 = (const float*)d_in[7];
    const float* g1b2 = (const float*)d_in[8];
    const float* grw1 = (const float*)d_in[9];
    const float* grb1 = (const float*)d_in[10];
    const float* grw2 = (const float*)d_in[11];
    const float* grb2 = (const float*)d_in[12];
    const float* bng = (const float*)d_in[13];
    const float* bnb = (const float*)d_in[14];
    const float* fcdw = (const float*)d_in[15];
    const float* fcdb = (const float*)d_in[16];
    const float* emb = (const float*)d_in[17];
    const float* convk = (const float*)d_in[18];
    const float* convb = (const float*)d_in[19];
    const float* fctw = (const float*)d_in[20];
    const float* fctb = (const float*)d_in[21];
    const float* cw1 = (const float*)d_in[22];
    const float* cb1 = (const float*)d_in[23];
    const float* cw2 = (const float*)d_in[24];
    const float* cb2 = (const float*)d_in[25];
    const float* cw3 = (const float*)d_in[26];
    const float* cb3 = (const float*)d_in[27];

    const int* src = ei;
    const int* dst = ei + EE;

    size_t off = 0;
    auto alloc = [&](size_t bytes) {
        size_t o = off;
        off = (off + bytes + 255) & ~(size_t)255;
        return o;
    };
    char* ws = (char*)d_ws;
    size_t o_rp = alloc(4ull * (NN + 1));
    size_t o_col = alloc(4ull * EE);
    size_t o_bc = alloc(4ull * 256);
    size_t o_bb = alloc(4ull * 256);
    size_t o_ha = alloc(2ull * NN * 32);
    size_t o_hb = alloc(2ull * NN * 32);
    size_t o_eb = alloc(8ull * NB * ESLOT);   // ebuf for CSR build (dead after k_build)
    size_t o_part = alloc(4ull * 2048 * 64);
    size_t o_aff = alloc(4ull * 64);
    size_t o_wf1 = alloc(2ull * 1024);
    size_t o_wf2 = alloc(2ull * 1024);
    size_t o_tv = alloc(4ull * 32);
    size_t o_ps = alloc(4ull * BB * 32);
    size_t o_cnt = alloc(4ull * BB);
    size_t o_xdv = alloc(4ull * BB * 128);
    size_t o_kT = alloc(4ull * LL * 256);
    size_t o_c = alloc(4ull * BB * CF);
    size_t o_xtv = alloc(4ull * BB * 128);
    size_t o_h1 = alloc(4ull * BB * 1024);
    size_t o_h2 = alloc(4ull * BB * 256);

    int* rp = (int*)(ws + o_rp);
    int* col = (int*)(ws + o_col);
    int* bcur = (int*)(ws + o_bc);
    int* bbase = (int*)(ws + o_bb);
    __half* ha = (__half*)(ws + o_ha);
    __half* hb = (__half*)(ws + o_hb);
    unsigned long long* ebuf = (unsigned long long*)(ws + o_eb);
    float* part = (float*)(ws + o_part);
    float* aff = (float*)(ws + o_aff);
    __half* wf1 = (__half*)(ws + o_wf1);
    __half* wf2 = (__half*)(ws + o_wf2);
    float* tvb = (float*)(ws + o_tv);
    float* ps = (float*)(ws + o_ps);
    int* cnt = (int*)(ws + o_cnt);
    float* xdv = (float*)(ws + o_xdv);
    float* kT = (float*)(ws + o_kT);
    float* cbuf = (float*)(ws + o_c);
    float* xtv = (float*)(ws + o_xtv);
    float* h1 = (float*)(ws + o_h1);
    float* h2 = (float*)(ws + o_h2);
    float* dout = (float*)d_out;

    // --- CSR build (bucketed two-pass) ---
    hipMemsetAsync(bcur, 0, 4ull * NB, stream);
    k_bscatter<<<977, 256, 0, stream>>>(src, dst, bcur, ebuf);
    k_bscan<<<1, 256, 0, stream>>>(bcur, bbase);
    k_build<<<NB, 256, 0, stream>>>(ebuf, bbase, bcur, rp, col);

    // --- GIN layers (fused gather + MFMA mlp) ---
    k_p1<<<(NN + 255) / 256, 256, 0, stream>>>(xd, g1w1, ha);

    // layer 1
    k_wfrag<1><<<1, 64, 0, stream>>>(aff, g1w1, g1w2, wf1, wf2, tvb);
    k_mlp<1><<<2048, 256, 0, stream>>>(ha, rp, col, wf1, wf2, tvb, g1b1, g1b2, hb, part);
    k_reduce<<<32, 256, 0, stream>>>(part, 2048, bng, bnb, aff);

    const __half* srcbuf = hb;
    __half* dstbuf = ha;
    for (int i = 0; i < 4; ++i) {
        k_wfrag<0><<<1, 64, 0, stream>>>(aff, grw1 + (size_t)i * 1024, grw2 + (size_t)i * 1024,
                                         wf1, wf2, tvb);
        k_mlp<0><<<2048, 256, 0, stream>>>(srcbuf, rp, col, wf1, wf2, tvb,
                                           grb1 + (size_t)i * 32, grb2 + (size_t)i * 32,
                                           dstbuf, part);
        k_reduce<<<32, 256, 0, stream>>>(part, 2048, bng + (i + 1) * 32, bnb + (i + 1) * 32, aff);
        const __half* tmp = srcbuf;
        srcbuf = dstbuf;
        dstbuf = (__half*)tmp;
    }
    // after loop: srcbuf == layer-5 output, aff == layer-5 affine

    // --- pooling + xdv ---
    hipMemsetAsync(ps, 0, 4ull * BB * 32, stream);
    k_pool<<<1024, 256, 0, stream>>>(srcbuf, batch, ps);
    k_counts<<<4, 256, 0, stream>>>(batch, cnt);
    k_xdv<<<BB, 128, 0, stream>>>(ps, cnt, aff, fcdw, fcdb, xdv);

    // --- conv branch ---
    k_kT<<<LL, 256, 0, stream>>>(convk, kT);
    k_conv<<<BB, 256, 0, stream>>>(xt, kT, emb, convb, cbuf);
    k_binit<<<BB * 128 / 256, 256, 0, stream>>>(fctb, xtv, 127);
    k_xtv<<<512, 256, 0, stream>>>(cbuf, fctw, xtv);

    // --- classifier ---
    k_cls1<<<BB / 8, 1024, 0, stream>>>(xdv, xtv, cw1, cb1, h1);
    k_binit<<<BB * 256 / 256, 256, 0, stream>>>(cb2, h2, 255);
    k_cls2<<<512, 256, 0, stream>>>(h1, cw2, h2);
    k_cls3<<<256, 256, 0, stream>>>(h2, cw3, cb3, y, dout);
}

// Round 9
// 1149.356 us; speedup vs baseline: 4.1515x; 1.0043x over previous
//
#include <hip/hip_runtime.h>
#include <hip/hip_bf16.h>
#include <hip/hip_fp16.h>

#define NN 1000000
#define EE 4000000
#define BB 1024
#define DIM 32
#define FXDIM 55
#define EMBD 128
#define VOCAB 26
#define LL 1000
#define NF 32
#define KK 8
#define CF 3872   // 32*121
#define BSH 12
#define NB 245          // ceil(NN / 4096)
#define ESLOT 20480     // padded records per bucket

typedef _Float16 f16x8 __attribute__((ext_vector_type(8)));
typedef float f32x4 __attribute__((ext_vector_type(4)));

// ---------------- CSR build: bucketed two-pass (write-coalescing-friendly) ----------------
__global__ __launch_bounds__(256) void k_bscatter(const int* __restrict__ src,
                                                  const int* __restrict__ dst,
                                                  int* __restrict__ bcur,
                                                  unsigned long long* __restrict__ ebuf) {
    __shared__ unsigned long long rec[4096];
    __shared__ short bid[4096];
    __shared__ int cnt[NB], pref[NB], gb[NB];
    __shared__ int sc[256];
    int t = threadIdx.x;
    for (int i = t; i < NB; i += 256) cnt[i] = 0;
    __syncthreads();
    size_t base = (size_t)blockIdx.x * 4096;
    int b_[16], s_[16], d_[16];
#pragma unroll
    for (int j = 0; j < 16; ++j) {
        size_t e = base + (size_t)j * 256 + t;
        if (e < EE) {
            int d = dst[e];
            b_[j] = d >> BSH;
            d_[j] = d;
            s_[j] = src[e];
            atomicAdd(&cnt[b_[j]], 1);
        } else b_[j] = -1;
    }
    __syncthreads();
    int v = (t < NB) ? cnt[t] : 0;
    sc[t] = v;
    __syncthreads();
    for (int off = 1; off < 256; off <<= 1) {
        int a = (t >= off) ? sc[t - off] : 0;
        __syncthreads();
        sc[t] += a;
        __syncthreads();
    }
    if (t < NB) {
        pref[t] = sc[t] - v;
        gb[t] = (v > 0) ? atomicAdd(&bcur[t], v) : 0;
        cnt[t] = 0;
    }
    __syncthreads();
#pragma unroll
    for (int j = 0; j < 16; ++j) {
        if (b_[j] >= 0) {
            int r = atomicAdd(&cnt[b_[j]], 1);
            int p = pref[b_[j]] + r;
            rec[p] = ((unsigned long long)(unsigned)d_[j] << 32) | (unsigned)s_[j];
            bid[p] = (short)b_[j];
        }
    }
    __syncthreads();
    int total = sc[NB - 1];
    for (int p = t; p < total; p += 256) {
        int b = bid[p];
        size_t gp = (size_t)b * ESLOT + gb[b] + (p - pref[b]);
        ebuf[gp] = rec[p];
    }
}

__global__ void k_bscan(const int* __restrict__ bcnt, int* __restrict__ bbase) {
    __shared__ int sh[256];
    int t = threadIdx.x;
    int v = (t < NB) ? bcnt[t] : 0;
    sh[t] = v;
    __syncthreads();
    for (int off = 1; off < 256; off <<= 1) {
        int a = (t >= off) ? sh[t - off] : 0;
        __syncthreads();
        sh[t] += a;
        __syncthreads();
    }
    if (t < NB) bbase[t] = sh[t] - v;
}

__global__ __launch_bounds__(256) void k_build(const unsigned long long* __restrict__ ebuf,
                                               const int* __restrict__ bbase,
                                               const int* __restrict__ bcnt,
                                               int* __restrict__ rowptr,
                                               int* __restrict__ col) {
    __shared__ int cnt[4096];
    __shared__ int pref[4096];
    __shared__ int part[256];
    int b = blockIdx.x, t = threadIdx.x;
    int n0 = b << BSH;
    int nmax = min(4096, NN - n0);
    for (int i = t; i < 4096; i += 256) cnt[i] = 0;
    __syncthreads();
    int e0 = bbase[b];
    int ne = bcnt[b];
    const unsigned long long* eb = ebuf + (size_t)b * ESLOT;
    for (int e = t; e < ne; e += 256) {
        int d = (int)(eb[e] >> 32) & 4095;
        atomicAdd(&cnt[d], 1);
    }
    __syncthreads();
    int s = 0, loc[16];
    int bi = t * 16;
#pragma unroll
    for (int j = 0; j < 16; ++j) { loc[j] = s; s += cnt[bi + j]; }
    part[t] = s;
    __syncthreads();
    for (int off = 1; off < 256; off <<= 1) {
        int a = (t >= off) ? part[t - off] : 0;
        __syncthreads();
        part[t] += a;
        __syncthreads();
    }
    int pb = part[t] - s;
#pragma unroll
    for (int j = 0; j < 16; ++j) pref[bi + j] = pb + loc[j];
    __syncthreads();
    for (int i = t; i < nmax; i += 256) rowptr[n0 + i] = e0 + pref[i];
    if (b == NB - 1 && t == 0) rowptr[NN] = EE;
    __syncthreads();
    for (int e = t; e < ne; e += 256) {
        unsigned long long r = eb[e];
        int d = (int)(r >> 32) & 4095;
        int p = atomicAdd(&pref[d], 1);
        col[e0 + p] = (int)(r & 0xffffffffu);
    }
}

// ---------------- w1 fragment prep for MFMA p1 (K padded 55 -> 64) ----------------
__global__ __launch_bounds__(64) void k_pfrag(const float* __restrict__ w1,
                                              __half* __restrict__ w1f) {
    int l = threadIdx.x;
    int kbase = (l >> 4) * 8;
    int jj = l & 15;
#pragma unroll
    for (int q = 0; q < 2; ++q) {
#pragma unroll
        for (int c = 0; c < 2; ++c) {
            __half v[8];
#pragma unroll
            for (int i = 0; i < 8; ++i) {
                int k = q * 32 + kbase + i;
                int j = c * 16 + jj;
                v[i] = (k < FXDIM) ? __float2half_rn(w1[k * 32 + j]) : __half(0.f);
            }
            *(uint4*)&w1f[(size_t)((q * 2 + c) * 64 + l) * 8] = *(const uint4*)v;
        }
    }
}

// ---------------- layer-1 projection p = xd @ w1 via MFMA (exactly-once reads) ----------------
// Per 16-node tile: lane l reads xd row (n0 + l&15), k-slice (l>>4)*8, two K=32 chunks.
// Wave collectively reads a contiguous 3.5KB block once. LDS-transpose epilogue.
__global__ __launch_bounds__(256) void k_p1(const float* __restrict__ xd,
                                            const __half* __restrict__ w1f,
                                            __half* __restrict__ out) {
    __shared__ float zb[4][16 * 36];
    int tid = threadIdx.x;
    int l = tid & 63;
    int wid = tid >> 6;
    int rowg = l >> 4;
    int lan16 = l & 15;
    f16x8 bw00 = __builtin_bit_cast(f16x8, *(const uint4*)&w1f[(size_t)(0 * 64 + l) * 8]);
    f16x8 bw01 = __builtin_bit_cast(f16x8, *(const uint4*)&w1f[(size_t)(1 * 64 + l) * 8]);
    f16x8 bw10 = __builtin_bit_cast(f16x8, *(const uint4*)&w1f[(size_t)(2 * 64 + l) * 8]);
    f16x8 bw11 = __builtin_bit_cast(f16x8, *(const uint4*)&w1f[(size_t)(3 * 64 + l) * 8]);
    float* zw = zb[wid];
    int gw = (blockIdx.x * 256 + tid) >> 6;
    int ngw = (gridDim.x * 256) >> 6;
    for (int t = gw; t < NN / 16; t += ngw) {
        int n0 = t * 16;
        const float* row = xd + (size_t)(n0 + lan16) * FXDIM;
        f16x8 a0, a1;
#pragma unroll
        for (int i = 0; i < 8; ++i) a0[i] = (_Float16)row[rowg * 8 + i];
#pragma unroll
        for (int i = 0; i < 8; ++i) {
            int k = 32 + rowg * 8 + i;
            a1[i] = (k < FXDIM) ? (_Float16)row[k] : (_Float16)0.f;
        }
        f32x4 h0, h1;
#pragma unroll
        for (int r = 0; r < 4; ++r) { h0[r] = 0.f; h1[r] = 0.f; }
        h0 = __builtin_amdgcn_mfma_f32_16x16x32_f16(a0, bw00, h0, 0, 0, 0);
        h1 = __builtin_amdgcn_mfma_f32_16x16x32_f16(a0, bw01, h1, 0, 0, 0);
        h0 = __builtin_amdgcn_mfma_f32_16x16x32_f16(a1, bw10, h0, 0, 0, 0);
        h1 = __builtin_amdgcn_mfma_f32_16x16x32_f16(a1, bw11, h1, 0, 0, 0);
#pragma unroll
        for (int r = 0; r < 4; ++r) {
            int nd = rowg * 4 + r;
            zw[nd * 36 + lan16] = h0[r];
            zw[nd * 36 + 16 + lan16] = h1[r];
        }
        int sn = l >> 2, sc = (l & 3) * 8;
        f32x4 hv0 = *(const f32x4*)&zw[sn * 36 + sc];
        f32x4 hv1 = *(const f32x4*)&zw[sn * 36 + sc + 4];
        __half hh[8];
#pragma unroll
        for (int i = 0; i < 4; ++i) {
            hh[i] = __float2half_rn(hv0[i]);
            hh[4 + i] = __float2half_rn(hv1[i]);
        }
        *(uint4*)(out + (size_t)(n0 + sn) * 32 + sc) = *(const uint4*)hh;
    }
}

// ---------------- per-layer weight fragment prep (BN folded into W1) ----------------
template <int FIRST>
__global__ __launch_bounds__(64) void k_wfrag(const float* __restrict__ aff,
                                              const float* __restrict__ w1,
                                              const float* __restrict__ w2,
                                              __half* __restrict__ wf1,
                                              __half* __restrict__ wf2,
                                              float* __restrict__ tv) {
    int l = threadIdx.x;
    int kbase = (l >> 4) * 8;
    int jj = l & 15;
#pragma unroll
    for (int c = 0; c < 2; ++c) {
        int j = c * 16 + jj;
        __half v1[8], v2[8];
#pragma unroll
        for (int i = 0; i < 8; ++i) {
            int k = kbase + i;
            float s = FIRST ? 1.f : aff[k];
            v1[i] = __float2half_rn(s * w1[k * 32 + j]);
            v2[i] = __float2half_rn(w2[k * 32 + j]);
        }
        *(uint4*)&wf1[(size_t)(c * 64 + l) * 8] = *(const uint4*)v1;
        *(uint4*)&wf2[(size_t)(c * 64 + l) * 8] = *(const uint4*)v2;
    }
    if (!FIRST && l < 32) {
        float acc = 0.f;
        for (int k = 0; k < 32; ++k) acc += aff[32 + k] * w1[k * 32 + l];
        tv[l] = acc;
    }
}

// ---------------- fused GIN layer: gather-agg (4-chain ILP) + MFMA MLP + BN stats ----------------
template <int FIRST>
__global__ __launch_bounds__(256) void k_mlp(const __half* __restrict__ hsrc,
                                             const int* __restrict__ rowptr,
                                             const int* __restrict__ colidx,
                                             const __half* __restrict__ wf1,
                                             const __half* __restrict__ wf2,
                                             const float* __restrict__ tv,
                                             const float* __restrict__ b1,
                                             const float* __restrict__ b2,
                                             __half* __restrict__ hdst,
                                             float* __restrict__ partial) {
    __shared__ float zb[4][16 * 36];
    __shared__ float sred[4][64];
    int tid = threadIdx.x;
    int l = tid & 63;
    int wid = tid >> 6;
    int rowg = l >> 4;
    int lan16 = l & 15;

    f16x8 bw2_0 = __builtin_bit_cast(f16x8, *(const uint4*)&wf2[(size_t)(0 * 64 + l) * 8]);
    f16x8 bw2_1 = __builtin_bit_cast(f16x8, *(const uint4*)&wf2[(size_t)(1 * 64 + l) * 8]);
    f16x8 bw1_0{}, bw1_1{};
    float tv0 = 0.f, tv1 = 0.f, b1c0 = 0.f, b1c1 = 0.f;
    float b1v[8];
    if (FIRST) {
#pragma unroll
        for (int i = 0; i < 8; ++i) b1v[i] = b1[rowg * 8 + i];
    } else {
        bw1_0 = __builtin_bit_cast(f16x8, *(const uint4*)&wf1[(size_t)(0 * 64 + l) * 8]);
        bw1_1 = __builtin_bit_cast(f16x8, *(const uint4*)&wf1[(size_t)(1 * 64 + l) * 8]);
        tv0 = tv[lan16];
        tv1 = tv[16 + lan16];
        b1c0 = b1[lan16];
        b1c1 = b1[16 + lan16];
    }
    float b2c0 = b2[lan16], b2c1 = b2[16 + lan16];
    float* zw = zb[wid];
    float ps0 = 0.f, ps1 = 0.f, pq0 = 0.f, pq1 = 0.f;
    int gw = (blockIdx.x * 256 + tid) >> 6;
    int ngw = (gridDim.x * 256) >> 6;
    for (int t = gw; t < NN / 16; t += ngw) {
        int n0 = t * 16;
        int node = n0 + lan16;
        int r0 = rowptr[node], r1 = rowptr[node + 1];
        // gather: self + neighbors, f32 accumulate, 4 independent chains
        uint4 su = *(const uint4*)(hsrc + (size_t)node * 32 + rowg * 8);
        f16x8 sf = __builtin_bit_cast(f16x8, su);
        float a0[8], a1[8], a2[8], a3[8];
#pragma unroll
        for (int i = 0; i < 8; ++i) {
            a0[i] = (float)sf[i];
            a1[i] = 0.f; a2[i] = 0.f; a3[i] = 0.f;
        }
        int e = r0;
        for (; e + 4 <= r1; e += 4) {
            int s0 = colidx[e], s1 = colidx[e + 1], s2 = colidx[e + 2], s3 = colidx[e + 3];
            uint4 u0 = *(const uint4*)(hsrc + (size_t)s0 * 32 + rowg * 8);
            uint4 u1 = *(const uint4*)(hsrc + (size_t)s1 * 32 + rowg * 8);
            uint4 u2 = *(const uint4*)(hsrc + (size_t)s2 * 32 + rowg * 8);
            uint4 u3 = *(const uint4*)(hsrc + (size_t)s3 * 32 + rowg * 8);
            f16x8 f0 = __builtin_bit_cast(f16x8, u0);
            f16x8 f1 = __builtin_bit_cast(f16x8, u1);
            f16x8 f2 = __builtin_bit_cast(f16x8, u2);
            f16x8 f3 = __builtin_bit_cast(f16x8, u3);
#pragma unroll
            for (int i = 0; i < 8; ++i) {
                a0[i] += (float)f0[i]; a1[i] += (float)f1[i];
                a2[i] += (float)f2[i]; a3[i] += (float)f3[i];
            }
        }
        if (e + 2 <= r1) {
            int s0 = colidx[e], s1 = colidx[e + 1];
            uint4 u0 = *(const uint4*)(hsrc + (size_t)s0 * 32 + rowg * 8);
            uint4 u1 = *(const uint4*)(hsrc + (size_t)s1 * 32 + rowg * 8);
            f16x8 f0 = __builtin_bit_cast(f16x8, u0);
            f16x8 f1 = __builtin_bit_cast(f16x8, u1);
#pragma unroll
            for (int i = 0; i < 8; ++i) { a1[i] += (float)f0[i]; a2[i] += (float)f1[i]; }
            e += 2;
        }
        if (e < r1) {
            uint4 u0 = *(const uint4*)(hsrc + (size_t)colidx[e] * 32 + rowg * 8);
            f16x8 f0 = __builtin_bit_cast(f16x8, u0);
#pragma unroll
            for (int i = 0; i < 8; ++i) a3[i] += (float)f0[i];
        }
        f16x8 za;
        if (FIRST) {
#pragma unroll
            for (int i = 0; i < 8; ++i)
                za[i] = (_Float16)fmaxf((a0[i] + a1[i]) + (a2[i] + a3[i]) + b1v[i], 0.f);
        } else {
            f16x8 af;
#pragma unroll
            for (int i = 0; i < 8; ++i) af[i] = (_Float16)((a0[i] + a1[i]) + (a2[i] + a3[i]));
            int rbase = n0 + rowg * 4;
            int4 rv = *(const int4*)&rowptr[rbase];
            int rext = rowptr[rbase + 4];
            float c0 = (float)(rv.y - rv.x + 1);
            float c1 = (float)(rv.z - rv.y + 1);
            float c2 = (float)(rv.w - rv.z + 1);
            float c3 = (float)(rext - rv.w + 1);
            f32x4 ac0, ac1;
            ac0[0] = fmaf(c0, tv0, b1c0); ac1[0] = fmaf(c0, tv1, b1c1);
            ac0[1] = fmaf(c1, tv0, b1c0); ac1[1] = fmaf(c1, tv1, b1c1);
            ac0[2] = fmaf(c2, tv0, b1c0); ac1[2] = fmaf(c2, tv1, b1c1);
            ac0[3] = fmaf(c3, tv0, b1c0); ac1[3] = fmaf(c3, tv1, b1c1);
            ac0 = __builtin_amdgcn_mfma_f32_16x16x32_f16(af, bw1_0, ac0, 0, 0, 0);
            ac1 = __builtin_amdgcn_mfma_f32_16x16x32_f16(af, bw1_1, ac1, 0, 0, 0);
#pragma unroll
            for (int r = 0; r < 4; ++r) {
                int nd = rowg * 4 + r;
                zw[nd * 36 + lan16] = fmaxf(ac0[r], 0.f);
                zw[nd * 36 + 16 + lan16] = fmaxf(ac1[r], 0.f);
            }
            f32x4 z0 = *(const f32x4*)&zw[lan16 * 36 + rowg * 8];
            f32x4 z1 = *(const f32x4*)&zw[lan16 * 36 + rowg * 8 + 4];
#pragma unroll
            for (int i = 0; i < 4; ++i) {
                za[i] = (_Float16)z0[i];
                za[4 + i] = (_Float16)z1[i];
            }
        }
        f32x4 h0, h1;
#pragma unroll
        for (int r = 0; r < 4; ++r) { h0[r] = b2c0; h1[r] = b2c1; }
        h0 = __builtin_amdgcn_mfma_f32_16x16x32_f16(za, bw2_0, h0, 0, 0, 0);
        h1 = __builtin_amdgcn_mfma_f32_16x16x32_f16(za, bw2_1, h1, 0, 0, 0);
#pragma unroll
        for (int r = 0; r < 4; ++r) {
            float v0 = fmaxf(h0[r], 0.f);
            float v1 = fmaxf(h1[r], 0.f);
            ps0 += v0; pq0 += v0 * v0;
            ps1 += v1; pq1 += v1 * v1;
            int nd = rowg * 4 + r;
            zw[nd * 36 + lan16] = v0;
            zw[nd * 36 + 16 + lan16] = v1;
        }
        int sn = l >> 2, sc = (l & 3) * 8;
        f32x4 hv0 = *(const f32x4*)&zw[sn * 36 + sc];
        f32x4 hv1 = *(const f32x4*)&zw[sn * 36 + sc + 4];
        __half hh[8];
#pragma unroll
        for (int i = 0; i < 4; ++i) {
            hh[i] = __float2half_rn(hv0[i]);
            hh[4 + i] = __float2half_rn(hv1[i]);
        }
        *(uint4*)(hdst + (size_t)(n0 + sn) * 32 + sc) = *(const uint4*)hh;
    }
    // stats reduce
    ps0 += __shfl_xor(ps0, 16, 64); ps0 += __shfl_xor(ps0, 32, 64);
    ps1 += __shfl_xor(ps1, 16, 64); ps1 += __shfl_xor(ps1, 32, 64);
    pq0 += __shfl_xor(pq0, 16, 64); pq0 += __shfl_xor(pq0, 32, 64);
    pq1 += __shfl_xor(pq1, 16, 64); pq1 += __shfl_xor(pq1, 32, 64);
    if (l < 16) {
        sred[wid][lan16] = ps0;
        sred[wid][16 + lan16] = ps1;
        sred[wid][32 + lan16] = pq0;
        sred[wid][48 + lan16] = pq1;
    }
    __syncthreads();
    if (tid < 64) {
        float s = sred[0][tid] + sred[1][tid] + sred[2][tid] + sred[3][tid];
        partial[(size_t)blockIdx.x * 64 + tid] = s;
    }
}

// ---------------- finalize BN stats -> affine s,t (1 block/channel) ----------------
__global__ __launch_bounds__(256) void k_reduce(const float* __restrict__ partial, int nblocks,
                                                const float* __restrict__ g, const float* __restrict__ bt,
                                                float* __restrict__ aff) {
    int c = blockIdx.x;
    int t = threadIdx.x;
    double s = 0.0, q = 0.0;
    for (int b = t; b < nblocks; b += 256) {
        s += (double)partial[(size_t)b * 64 + c];
        q += (double)partial[(size_t)b * 64 + 32 + c];
    }
    __shared__ double shs[256], shq[256];
    shs[t] = s; shq[t] = q;
    __syncthreads();
    for (int off = 128; off; off >>= 1) {
        if (t < off) { shs[t] += shs[t + off]; shq[t] += shq[t + off]; }
        __syncthreads();
    }
    if (t == 0) {
        double mean = shs[0] / (double)NN;
        double var = shq[0] / (double)NN - mean * mean;
        float r = (float)rsqrt(var + 1e-5);
        float sv = g[c] * r;
        aff[c] = sv;
        aff[32 + c] = bt[c] - (float)mean * sv;
    }
}

// ---------------- pooling (xd_batch sorted -> run-length + atomics) ----------------
__global__ __launch_bounds__(256) void k_pool(const __half* __restrict__ h,
                                              const int* __restrict__ batch,
                                              float* __restrict__ ps) {
    int lane = threadIdx.x & 31;
    int g = threadIdx.x >> 5;
    const int chunk = (NN + gridDim.x - 1) / gridDim.x;
    int s0 = blockIdx.x * chunk;
    int s1 = min(NN, s0 + chunk);
    int curb = -1;
    float acc = 0.f;
    for (int i = s0 + g; i < s1; i += 8) {
        int b = batch[i];
        if (b != curb) {
            if (curb >= 0) atomicAdd(&ps[curb * 32 + lane], acc);
            acc = 0.f;
            curb = b;
        }
        acc += __half2float(h[(size_t)i * 32 + lane]);
    }
    if (curb >= 0) atomicAdd(&ps[curb * 32 + lane], acc);
}

__device__ int lowerb(const int* a, int n, int key) {
    int lo = 0, hi = n;
    while (lo < hi) {
        int m = (lo + hi) >> 1;
        if (a[m] < key) lo = m + 1;
        else hi = m;
    }
    return lo;
}

__global__ void k_counts(const int* __restrict__ batch, int* __restrict__ cnt) {
    int b = blockIdx.x * blockDim.x + threadIdx.x;
    if (b < BB) cnt[b] = lowerb(batch, NN, b + 1) - lowerb(batch, NN, b);
}

// ---------------- xdv = ReLU(pooled' @ fcd_w + fcd_b) ----------------
__global__ __launch_bounds__(128) void k_xdv(const float* __restrict__ ps,
                                             const int* __restrict__ cnt,
                                             const float* __restrict__ aff,
                                             const float* __restrict__ w,
                                             const float* __restrict__ bb,
                                             float* __restrict__ xdv) {
    int b = blockIdx.x;
    int j = threadIdx.x;
    __shared__ float p[32];
    if (j < 32) p[j] = aff[j] * ps[b * 32 + j] + (float)cnt[b] * aff[32 + j];
    __syncthreads();
    float acc = bb[j];
#pragma unroll
    for (int c = 0; c < 32; ++c) acc += p[c] * w[c * 128 + j];
    xdv[b * 128 + j] = fmaxf(acc, 0.f);
}

// ---------------- conv branch ----------------
__global__ void k_kT(const float* __restrict__ ck, float* __restrict__ kT) {
    int i = blockIdx.x;
    int t = threadIdx.x;
    int o = t >> 3, k = t & 7;
    kT[(size_t)i * 256 + t] = ck[(size_t)o * (LL * KK) + (size_t)i * KK + k];
}

__global__ __launch_bounds__(256) void k_conv(const int* __restrict__ xt,
                                              const float* __restrict__ kT,
                                              const float* __restrict__ emb,
                                              const float* __restrict__ cb,
                                              float* __restrict__ cbuf) {
    __shared__ float S[VOCAB * 256];
    __shared__ float Em[VOCAB * EMBD];
    int t = threadIdx.x;
    int b = blockIdx.x;
    for (int v = t; v < VOCAB * 256; v += 256) S[v] = 0.f;
    for (int v = t; v < VOCAB * EMBD; v += 256) Em[v] = emb[v];
    __syncthreads();
    const int* row = xt + (size_t)b * LL;
#pragma unroll 4
    for (int i = 0; i < LL; ++i) {
        int v = row[i];
        S[v * 256 + t] += kT[(size_t)i * 256 + t];
    }
    __syncthreads();
    int h = t & 127, half = t >> 7;
    if (h < 121) {
        float acc[16];
        int o0 = half * 16;
#pragma unroll
        for (int o = 0; o < 16; ++o) acc[o] = cb[o0 + o];
        for (int v = 0; v < VOCAB; ++v) {
            float e[8];
#pragma unroll
            for (int k = 0; k < 8; ++k) e[k] = Em[v * EMBD + h + k];
#pragma unroll
            for (int o = 0; o < 16; ++o) {
                float a = acc[o];
#pragma unroll
                for (int k = 0; k < 8; ++k) a += S[v * 256 + (o0 + o) * 8 + k] * e[k];
                acc[o] = a;
            }
        }
#pragma unroll
        for (int o = 0; o < 16; ++o)
            cbuf[(size_t)b * CF + (size_t)(o0 + o) * 121 + h] = acc[o];
    }
}

// ---------------- bias init ----------------
__global__ void k_binit(const float* __restrict__ bias, float* __restrict__ out, int mask) {
    int i = blockIdx.x * blockDim.x + threadIdx.x;
    out[i] = bias[i & mask];
}

// ---------------- xtv += c_tile @ w_tile (split-K, LDS-tiled, atomic accumulate) ----------------
__global__ __launch_bounds__(256) void k_xtv(const float* __restrict__ c,
                                             const float* __restrict__ w,
                                             float* __restrict__ xtv) {
    __shared__ float ct[16][484];
    int rb = blockIdx.x >> 3, kc = blockIdx.x & 7;
    int b0 = rb * 16, k0 = kc * 484;
    int tid = threadIdx.x;
#pragma unroll
    for (int r = 0; r < 16; ++r)
        for (int k = tid; k < 484; k += 256)
            ct[r][k] = c[(size_t)(b0 + r) * CF + k0 + k];
    __syncthreads();
    int j = tid & 127, rh = tid >> 7;
    float acc[8];
#pragma unroll
    for (int r = 0; r < 8; ++r) acc[r] = 0.f;
    const float2* ct2 = (const float2*)&ct[0][0];
    for (int k2 = 0; k2 < 242; ++k2) {
        float w0 = w[(size_t)(k0 + 2 * k2) * 128 + j];
        float w1 = w[(size_t)(k0 + 2 * k2 + 1) * 128 + j];
#pragma unroll
        for (int r = 0; r < 8; ++r) {
            float2 cv = ct2[(rh * 8 + r) * 242 + k2];
            acc[r] = fmaf(cv.x, w0, fmaf(cv.y, w1, acc[r]));
        }
    }
#pragma unroll
    for (int r = 0; r < 8; ++r)
        atomicAdd(&xtv[(size_t)(b0 + rh * 8 + r) * 128 + j], acc[r]);
}

// ---------------- classifier ----------------
__global__ __launch_bounds__(1024) void k_cls1(const float* __restrict__ xdv,
                                               const float* __restrict__ xtv,
                                               const float* __restrict__ w,
                                               const float* __restrict__ bb,
                                               float* __restrict__ h1) {
    __shared__ float X[8][256];
    int j = threadIdx.x;
    int b0 = blockIdx.x * 8;
    for (int idx = j; idx < 8 * 256; idx += 1024) {
        int r = idx >> 8, k = idx & 255;
        X[r][k] = (k < 128) ? xdv[(b0 + r) * 128 + k] : xtv[(b0 + r) * 128 + (k - 128)];
    }
    __syncthreads();
    float acc[8];
#pragma unroll
    for (int r = 0; r < 8; ++r) acc[r] = bb[j];
    for (int k = 0; k < 256; ++k) {
        float wv = w[(size_t)k * 1024 + j];
#pragma unroll
        for (int r = 0; r < 8; ++r) acc[r] += X[r][k] * wv;
    }
#pragma unroll
    for (int r = 0; r < 8; ++r) h1[(size_t)(b0 + r) * 1024 + j] = fmaxf(acc[r], 0.f);
}

__global__ __launch_bounds__(256) void k_cls2(const float* __restrict__ h1,
                                              const float* __restrict__ w,
                                              float* __restrict__ h2) {
    __shared__ float X[8][256];
    int rb = blockIdx.x >> 2, kc = blockIdx.x & 3;
    int b0 = rb * 8, k0 = kc * 256;
    int tid = threadIdx.x;
#pragma unroll
    for (int r = 0; r < 8; ++r)
        X[r][tid] = h1[(size_t)(b0 + r) * 1024 + k0 + tid];
    __syncthreads();
    int j = tid;
    float acc[8];
#pragma unroll
    for (int r = 0; r < 8; ++r) acc[r] = 0.f;
    const float2* X2 = (const float2*)&X[0][0];
    for (int k2 = 0; k2 < 128; ++k2) {
        float w0 = w[(size_t)(k0 + 2 * k2) * 256 + j];
        float w1 = w[(size_t)(k0 + 2 * k2 + 1) * 256 + j];
#pragma unroll
        for (int r = 0; r < 8; ++r) {
            float2 xv = X2[r * 128 + k2];
            acc[r] = fmaf(xv.x, w0, fmaf(xv.y, w1, acc[r]));
        }
    }
#pragma unroll
    for (int r = 0; r < 8; ++r)
        atomicAdd(&h2[(size_t)(b0 + r) * 256 + j], acc[r]);
}

__global__ __launch_bounds__(256) void k_cls3(const float* __restrict__ h2,
                                              const float* __restrict__ w,
                                              const float* __restrict__ bb,
                                              const float* __restrict__ y,
                                              float* __restrict__ dout) {
    int lane = threadIdx.x & 63;
    int b = (blockIdx.x * blockDim.x + threadIdx.x) >> 6;
    if (b >= BB) return;
    float acc = 0.f;
    for (int k = lane; k < 256; k += 64) acc += fmaxf(h2[(size_t)b * 256 + k], 0.f) * w[k];
#pragma unroll
    for (int off = 32; off; off >>= 1) acc += __shfl_xor(acc, off, 64);
    if (lane == 0) dout[b] = acc + bb[0];
    if (lane == 1) dout[BB + b] = y[b];
}

// ---------------- launch ----------------
extern "C" void kernel_launch(void* const* d_in, const int* in_sizes, int n_in,
                              void* d_out, int out_size, void* d_ws, size_t ws_size,
                              hipStream_t stream) {
    const float* xd = (const float*)d_in[0];
    const int* ei = (const int*)d_in[1];
    const int* batch = (const int*)d_in[2];
    const int* xt = (const int*)d_in[3];
    const float* y = (const float*)d_in[4];
    const float* g1w1 = (const float*)d_in[5];
    const float* g1b1 = (const float*)d_in[6];
    const float* g1w2 = (const float*)d_in[7];
    const float* g1b2 = (const float*)d_in[8];
    const float* grw1 = (const float*)d_in[9];
    const float* grb1 = (const float*)d_in[10];
    const float* grw2 = (const float*)d_in[11];
    const float* grb2 = (const float*)d_in[12];
    const float* bng = (const float*)d_in[13];
    const float* bnb = (const float*)d_in[14];
    const float* fcdw = (const float*)d_in[15];
    const float* fcdb = (const float*)d_in[16];
    const float* emb = (const float*)d_in[17];
    const float* convk = (const float*)d_in[18];
    const float* convb = (const float*)d_in[19];
    const float* fctw = (const float*)d_in[20];
    const float* fctb = (const float*)d_in[21];
    const float* cw1 = (const float*)d_in[22];
    const float* cb1 = (const float*)d_in[23];
    const float* cw2 = (const float*)d_in[24];
    const float* cb2 = (const float*)d_in[25];
    const float* cw3 = (const float*)d_in[26];
    const float* cb3 = (const float*)d_in[27];

    const int* src = ei;
    const int* dst = ei + EE;

    size_t off = 0;
    auto alloc = [&](size_t bytes) {
        size_t o = off;
        off = (off + bytes + 255) & ~(size_t)255;
        return o;
    };
    char* ws = (char*)d_ws;
    size_t o_rp = alloc(4ull * (NN + 1));
    size_t o_col = alloc(4ull * EE);
    size_t o_bc = alloc(4ull * 256);
    size_t o_bb = alloc(4ull * 256);
    size_t o_ha = alloc(2ull * NN * 32);
    size_t o_hb = alloc(2ull * NN * 32);
    size_t o_eb = alloc(8ull * NB * ESLOT);
    size_t o_part = alloc(4ull * 2048 * 64);
    size_t o_aff = alloc(4ull * 64);
    size_t o_w1f = alloc(2ull * 2048);
    size_t o_wf1 = alloc(2ull * 1024);
    size_t o_wf2 = alloc(2ull * 1024);
    size_t o_tv = alloc(4ull * 32);
    size_t o_ps = alloc(4ull * BB * 32);
    size_t o_cnt = alloc(4ull * BB);
    size_t o_xdv = alloc(4ull * BB * 128);
    size_t o_kT = alloc(4ull * LL * 256);
    size_t o_c = alloc(4ull * BB * CF);
    size_t o_xtv = alloc(4ull * BB * 128);
    size_t o_h1 = alloc(4ull * BB * 1024);
    size_t o_h2 = alloc(4ull * BB * 256);

    int* rp = (int*)(ws + o_rp);
    int* col = (int*)(ws + o_col);
    int* bcur = (int*)(ws + o_bc);
    int* bbase = (int*)(ws + o_bb);
    __half* ha = (__half*)(ws + o_ha);
    __half* hb = (__half*)(ws + o_hb);
    unsigned long long* ebuf = (unsigned long long*)(ws + o_eb);
    float* part = (float*)(ws + o_part);
    float* aff = (float*)(ws + o_aff);
    __half* w1f = (__half*)(ws + o_w1f);
    __half* wf1 = (__half*)(ws + o_wf1);
    __half* wf2 = (__half*)(ws + o_wf2);
    float* tvb = (float*)(ws + o_tv);
    float* ps = (float*)(ws + o_ps);
    int* cnt = (int*)(ws + o_cnt);
    float* xdv = (float*)(ws + o_xdv);
    float* kT = (float*)(ws + o_kT);
    float* cbuf = (float*)(ws + o_c);
    float* xtv = (float*)(ws + o_xtv);
    float* h1 = (float*)(ws + o_h1);
    float* h2 = (float*)(ws + o_h2);
    float* dout = (float*)d_out;

    // --- CSR build (bucketed two-pass) ---
    hipMemsetAsync(bcur, 0, 4ull * NB, stream);
    k_bscatter<<<977, 256, 0, stream>>>(src, dst, bcur, ebuf);
    k_bscan<<<1, 256, 0, stream>>>(bcur, bbase);
    k_build<<<NB, 256, 0, stream>>>(ebuf, bbase, bcur, rp, col);

    // --- GIN layers (fused gather + MFMA mlp) ---
    k_pfrag<<<1, 64, 0, stream>>>(g1w1, w1f);
    k_p1<<<2048, 256, 0, stream>>>(xd, w1f, ha);

    // layer 1
    k_wfrag<1><<<1, 64, 0, stream>>>(aff, g1w1, g1w2, wf1, wf2, tvb);
    k_mlp<1><<<2048, 256, 0, stream>>>(ha, rp, col, wf1, wf2, tvb, g1b1, g1b2, hb, part);
    k_reduce<<<32, 256, 0, stream>>>(part, 2048, bng, bnb, aff);

    const __half* srcbuf = hb;
    __half* dstbuf = ha;
    for (int i = 0; i < 4; ++i) {
        k_wfrag<0><<<1, 64, 0, stream>>>(aff, grw1 + (size_t)i * 1024, grw2 + (size_t)i * 1024,
                                         wf1, wf2, tvb);
        k_mlp<0><<<2048, 256, 0, stream>>>(srcbuf, rp, col, wf1, wf2, tvb,
                                           grb1 + (size_t)i * 32, grb2 + (size_t)i * 32,
                                           dstbuf, part);
        k_reduce<<<32, 256, 0, stream>>>(part, 2048, bng + (i + 1) * 32, bnb + (i + 1) * 32, aff);
        const __half* tmp = srcbuf;
        srcbuf = dstbuf;
        dstbuf = (__half*)tmp;
    }
    // after loop: srcbuf == layer-5 output, aff == layer-5 affine

    // --- pooling + xdv ---
    hipMemsetAsync(ps, 0, 4ull * BB * 32, stream);
    k_pool<<<1024, 256, 0, stream>>>(srcbuf, batch, ps);
    k_counts<<<4, 256, 0, stream>>>(batch, cnt);
    k_xdv<<<BB, 128, 0, stream>>>(ps, cnt, aff, fcdw, fcdb, xdv);

    // --- conv branch ---
    k_kT<<<LL, 256, 0, stream>>>(convk, kT);
    k_conv<<<BB, 256, 0, stream>>>(xt, kT, emb, convb, cbuf);
    k_binit<<<BB * 128 / 256, 256, 0, stream>>>(fctb, xtv, 127);
    k_xtv<<<512, 256, 0, stream>>>(cbuf, fctw, xtv);

    // --- classifier ---
    k_cls1<<<BB / 8, 1024, 0, stream>>>(xdv, xtv, cw1, cb1, h1);
    k_binit<<<BB * 256 / 256, 256, 0, stream>>>(cb2, h2, 255);
    k_cls2<<<512, 256, 0, stream>>>(h1, cw2, h2);
    k_cls3<<<256, 256, 0, stream>>>(h2, cw3, cb3, y, dout);
}